// Round 8
// baseline (2375.496 us; speedup 1.0000x reference)
//
#include <hip/hip_runtime.h>
#include <hip/hip_bf16.h>
#include <cstdint>
#include <cstddef>

// Problem dims
#define TT 4096   // B*S tokens
#define SS 2048   // S
#define DD 1024   // D
#define DDI 2048  // DI
#define LL 6
#define VV 32000
#define AA 7

typedef __hip_bfloat16 bf16;
typedef __attribute__((ext_vector_type(8))) short bf16x8;   // 8 bf16 in 4 VGPRs
typedef __attribute__((ext_vector_type(4))) float f32x4;

typedef const __attribute__((address_space(1))) void* gas_ptr;
typedef __attribute__((address_space(3))) void* las_ptr;

static __device__ __forceinline__ float b2f(bf16 h) { return __bfloat162float(h); }
static __device__ __forceinline__ bf16 f2b(float f) { return __float2bfloat16(f); }
static __device__ __forceinline__ float bs2f(short x) {
    unsigned int u = ((unsigned int)(unsigned short)x) << 16;
    float f; __builtin_memcpy(&f, &u, 4); return f;
}

// 64-B rows, 4x16B chunks; chunk ^= (row>>1)&3 -> verified 0 conflicts (R4/R5).
#define SWZ(off) ((off) ^ ((((off) >> 7) & 3) << 4))

// ---------------------------------------------------------------------------
// g8 (measured 347us on lang_w2, R5/R7): 256x256 8-phase GEMM, BK=64, 8 waves.
// Two 4-slot rings of 16 KiB K-half tiles; counted vmcnt(10); 0 conflicts.
// EPI: 0 = store bf16; 5 = bias + f32 store.
// ---------------------------------------------------------------------------
template<int EPI>
__global__ __launch_bounds__(512, 2)
void g8_k(const bf16* __restrict__ A, const bf16* __restrict__ Wt,
          int K, int mx, int out_ld,
          float* __restrict__ of32, bf16* __restrict__ ob16,
          const float* __restrict__ bias)
{
    extern __shared__ char lds[];   // 131072
    const int nwg = gridDim.x;
    int l = blockIdx.x;
    if ((nwg & 7) == 0) l = (l & 7) * (nwg >> 3) + (l >> 3);   // XCD-chunked
    const int row0 = (l % mx) * 256, col0 = (l / mx) * 256;

    const int tid = threadIdx.x, wid = tid >> 6, lane = tid & 63;
    const int wr = wid >> 2, wc = wid & 3;        // 2M x 4N waves
    const int l15 = lane & 15, kq = lane >> 4;

    f32x4 acc[8][4];
#pragma unroll
    for (int m = 0; m < 8; ++m)
#pragma unroll
        for (int n = 0; n < 4; ++n) acc[m][n] = f32x4{0.f, 0.f, 0.f, 0.f};

    const int sr   = tid >> 2;
    const int colE = (((tid & 3) ^ ((tid >> 3) & 3)) * 8);
    const bf16* gA = A  + (size_t)(row0 + sr) * K + colE;
    const bf16* gB = Wt + (size_t)(col0 + sr) * K + colE;
    const int dst0 = tid * 16, dst1 = 8192 + tid * 16;

    auto stageA = [&](int kh) {
        char* b = lds + (kh & 3) * 16384;
        __builtin_amdgcn_global_load_lds((gas_ptr)(gA + kh * 32),                   (las_ptr)(b + dst0), 16, 0, 0);
        __builtin_amdgcn_global_load_lds((gas_ptr)(gA + (size_t)128 * K + kh * 32), (las_ptr)(b + dst1), 16, 0, 0);
    };
    auto stageB = [&](int kh) {
        char* b = lds + 65536 + (kh & 3) * 16384;
        __builtin_amdgcn_global_load_lds((gas_ptr)(gB + kh * 32),                   (las_ptr)(b + dst0), 16, 0, 0);
        __builtin_amdgcn_global_load_lds((gas_ptr)(gB + (size_t)128 * K + kh * 32), (las_ptr)(b + dst1), 16, 0, 0);
    };

    const int NT = K >> 6, KH = K >> 5;
    stageA(0); stageB(0); stageA(1); stageB(1);
    stageA(2); stageB(2); stageA(3); stageB(3);
    int nextA = 4, nextB = 4;

    for (int t = 0; t < NT; ++t) {
        const char* As0 = lds + ((2 * t) & 3) * 16384;
        const char* As1 = lds + ((2 * t + 1) & 3) * 16384;
        const char* Bs0 = lds + 65536 + ((2 * t) & 3) * 16384;
        const char* Bs1 = lds + 65536 + ((2 * t + 1) & 3) * 16384;
        bf16x8 af[4], bfg[4];

        // q0
        if (t < NT - 3) asm volatile("s_waitcnt vmcnt(10)" ::: "memory");
        else            asm volatile("s_waitcnt vmcnt(0)" ::: "memory");
        __builtin_amdgcn_sched_barrier(0);
        __builtin_amdgcn_s_barrier();
        __builtin_amdgcn_sched_barrier(0);
#pragma unroll
        for (int fn = 0; fn < 4; ++fn)
            bfg[fn] = *(const bf16x8*)(Bs0 + SWZ((wc * 64 + fn * 16 + l15) * 64 + kq * 16));
#pragma unroll
        for (int fm = 0; fm < 4; ++fm)
            af[fm] = *(const bf16x8*)(As0 + SWZ((wr * 128 + fm * 16 + l15) * 64 + kq * 16));
        if (t > 0 && nextA < KH) { stageA(nextA); ++nextA; }
        asm volatile("s_waitcnt lgkmcnt(0)" ::: "memory");
        __builtin_amdgcn_sched_barrier(0);
        __builtin_amdgcn_s_setprio(1);
#pragma unroll
        for (int fm = 0; fm < 4; ++fm)
#pragma unroll
            for (int fn = 0; fn < 4; ++fn)
                acc[fm][fn] = __builtin_amdgcn_mfma_f32_16x16x32_bf16(af[fm], bfg[fn], acc[fm][fn], 0, 0, 0);
        __builtin_amdgcn_s_setprio(0);
        __builtin_amdgcn_sched_barrier(0);
        __builtin_amdgcn_s_barrier();
        __builtin_amdgcn_sched_barrier(0);

        // q1 (A mh1 of ks0; B reg-reused)
#pragma unroll
        for (int fm = 0; fm < 4; ++fm)
            af[fm] = *(const bf16x8*)(As0 + SWZ((wr * 128 + 64 + fm * 16 + l15) * 64 + kq * 16));
        if (nextB < KH) { stageB(nextB); ++nextB; }
        asm volatile("s_waitcnt lgkmcnt(0)" ::: "memory");
        __builtin_amdgcn_sched_barrier(0);
        __builtin_amdgcn_s_setprio(1);
#pragma unroll
        for (int fm = 0; fm < 4; ++fm)
#pragma unroll
            for (int fn = 0; fn < 4; ++fn)
                acc[4 + fm][fn] = __builtin_amdgcn_mfma_f32_16x16x32_bf16(af[fm], bfg[fn], acc[4 + fm][fn], 0, 0, 0);
        __builtin_amdgcn_s_setprio(0);
        __builtin_amdgcn_sched_barrier(0);
        __builtin_amdgcn_s_barrier();
        __builtin_amdgcn_sched_barrier(0);

        // q2
        if (t < NT - 3) asm volatile("s_waitcnt vmcnt(10)" ::: "memory");
        else            asm volatile("s_waitcnt vmcnt(0)" ::: "memory");
        __builtin_amdgcn_sched_barrier(0);
        __builtin_amdgcn_s_barrier();
        __builtin_amdgcn_sched_barrier(0);
#pragma unroll
        for (int fn = 0; fn < 4; ++fn)
            bfg[fn] = *(const bf16x8*)(Bs1 + SWZ((wc * 64 + fn * 16 + l15) * 64 + kq * 16));
#pragma unroll
        for (int fm = 0; fm < 4; ++fm)
            af[fm] = *(const bf16x8*)(As1 + SWZ((wr * 128 + fm * 16 + l15) * 64 + kq * 16));
        if (nextA < KH) { stageA(nextA); ++nextA; }
        asm volatile("s_waitcnt lgkmcnt(0)" ::: "memory");
        __builtin_amdgcn_sched_barrier(0);
        __builtin_amdgcn_s_setprio(1);
#pragma unroll
        for (int fm = 0; fm < 4; ++fm)
#pragma unroll
            for (int fn = 0; fn < 4; ++fn)
                acc[fm][fn] = __builtin_amdgcn_mfma_f32_16x16x32_bf16(af[fm], bfg[fn], acc[fm][fn], 0, 0, 0);
        __builtin_amdgcn_s_setprio(0);
        __builtin_amdgcn_sched_barrier(0);
        __builtin_amdgcn_s_barrier();
        __builtin_amdgcn_sched_barrier(0);

        // q3 (A mh1 of ks1; B reg-reused)
#pragma unroll
        for (int fm = 0; fm < 4; ++fm)
            af[fm] = *(const bf16x8*)(As1 + SWZ((wr * 128 + 64 + fm * 16 + l15) * 64 + kq * 16));
        if (nextB < KH) { stageB(nextB); ++nextB; }
        asm volatile("s_waitcnt lgkmcnt(0)" ::: "memory");
        __builtin_amdgcn_sched_barrier(0);
        __builtin_amdgcn_s_setprio(1);
#pragma unroll
        for (int fm = 0; fm < 4; ++fm)
#pragma unroll
            for (int fn = 0; fn < 4; ++fn)
                acc[4 + fm][fn] = __builtin_amdgcn_mfma_f32_16x16x32_bf16(af[fm], bfg[fn], acc[4 + fm][fn], 0, 0, 0);
        __builtin_amdgcn_s_setprio(0);
        __builtin_amdgcn_sched_barrier(0);
        __builtin_amdgcn_s_barrier();
        __builtin_amdgcn_sched_barrier(0);
    }

#pragma unroll
    for (int fm = 0; fm < 8; ++fm) {
#pragma unroll
        for (int fn = 0; fn < 4; ++fn) {
#pragma unroll
            for (int r = 0; r < 4; ++r) {
                const int row = row0 + wr * 128 + fm * 16 + kq * 4 + r;
                const int col = col0 + wc * 64 + fn * 16 + l15;
                float v = acc[fm][fn][r];
                if (EPI == 0) ob16[(size_t)row * out_ld + col] = f2b(v);
                else          of32[(size_t)row * out_ld + col] = v + bias[col];
            }
        }
    }
}

// ---------------------------------------------------------------------------
// 128x128 m97-structure GEMM (R1 baseline kernel).
// EPI: 0=store bf16; 2=mul silu(z) store bf16;
//      3=residual f32 in/out + bf16 out; 4=bias+relu bf16
// ---------------------------------------------------------------------------
template<int EPI>
__global__ __launch_bounds__(256)
void gemm_k(const bf16* __restrict__ A, const bf16* __restrict__ Wt,
            int K, int out_ld,
            float* __restrict__ of32, bf16* __restrict__ ob16,
            const float* __restrict__ bias,
            const bf16* __restrict__ zp, int z_ld)
{
    __shared__ bf16x8 lsA8[128 * 4];
    __shared__ bf16x8 lsB8[128 * 4];
    bf16* lsA = (bf16*)lsA8;
    bf16* lsB = (bf16*)lsB8;

    const int tid  = threadIdx.x;
    const int w    = tid >> 6;
    const int lane = tid & 63;
    const int row0 = blockIdx.x * 128;
    const int col0 = blockIdx.y * 128;
    const int wr   = (w >> 1) * 64;
    const int wc   = (w & 1) * 64;
    const int l15  = lane & 15;
    const int kq   = lane >> 4;

    f32x4 acc[4][4];
#pragma unroll
    for (int m = 0; m < 4; ++m)
#pragma unroll
        for (int n = 0; n < 4; ++n) acc[m][n] = f32x4{0.f, 0.f, 0.f, 0.f};

    const int s0 = tid, s1 = tid + 256;
    const size_t ga0 = (size_t)(row0 + (s0 >> 2)) * K + (s0 & 3) * 8;
    const size_t ga1 = (size_t)(row0 + (s1 >> 2)) * K + (s1 & 3) * 8;
    const size_t gb0 = (size_t)(col0 + (s0 >> 2)) * K + (s0 & 3) * 8;
    const size_t gb1 = (size_t)(col0 + (s1 >> 2)) * K + (s1 & 3) * 8;
    bf16* la0 = lsA + (size_t)(w * 64) * 8;
    bf16* la1 = lsA + (size_t)(256 + w * 64) * 8;
    bf16* lb0 = lsB + (size_t)(w * 64) * 8;
    bf16* lb1 = lsB + (size_t)(256 + w * 64) * 8;

    for (int k0 = 0; k0 < K; k0 += 32) {
        __builtin_amdgcn_global_load_lds((gas_ptr)(A  + ga0 + k0), (las_ptr)la0, 16, 0, 0);
        __builtin_amdgcn_global_load_lds((gas_ptr)(A  + ga1 + k0), (las_ptr)la1, 16, 0, 0);
        __builtin_amdgcn_global_load_lds((gas_ptr)(Wt + gb0 + k0), (las_ptr)lb0, 16, 0, 0);
        __builtin_amdgcn_global_load_lds((gas_ptr)(Wt + gb1 + k0), (las_ptr)lb1, 16, 0, 0);
        __syncthreads();

        bf16x8 af[4], bfr[4];
#pragma unroll
        for (int m = 0; m < 4; ++m)
            af[m] = *(const bf16x8*)(lsA + (size_t)(wr + m * 16 + l15) * 32 + kq * 8);
#pragma unroll
        for (int n = 0; n < 4; ++n)
            bfr[n] = *(const bf16x8*)(lsB + (size_t)(wc + n * 16 + l15) * 32 + kq * 8);
#pragma unroll
        for (int m = 0; m < 4; ++m)
#pragma unroll
            for (int n = 0; n < 4; ++n)
                acc[m][n] = __builtin_amdgcn_mfma_f32_16x16x32_bf16(af[m], bfr[n], acc[m][n], 0, 0, 0);
        __syncthreads();
    }

#pragma unroll
    for (int m = 0; m < 4; ++m) {
#pragma unroll
        for (int n = 0; n < 4; ++n) {
#pragma unroll
            for (int r = 0; r < 4; ++r) {
                const int row = row0 + wr + m * 16 + kq * 4 + r;
                const int col = col0 + wc + n * 16 + l15;
                float v = acc[m][n][r];
                if (EPI == 0) {
                    ob16[(size_t)row * out_ld + col] = f2b(v);
                } else if (EPI == 2) {
                    float zf = b2f(zp[(size_t)row * z_ld + col]);
                    v *= zf / (1.f + expf(-zf));
                    ob16[(size_t)row * out_ld + col] = f2b(v);
                } else if (EPI == 3) {
                    float rr = of32[(size_t)row * out_ld + col] + v;
                    of32[(size_t)row * out_ld + col] = rr;
                    ob16[(size_t)row * out_ld + col] = f2b(rr);
                } else if (EPI == 4) {
                    v = fmaxf(v + bias[col], 0.f);
                    ob16[(size_t)row * out_ld + col] = f2b(v);
                }
            }
        }
    }
}

// ---------------------------------------------------------------------------
// fp32 [K,N] -> bf16 [N,K] transpose (64x64 tiles through LDS)
// ---------------------------------------------------------------------------
__global__ __launch_bounds__(256)
void transpose_k(const float* __restrict__ W, bf16* __restrict__ WT, int K, int N)
{
    __shared__ bf16 t[64][66];
    const int k0 = blockIdx.x * 64, n0 = blockIdx.y * 64;
    const int tid = threadIdx.x;
#pragma unroll
    for (int i = 0; i < 16; ++i) {
        int idx = i * 256 + tid;
        int kk = idx >> 6, nn = idx & 63;
        t[nn][kk] = f2b(W[(size_t)(k0 + kk) * N + n0 + nn]);
    }
    __syncthreads();
#pragma unroll
    for (int i = 0; i < 16; ++i) {
        int idx = i * 256 + tid;
        int nn = idx >> 6, kk = idx & 63;
        WT[(size_t)(n0 + nn) * K + k0 + kk] = t[nn][kk];
    }
}

// C_ssm [16,DI] fp32 -> bf16 [DI,32] padded (K padded 16->32)
__global__ void prep_cm_k(const float* __restrict__ Cm, bf16* __restrict__ CmT)
{
    int idx = blockIdx.x * 256 + threadIdx.x;   // 2048*32
    int i = idx >> 5, k = idx & 31;
    float v = (k < 16) ? Cm[(size_t)k * 2048 + i] : 0.f;
    CmT[idx] = f2b(v);
}

// features -> fp32 residual copy + bf16 copy
__global__ void copyfeat_k(const float* __restrict__ f, float* __restrict__ xf,
                           bf16* __restrict__ xb)
{
    int i = (blockIdx.x * 256 + threadIdx.x) * 4;
    float4 v = *(const float4*)(f + i);
    *(float4*)(xf + i) = v;
    xb[i + 0] = f2b(v.x);
    xb[i + 1] = f2b(v.y);
    xb[i + 2] = f2b(v.z);
    xb[i + 3] = f2b(v.w);
}

// ---------------------------------------------------------------------------
// Fused causal dwconv(K=4)+bias+silu+B-projection (validated R2-R5):
// u[t,n] = 0.1 * sum_i silu(conv(xp)[t,i]) * Bm[i,n]
// One block per token; thread handles 8 channels; 16-acc shuffle+LDS reduce.
// ---------------------------------------------------------------------------
__global__ __launch_bounds__(256)
void convu_k(const bf16* __restrict__ xz, const float* __restrict__ cw,
             const float* __restrict__ cb, const float* __restrict__ Bm,
             float* __restrict__ u)
{
    const int t = blockIdx.x, tid = threadIdx.x;
    const int s = t & (SS - 1);
    const int i0 = tid * 8;
    const int lane = tid & 63, wv = tid >> 6;

    const bf16* b0 = xz + (size_t)t * 4096 + i0;
    bf16x8 x0 = *(const bf16x8*)b0;
    bf16x8 x1 = {}, x2 = {}, x3 = {};
    if (s >= 1) x1 = *(const bf16x8*)(b0 - 4096);
    if (s >= 2) x2 = *(const bf16x8*)(b0 - 2 * 4096);
    if (s >= 3) x3 = *(const bf16x8*)(b0 - 3 * 4096);

    float p[16];
#pragma unroll
    for (int n = 0; n < 16; ++n) p[n] = 0.f;

#pragma unroll
    for (int c = 0; c < 8; ++c) {
        const int i = i0 + c;
        float4 wv4 = ((const float4*)cw)[i];
        float acc = cb[i];
        acc = fmaf(bs2f(x3[c]), wv4.x, acc);
        acc = fmaf(bs2f(x2[c]), wv4.y, acc);
        acc = fmaf(bs2f(x1[c]), wv4.z, acc);
        acc = fmaf(bs2f(x0[c]), wv4.w, acc);
        float v = acc / (1.f + expf(-acc));      // silu
        const float4* bm = (const float4*)(Bm + (size_t)i * 16);
        float4 m0 = bm[0], m1 = bm[1], m2 = bm[2], m3 = bm[3];
        p[0]  = fmaf(v, m0.x, p[0]);  p[1]  = fmaf(v, m0.y, p[1]);
        p[2]  = fmaf(v, m0.z, p[2]);  p[3]  = fmaf(v, m0.w, p[3]);
        p[4]  = fmaf(v, m1.x, p[4]);  p[5]  = fmaf(v, m1.y, p[5]);
        p[6]  = fmaf(v, m1.z, p[6]);  p[7]  = fmaf(v, m1.w, p[7]);
        p[8]  = fmaf(v, m2.x, p[8]);  p[9]  = fmaf(v, m2.y, p[9]);
        p[10] = fmaf(v, m2.z, p[10]); p[11] = fmaf(v, m2.w, p[11]);
        p[12] = fmaf(v, m3.x, p[12]); p[13] = fmaf(v, m3.y, p[13]);
        p[14] = fmaf(v, m3.z, p[14]); p[15] = fmaf(v, m3.w, p[15]);
    }
#pragma unroll
    for (int off = 32; off > 0; off >>= 1)
#pragma unroll
        for (int n = 0; n < 16; ++n) p[n] += __shfl_down(p[n], off, 64);

    __shared__ float red[4][16];
    if (lane == 0)
#pragma unroll
        for (int n = 0; n < 16; ++n) red[wv][n] = p[n];
    __syncthreads();
    if (tid < 16)
        u[(size_t)t * 16 + tid] = 0.1f * (red[0][tid] + red[1][tid] + red[2][tid] + red[3][tid]);
}

// ---------------------------------------------------------------------------
// scan h_t = 0.9 h + u_t; chunk=32 tokens, redundant 96-step warmup;
// writes hs [T,32] bf16 with cols 16..31 zeroed (K-pad for the Cm GEMM).
// ---------------------------------------------------------------------------
__global__ void scan2_k(const float* __restrict__ u, bf16* __restrict__ hs)
{
    int gid = blockIdx.x * 256 + threadIdx.x;   // 2048 total
    int n = gid & 15, c = (gid >> 4) & 63, b = gid >> 10;
    int start = c * 32;
    const float* ub = u + (size_t)b * SS * 16;
    bf16* hb = hs + (size_t)b * SS * 32;
    float h = 0.f;
    int w0 = start - 96; if (w0 < 0) w0 = 0;
    for (int t = w0; t < start; ++t) h = 0.9f * h + ub[(size_t)t * 16 + n];
    const bf16 zero = f2b(0.f);
    for (int t = start; t < start + 32; ++t) {
        h = 0.9f * h + ub[(size_t)t * 16 + n];
        hb[(size_t)t * 32 + n] = f2b(h);
        hb[(size_t)t * 32 + 16 + n] = zero;
    }
}

// LayerNorm fp32 -> bf16
__global__ __launch_bounds__(256)
void ln_k(const float* __restrict__ x, const float* __restrict__ g,
          const float* __restrict__ bb, bf16* __restrict__ xn)
{
    int t = blockIdx.x, tid = threadIdx.x;
    const float* xr = x + (size_t)t * DD;
    float4 v = *(const float4*)(xr + tid * 4);
    float s = v.x + v.y + v.z + v.w;
#pragma unroll
    for (int o = 32; o > 0; o >>= 1) s += __shfl_down(s, o, 64);
    __shared__ float r1[4], r2[4];
    if ((tid & 63) == 0) r1[tid >> 6] = s;
    __syncthreads();
    float mu = (r1[0] + r1[1] + r1[2] + r1[3]) * (1.f / DD);
    float d0 = v.x - mu, d1 = v.y - mu, d2 = v.z - mu, d3 = v.w - mu;
    float ss = d0 * d0 + d1 * d1 + d2 * d2 + d3 * d3;
#pragma unroll
    for (int o = 32; o > 0; o >>= 1) ss += __shfl_down(ss, o, 64);
    if ((tid & 63) == 0) r2[tid >> 6] = ss;
    __syncthreads();
    float var = (r2[0] + r2[1] + r2[2] + r2[3]) * (1.f / DD);
    float inv = rsqrtf(var + 1e-5f);
    int di = tid * 4;
    xn[(size_t)t * DD + di + 0] = f2b(d0 * inv * g[di + 0] + bb[di + 0]);
    xn[(size_t)t * DD + di + 1] = f2b(d1 * inv * g[di + 1] + bb[di + 1]);
    xn[(size_t)t * DD + di + 2] = f2b(d2 * inv * g[di + 2] + bb[di + 2]);
    xn[(size_t)t * DD + di + 3] = f2b(d3 * inv * g[di + 3] + bb[di + 3]);
}

// tiny head: actions = tanh(h2 @ w3 + b3)
__global__ void act3_k(const bf16* __restrict__ h2, const float* __restrict__ w3,
                       const float* __restrict__ b3, float* __restrict__ out)
{
    int idx = blockIdx.x * 256 + threadIdx.x;
    if (idx >= TT * AA) return;
    int t = idx / AA, a = idx - t * AA;
    float acc = b3[a];
    const bf16* hr = h2 + (size_t)t * 256;
    for (int k = 0; k < 256; ++k)
        acc = fmaf(b2f(hr[k]), w3[k * AA + a], acc);
    out[idx] = tanhf(acc);
}

// ---------------------------------------------------------------------------
extern "C" void kernel_launch(void* const* d_in, const int* in_sizes, int n_in,
                              void* d_out, int out_size, void* d_ws, size_t ws_size,
                              hipStream_t stream)
{
    (void)in_sizes; (void)n_in; (void)out_size; (void)ws_size;
    const float* features = (const float*)d_in[0];
    const float* in_proj_w = (const float*)d_in[1];
    const float* conv_w = (const float*)d_in[2];
    const float* conv_b = (const float*)d_in[3];
    const float* B_ssm = (const float*)d_in[4];
    const float* C_ssm = (const float*)d_in[5];
    const float* out_w = (const float*)d_in[6];
    const float* ln_g = (const float*)d_in[7];
    const float* ln_b = (const float*)d_in[8];
    const float* act_w1 = (const float*)d_in[9];
    const float* act_b1 = (const float*)d_in[10];
    const float* act_w2 = (const float*)d_in[11];
    const float* act_b2 = (const float*)d_in[12];
    const float* act_w3 = (const float*)d_in[13];
    const float* act_b3 = (const float*)d_in[14];
    const float* lang_w1 = (const float*)d_in[15];
    const float* lang_b1 = (const float*)d_in[16];
    const float* lang_w2 = (const float*)d_in[17];
    const float* lang_b2 = (const float*)d_in[18];

    static bool attr_done = false;
    if (!attr_done) {
        hipFuncSetAttribute((const void*)&g8_k<5>, hipFuncAttributeMaxDynamicSharedMemorySize, 131072);
        attr_done = true;
    }

    char* p = (char*)d_ws;
    size_t off = 0;
    auto alloc = [&](size_t bytes) -> void* {
        void* q = p + off;
        off = (off + bytes + 255) & ~(size_t)255;
        return q;
    };
    float* x_f  = (float*)alloc((size_t)TT * DD * 4);     // fp32 residual stream
    bf16*  x_b  = (bf16*) alloc((size_t)TT * DD * 2);     // bf16 mirror
    bf16*  xz   = (bf16*) alloc((size_t)TT * 4096 * 2);   // in_proj out (xp|z)
    bf16*  y    = (bf16*) alloc((size_t)TT * DDI * 2);    // gated SSM out
    float* u    = (float*)alloc((size_t)TT * 16 * 4);
    bf16*  hs   = (bf16*) alloc((size_t)TT * 32 * 2);     // scan out, K-padded
    bf16*  xn   = (bf16*) alloc((size_t)TT * DD * 2);
    bf16*  h1   = (bf16*) alloc((size_t)TT * 512 * 2);
    bf16*  h2   = (bf16*) alloc((size_t)TT * 256 * 2);
    bf16*  hl   = (bf16*) alloc((size_t)TT * DD * 2);
    bf16*  inwT = (bf16*) alloc((size_t)LL * 4096 * 1024 * 2);
    bf16*  owT  = (bf16*) alloc((size_t)LL * 1024 * 2048 * 2);
    bf16*  cmT  = (bf16*) alloc((size_t)LL * 2048 * 32 * 2);
    bf16*  a1T  = (bf16*) alloc((size_t)512 * 1024 * 2);
    bf16*  a2T  = (bf16*) alloc((size_t)256 * 512 * 2);
    bf16*  l1T  = (bf16*) alloc((size_t)1024 * 1024 * 2);
    bf16*  l2T  = (bf16*) alloc((size_t)VV * 1024 * 2);

    // ---- prep: fp32->bf16 + transpose all GEMM weights (per call) ----
    copyfeat_k<<<TT * DD / 1024, 256, 0, stream>>>(features, x_f, x_b);
    for (int l = 0; l < LL; ++l) {
        transpose_k<<<dim3(16, 64), 256, 0, stream>>>(in_proj_w + (size_t)l * 1024 * 4096,
                                                      inwT + (size_t)l * 4096 * 1024, 1024, 4096);
        transpose_k<<<dim3(32, 16), 256, 0, stream>>>(out_w + (size_t)l * 2048 * 1024,
                                                      owT + (size_t)l * 1024 * 2048, 2048, 1024);
        prep_cm_k<<<(2048 * 32) / 256, 256, 0, stream>>>(C_ssm + (size_t)l * 16 * 2048,
                                                         cmT + (size_t)l * 2048 * 32);
    }
    transpose_k<<<dim3(16, 8), 256, 0, stream>>>(act_w1, a1T, 1024, 512);
    transpose_k<<<dim3(8, 4), 256, 0, stream>>>(act_w2, a2T, 512, 256);
    transpose_k<<<dim3(16, 16), 256, 0, stream>>>(lang_w1, l1T, 1024, 1024);
    transpose_k<<<dim3(16, 500), 256, 0, stream>>>(lang_w2, l2T, 1024, VV);

    // ---- 6 mamba blocks ----
    for (int l = 0; l < LL; ++l) {
        // xz = x @ in_w
        gemm_k<0><<<dim3(32, 32), 256, 0, stream>>>(x_b, inwT + (size_t)l * 4096 * 1024,
                                                    1024, 4096, nullptr, xz, nullptr, nullptr, 0);
        // u = 0.1 * silu(conv(xp)+cb) @ Bm   (fused, replaces conv + skinny GEMM)
        convu_k<<<TT, 256, 0, stream>>>(xz, conv_w + (size_t)l * DDI * 4,
                                        conv_b + (size_t)l * DDI,
                                        B_ssm + (size_t)l * DDI * 16, u);
        // hs = scan(u)
        scan2_k<<<8, 256, 0, stream>>>(u, hs);
        // y = (hs @ Cm) * silu(z)
        gemm_k<2><<<dim3(32, 16), 256, 0, stream>>>(hs, cmT + (size_t)l * 2048 * 32,
                                                    32, 2048, nullptr, y, nullptr, xz + 2048, 4096);
        // x += y @ ow  (fp32 residual, refresh bf16 mirror)
        gemm_k<3><<<dim3(32, 8), 256, 0, stream>>>(y, owT + (size_t)l * 1024 * 2048,
                                                   2048, 1024, x_f, x_b, nullptr, nullptr, 0);
    }

    // ---- LN + heads ----
    ln_k<<<TT, 256, 0, stream>>>(x_f, ln_g, ln_b, xn);
    gemm_k<4><<<dim3(32, 4), 256, 0, stream>>>(xn, a1T, 1024, 512, nullptr, h1, act_b1, nullptr, 0);
    gemm_k<4><<<dim3(32, 2), 256, 0, stream>>>(h1, a2T, 512, 256, nullptr, h2, act_b2, nullptr, 0);
    act3_k<<<(TT * AA + 255) / 256, 256, 0, stream>>>(h2, act_w3, act_b3, (float*)d_out);
    gemm_k<4><<<dim3(32, 8), 256, 0, stream>>>(xn, l1T, 1024, 1024, nullptr, hl, lang_b1, nullptr, 0);
    // logits: g8 (measured 347us), 16 x 125 tiles of 256^2 -> 2000 blocks
    g8_k<5><<<2000, 512, 131072, stream>>>(hl, l2T, 1024, 16, VV,
                                           (float*)d_out + (size_t)TT * AA, nullptr, lang_b2);
}

// Round 9
// 1894.223 us; speedup vs baseline: 1.2541x; 1.2541x over previous
//
#include <hip/hip_runtime.h>
#include <hip/hip_bf16.h>
#include <cstdint>
#include <cstddef>

// Problem dims
#define TT 4096   // B*S tokens
#define SS 2048   // S
#define DD 1024   // D
#define DDI 2048  // DI
#define LL 6
#define VV 32000
#define AA 7

typedef __hip_bfloat16 bf16;
typedef __attribute__((ext_vector_type(8))) short bf16x8;   // 8 bf16 in 4 VGPRs
typedef __attribute__((ext_vector_type(4))) float f32x4;

typedef const __attribute__((address_space(1))) void* gas_ptr;
typedef __attribute__((address_space(3))) void* las_ptr;

static __device__ __forceinline__ float b2f(bf16 h) { return __bfloat162float(h); }
static __device__ __forceinline__ bf16 f2b(float f) { return __float2bfloat16(f); }

// 64-B rows, 4x16B chunks; chunk ^= (row>>1)&3 -> verified 0 conflicts (R4/R5).
#define SWZ(off) ((off) ^ ((((off) >> 7) & 3) << 4))

// ---------------------------------------------------------------------------
// g8 (measured 347us lang_w2 R5/R7; best in_proj class R3-R5): 256x256
// 8-phase GEMM, BK=64, 8 waves. Two 4-slot rings of 16 KiB K-half tiles;
// counted vmcnt(10); 0 bank conflicts.  EPI: 0 = store bf16; 5 = bias + f32.
// ---------------------------------------------------------------------------
template<int EPI>
__global__ __launch_bounds__(512, 2)
void g8_k(const bf16* __restrict__ A, const bf16* __restrict__ Wt,
          int K, int mx, int out_ld,
          float* __restrict__ of32, bf16* __restrict__ ob16,
          const float* __restrict__ bias)
{
    extern __shared__ char lds[];   // 131072
    const int nwg = gridDim.x;
    int l = blockIdx.x;
    if ((nwg & 7) == 0) l = (l & 7) * (nwg >> 3) + (l >> 3);   // XCD-chunked
    const int row0 = (l % mx) * 256, col0 = (l / mx) * 256;

    const int tid = threadIdx.x, wid = tid >> 6, lane = tid & 63;
    const int wr = wid >> 2, wc = wid & 3;        // 2M x 4N waves
    const int l15 = lane & 15, kq = lane >> 4;

    f32x4 acc[8][4];
#pragma unroll
    for (int m = 0; m < 8; ++m)
#pragma unroll
        for (int n = 0; n < 4; ++n) acc[m][n] = f32x4{0.f, 0.f, 0.f, 0.f};

    const int sr   = tid >> 2;
    const int colE = (((tid & 3) ^ ((tid >> 3) & 3)) * 8);
    const bf16* gA = A  + (size_t)(row0 + sr) * K + colE;
    const bf16* gB = Wt + (size_t)(col0 + sr) * K + colE;
    const int dst0 = tid * 16, dst1 = 8192 + tid * 16;

    auto stageA = [&](int kh) {
        char* b = lds + (kh & 3) * 16384;
        __builtin_amdgcn_global_load_lds((gas_ptr)(gA + kh * 32),                   (las_ptr)(b + dst0), 16, 0, 0);
        __builtin_amdgcn_global_load_lds((gas_ptr)(gA + (size_t)128 * K + kh * 32), (las_ptr)(b + dst1), 16, 0, 0);
    };
    auto stageB = [&](int kh) {
        char* b = lds + 65536 + (kh & 3) * 16384;
        __builtin_amdgcn_global_load_lds((gas_ptr)(gB + kh * 32),                   (las_ptr)(b + dst0), 16, 0, 0);
        __builtin_amdgcn_global_load_lds((gas_ptr)(gB + (size_t)128 * K + kh * 32), (las_ptr)(b + dst1), 16, 0, 0);
    };

    const int NT = K >> 6, KH = K >> 5;
    stageA(0); stageB(0); stageA(1); stageB(1);
    stageA(2); stageB(2); stageA(3); stageB(3);
    int nextA = 4, nextB = 4;

    for (int t = 0; t < NT; ++t) {
        const char* As0 = lds + ((2 * t) & 3) * 16384;
        const char* As1 = lds + ((2 * t + 1) & 3) * 16384;
        const char* Bs0 = lds + 65536 + ((2 * t) & 3) * 16384;
        const char* Bs1 = lds + 65536 + ((2 * t + 1) & 3) * 16384;
        bf16x8 af[4], bfg[4];

        // q0
        if (t < NT - 3) asm volatile("s_waitcnt vmcnt(10)" ::: "memory");
        else            asm volatile("s_waitcnt vmcnt(0)" ::: "memory");
        __builtin_amdgcn_sched_barrier(0);
        __builtin_amdgcn_s_barrier();
        __builtin_amdgcn_sched_barrier(0);
#pragma unroll
        for (int fn = 0; fn < 4; ++fn)
            bfg[fn] = *(const bf16x8*)(Bs0 + SWZ((wc * 64 + fn * 16 + l15) * 64 + kq * 16));
#pragma unroll
        for (int fm = 0; fm < 4; ++fm)
            af[fm] = *(const bf16x8*)(As0 + SWZ((wr * 128 + fm * 16 + l15) * 64 + kq * 16));
        if (t > 0 && nextA < KH) { stageA(nextA); ++nextA; }
        asm volatile("s_waitcnt lgkmcnt(0)" ::: "memory");
        __builtin_amdgcn_sched_barrier(0);
        __builtin_amdgcn_s_setprio(1);
#pragma unroll
        for (int fm = 0; fm < 4; ++fm)
#pragma unroll
            for (int fn = 0; fn < 4; ++fn)
                acc[fm][fn] = __builtin_amdgcn_mfma_f32_16x16x32_bf16(af[fm], bfg[fn], acc[fm][fn], 0, 0, 0);
        __builtin_amdgcn_s_setprio(0);
        __builtin_amdgcn_sched_barrier(0);
        __builtin_amdgcn_s_barrier();
        __builtin_amdgcn_sched_barrier(0);

        // q1 (A mh1 of ks0; B reg-reused)
#pragma unroll
        for (int fm = 0; fm < 4; ++fm)
            af[fm] = *(const bf16x8*)(As0 + SWZ((wr * 128 + 64 + fm * 16 + l15) * 64 + kq * 16));
        if (nextB < KH) { stageB(nextB); ++nextB; }
        asm volatile("s_waitcnt lgkmcnt(0)" ::: "memory");
        __builtin_amdgcn_sched_barrier(0);
        __builtin_amdgcn_s_setprio(1);
#pragma unroll
        for (int fm = 0; fm < 4; ++fm)
#pragma unroll
            for (int fn = 0; fn < 4; ++fn)
                acc[4 + fm][fn] = __builtin_amdgcn_mfma_f32_16x16x32_bf16(af[fm], bfg[fn], acc[4 + fm][fn], 0, 0, 0);
        __builtin_amdgcn_s_setprio(0);
        __builtin_amdgcn_sched_barrier(0);
        __builtin_amdgcn_s_barrier();
        __builtin_amdgcn_sched_barrier(0);

        // q2
        if (t < NT - 3) asm volatile("s_waitcnt vmcnt(10)" ::: "memory");
        else            asm volatile("s_waitcnt vmcnt(0)" ::: "memory");
        __builtin_amdgcn_sched_barrier(0);
        __builtin_amdgcn_s_barrier();
        __builtin_amdgcn_sched_barrier(0);
#pragma unroll
        for (int fn = 0; fn < 4; ++fn)
            bfg[fn] = *(const bf16x8*)(Bs1 + SWZ((wc * 64 + fn * 16 + l15) * 64 + kq * 16));
#pragma unroll
        for (int fm = 0; fm < 4; ++fm)
            af[fm] = *(const bf16x8*)(As1 + SWZ((wr * 128 + fm * 16 + l15) * 64 + kq * 16));
        if (nextA < KH) { stageA(nextA); ++nextA; }
        asm volatile("s_waitcnt lgkmcnt(0)" ::: "memory");
        __builtin_amdgcn_sched_barrier(0);
        __builtin_amdgcn_s_setprio(1);
#pragma unroll
        for (int fm = 0; fm < 4; ++fm)
#pragma unroll
            for (int fn = 0; fn < 4; ++fn)
                acc[fm][fn] = __builtin_amdgcn_mfma_f32_16x16x32_bf16(af[fm], bfg[fn], acc[fm][fn], 0, 0, 0);
        __builtin_amdgcn_s_setprio(0);
        __builtin_amdgcn_sched_barrier(0);
        __builtin_amdgcn_s_barrier();
        __builtin_amdgcn_sched_barrier(0);

        // q3 (A mh1 of ks1; B reg-reused)
#pragma unroll
        for (int fm = 0; fm < 4; ++fm)
            af[fm] = *(const bf16x8*)(As1 + SWZ((wr * 128 + 64 + fm * 16 + l15) * 64 + kq * 16));
        if (nextB < KH) { stageB(nextB); ++nextB; }
        asm volatile("s_waitcnt lgkmcnt(0)" ::: "memory");
        __builtin_amdgcn_sched_barrier(0);
        __builtin_amdgcn_s_setprio(1);
#pragma unroll
        for (int fm = 0; fm < 4; ++fm)
#pragma unroll
            for (int fn = 0; fn < 4; ++fn)
                acc[4 + fm][fn] = __builtin_amdgcn_mfma_f32_16x16x32_bf16(af[fm], bfg[fn], acc[4 + fm][fn], 0, 0, 0);
        __builtin_amdgcn_s_setprio(0);
        __builtin_amdgcn_sched_barrier(0);
        __builtin_amdgcn_s_barrier();
        __builtin_amdgcn_sched_barrier(0);
    }

#pragma unroll
    for (int fm = 0; fm < 8; ++fm) {
#pragma unroll
        for (int fn = 0; fn < 4; ++fn) {
#pragma unroll
            for (int r = 0; r < 4; ++r) {
                const int row = row0 + wr * 128 + fm * 16 + kq * 4 + r;
                const int col = col0 + wc * 64 + fn * 16 + l15;
                float v = acc[fm][fn][r];
                if (EPI == 0) ob16[(size_t)row * out_ld + col] = f2b(v);
                else          of32[(size_t)row * out_ld + col] = v + bias[col];
            }
        }
    }
}

// ---------------------------------------------------------------------------
// 128x128 m97-structure GEMM (R1 baseline kernel).
// EPI: 1=store f32 cols<z_ld(=ncap); 2=mul silu(z) store bf16;
//      3=residual f32 in/out + bf16 out; 4=bias+relu bf16
// ---------------------------------------------------------------------------
template<int EPI>
__global__ __launch_bounds__(256)
void gemm_k(const bf16* __restrict__ A, const bf16* __restrict__ Wt,
            int K, int out_ld,
            float* __restrict__ of32, bf16* __restrict__ ob16,
            const float* __restrict__ bias,
            const bf16* __restrict__ zp, int z_ld)
{
    __shared__ bf16x8 lsA8[128 * 4];
    __shared__ bf16x8 lsB8[128 * 4];
    bf16* lsA = (bf16*)lsA8;
    bf16* lsB = (bf16*)lsB8;

    const int tid  = threadIdx.x;
    const int w    = tid >> 6;
    const int lane = tid & 63;
    const int row0 = blockIdx.x * 128;
    const int col0 = blockIdx.y * 128;
    const int wr   = (w >> 1) * 64;
    const int wc   = (w & 1) * 64;
    const int l15  = lane & 15;
    const int kq   = lane >> 4;

    f32x4 acc[4][4];
#pragma unroll
    for (int m = 0; m < 4; ++m)
#pragma unroll
        for (int n = 0; n < 4; ++n) acc[m][n] = f32x4{0.f, 0.f, 0.f, 0.f};

    const int s0 = tid, s1 = tid + 256;
    const size_t ga0 = (size_t)(row0 + (s0 >> 2)) * K + (s0 & 3) * 8;
    const size_t ga1 = (size_t)(row0 + (s1 >> 2)) * K + (s1 & 3) * 8;
    const size_t gb0 = (size_t)(col0 + (s0 >> 2)) * K + (s0 & 3) * 8;
    const size_t gb1 = (size_t)(col0 + (s1 >> 2)) * K + (s1 & 3) * 8;
    bf16* la0 = lsA + (size_t)(w * 64) * 8;
    bf16* la1 = lsA + (size_t)(256 + w * 64) * 8;
    bf16* lb0 = lsB + (size_t)(w * 64) * 8;
    bf16* lb1 = lsB + (size_t)(256 + w * 64) * 8;

    for (int k0 = 0; k0 < K; k0 += 32) {
        __builtin_amdgcn_global_load_lds((gas_ptr)(A  + ga0 + k0), (las_ptr)la0, 16, 0, 0);
        __builtin_amdgcn_global_load_lds((gas_ptr)(A  + ga1 + k0), (las_ptr)la1, 16, 0, 0);
        __builtin_amdgcn_global_load_lds((gas_ptr)(Wt + gb0 + k0), (las_ptr)lb0, 16, 0, 0);
        __builtin_amdgcn_global_load_lds((gas_ptr)(Wt + gb1 + k0), (las_ptr)lb1, 16, 0, 0);
        __syncthreads();

        bf16x8 af[4], bfr[4];
#pragma unroll
        for (int m = 0; m < 4; ++m)
            af[m] = *(const bf16x8*)(lsA + (size_t)(wr + m * 16 + l15) * 32 + kq * 8);
#pragma unroll
        for (int n = 0; n < 4; ++n)
            bfr[n] = *(const bf16x8*)(lsB + (size_t)(wc + n * 16 + l15) * 32 + kq * 8);
#pragma unroll
        for (int m = 0; m < 4; ++m)
#pragma unroll
            for (int n = 0; n < 4; ++n)
                acc[m][n] = __builtin_amdgcn_mfma_f32_16x16x32_bf16(af[m], bfr[n], acc[m][n], 0, 0, 0);
        __syncthreads();
    }

#pragma unroll
    for (int m = 0; m < 4; ++m) {
#pragma unroll
        for (int n = 0; n < 4; ++n) {
#pragma unroll
            for (int r = 0; r < 4; ++r) {
                const int row = row0 + wr + m * 16 + kq * 4 + r;
                const int col = col0 + wc + n * 16 + l15;
                float v = acc[m][n][r];
                if (EPI == 1) {
                    if (col < z_ld) of32[(size_t)row * out_ld + col] = v;
                } else if (EPI == 2) {
                    float zf = b2f(zp[(size_t)row * z_ld + col]);
                    v *= zf / (1.f + expf(-zf));
                    ob16[(size_t)row * out_ld + col] = f2b(v);
                } else if (EPI == 3) {
                    float rr = of32[(size_t)row * out_ld + col] + v;
                    of32[(size_t)row * out_ld + col] = rr;
                    ob16[(size_t)row * out_ld + col] = f2b(rr);
                } else if (EPI == 4) {
                    v = fmaxf(v + bias[col], 0.f);
                    ob16[(size_t)row * out_ld + col] = f2b(v);
                }
            }
        }
    }
}

// ---------------------------------------------------------------------------
// fp32 [K,N] -> bf16 [N,K] transpose (64x64 tiles through LDS)
// ---------------------------------------------------------------------------
__global__ __launch_bounds__(256)
void transpose_k(const float* __restrict__ W, bf16* __restrict__ WT, int K, int N)
{
    __shared__ bf16 t[64][66];
    const int k0 = blockIdx.x * 64, n0 = blockIdx.y * 64;
    const int tid = threadIdx.x;
#pragma unroll
    for (int i = 0; i < 16; ++i) {
        int idx = i * 256 + tid;
        int kk = idx >> 6, nn = idx & 63;
        t[nn][kk] = f2b(W[(size_t)(k0 + kk) * N + n0 + nn]);
    }
    __syncthreads();
#pragma unroll
    for (int i = 0; i < 16; ++i) {
        int idx = i * 256 + tid;
        int nn = idx >> 6, kk = idx & 63;
        WT[(size_t)(n0 + nn) * K + k0 + kk] = t[nn][kk];
    }
}

// B_ssm [DI,16] fp32 -> bf16 [128,DI] padded, x0.1 folded in
__global__ void prep_bm_k(const float* __restrict__ Bm, bf16* __restrict__ BmT)
{
    int idx = blockIdx.x * 256 + threadIdx.x;   // 128*2048
    int n = idx >> 11, k = idx & 2047;
    float v = (n < 16) ? Bm[(size_t)k * 16 + n] * 0.1f : 0.f;
    BmT[idx] = f2b(v);
}

// C_ssm [16,DI] fp32 -> bf16 [DI,32] padded (K padded 16->32)
__global__ void prep_cm_k(const float* __restrict__ Cm, bf16* __restrict__ CmT)
{
    int idx = blockIdx.x * 256 + threadIdx.x;   // 2048*32
    int i = idx >> 5, k = idx & 31;
    float v = (k < 16) ? Cm[(size_t)k * 2048 + i] : 0.f;
    CmT[idx] = f2b(v);
}

// features -> fp32 residual copy + bf16 copy
__global__ void copyfeat_k(const float* __restrict__ f, float* __restrict__ xf,
                           bf16* __restrict__ xb)
{
    int i = (blockIdx.x * 256 + threadIdx.x) * 4;
    float4 v = *(const float4*)(f + i);
    *(float4*)(xf + i) = v;
    xb[i + 0] = f2b(v.x);
    xb[i + 1] = f2b(v.y);
    xb[i + 2] = f2b(v.z);
    xb[i + 3] = f2b(v.w);
}

// causal depthwise conv (K=4) + bias + silu; xp = first DI cols of xz[T,4096]
__global__ void conv_k(const bf16* __restrict__ xz, const float* __restrict__ cw,
                       const float* __restrict__ cb, bf16* __restrict__ xc)
{
    int idx = blockIdx.x * 256 + threadIdx.x;   // T*DI
    int t = idx >> 11, i = idx & 2047;
    int s = t & (SS - 1);
    float4 wv = *(const float4*)(cw + i * 4);
    float acc = cb[i];
    const bf16* base = xz + (size_t)t * 4096 + i;
    if (s >= 3) {
        acc = fmaf(b2f(base[-3 * 4096]), wv.x, acc);
        acc = fmaf(b2f(base[-2 * 4096]), wv.y, acc);
        acc = fmaf(b2f(base[-1 * 4096]), wv.z, acc);
    } else {
        if (s >= 2) acc = fmaf(b2f(base[-2 * 4096]), wv.y, acc);
        if (s >= 1) acc = fmaf(b2f(base[-1 * 4096]), wv.z, acc);
    }
    acc = fmaf(b2f(base[0]), wv.w, acc);
    float sig = 1.f / (1.f + expf(-acc));
    xc[idx] = f2b(acc * sig);
}

// ---------------------------------------------------------------------------
// scan h_t = 0.9 h + u_t; chunk=32 tokens, redundant 96-step warmup;
// writes hs [T,32] bf16 with cols 16..31 zeroed (K-pad for the Cm GEMM).
// ---------------------------------------------------------------------------
__global__ void scan2_k(const float* __restrict__ u, bf16* __restrict__ hs)
{
    int gid = blockIdx.x * 256 + threadIdx.x;   // 2048 total
    int n = gid & 15, c = (gid >> 4) & 63, b = gid >> 10;
    int start = c * 32;
    const float* ub = u + (size_t)b * SS * 16;
    bf16* hb = hs + (size_t)b * SS * 32;
    float h = 0.f;
    int w0 = start - 96; if (w0 < 0) w0 = 0;
    for (int t = w0; t < start; ++t) h = 0.9f * h + ub[(size_t)t * 16 + n];
    const bf16 zero = f2b(0.f);
    for (int t = start; t < start + 32; ++t) {
        h = 0.9f * h + ub[(size_t)t * 16 + n];
        hb[(size_t)t * 32 + n] = f2b(h);
        hb[(size_t)t * 32 + 16 + n] = zero;
    }
}

// LayerNorm fp32 -> bf16
__global__ __launch_bounds__(256)
void ln_k(const float* __restrict__ x, const float* __restrict__ g,
          const float* __restrict__ bb, bf16* __restrict__ xn)
{
    int t = blockIdx.x, tid = threadIdx.x;
    const float* xr = x + (size_t)t * DD;
    float4 v = *(const float4*)(xr + tid * 4);
    float s = v.x + v.y + v.z + v.w;
#pragma unroll
    for (int o = 32; o > 0; o >>= 1) s += __shfl_down(s, o, 64);
    __shared__ float r1[4], r2[4];
    if ((tid & 63) == 0) r1[tid >> 6] = s;
    __syncthreads();
    float mu = (r1[0] + r1[1] + r1[2] + r1[3]) * (1.f / DD);
    float d0 = v.x - mu, d1 = v.y - mu, d2 = v.z - mu, d3 = v.w - mu;
    float ss = d0 * d0 + d1 * d1 + d2 * d2 + d3 * d3;
#pragma unroll
    for (int o = 32; o > 0; o >>= 1) ss += __shfl_down(ss, o, 64);
    if ((tid & 63) == 0) r2[tid >> 6] = ss;
    __syncthreads();
    float var = (r2[0] + r2[1] + r2[2] + r2[3]) * (1.f / DD);
    float inv = rsqrtf(var + 1e-5f);
    int di = tid * 4;
    xn[(size_t)t * DD + di + 0] = f2b(d0 * inv * g[di + 0] + bb[di + 0]);
    xn[(size_t)t * DD + di + 1] = f2b(d1 * inv * g[di + 1] + bb[di + 1]);
    xn[(size_t)t * DD + di + 2] = f2b(d2 * inv * g[di + 2] + bb[di + 2]);
    xn[(size_t)t * DD + di + 3] = f2b(d3 * inv * g[di + 3] + bb[di + 3]);
}

// tiny head: actions = tanh(h2 @ w3 + b3)
__global__ void act3_k(const bf16* __restrict__ h2, const float* __restrict__ w3,
                       const float* __restrict__ b3, float* __restrict__ out)
{
    int idx = blockIdx.x * 256 + threadIdx.x;
    if (idx >= TT * AA) return;
    int t = idx / AA, a = idx - t * AA;
    float acc = b3[a];
    const bf16* hr = h2 + (size_t)t * 256;
    for (int k = 0; k < 256; ++k)
        acc = fmaf(b2f(hr[k]), w3[k * AA + a], acc);
    out[idx] = tanhf(acc);
}

// ---------------------------------------------------------------------------
extern "C" void kernel_launch(void* const* d_in, const int* in_sizes, int n_in,
                              void* d_out, int out_size, void* d_ws, size_t ws_size,
                              hipStream_t stream)
{
    (void)in_sizes; (void)n_in; (void)out_size; (void)ws_size;
    const float* features = (const float*)d_in[0];
    const float* in_proj_w = (const float*)d_in[1];
    const float* conv_w = (const float*)d_in[2];
    const float* conv_b = (const float*)d_in[3];
    const float* B_ssm = (const float*)d_in[4];
    const float* C_ssm = (const float*)d_in[5];
    const float* out_w = (const float*)d_in[6];
    const float* ln_g = (const float*)d_in[7];
    const float* ln_b = (const float*)d_in[8];
    const float* act_w1 = (const float*)d_in[9];
    const float* act_b1 = (const float*)d_in[10];
    const float* act_w2 = (const float*)d_in[11];
    const float* act_b2 = (const float*)d_in[12];
    const float* act_w3 = (const float*)d_in[13];
    const float* act_b3 = (const float*)d_in[14];
    const float* lang_w1 = (const float*)d_in[15];
    const float* lang_b1 = (const float*)d_in[16];
    const float* lang_w2 = (const float*)d_in[17];
    const float* lang_b2 = (const float*)d_in[18];

    static bool attr_done = false;
    if (!attr_done) {
        hipFuncSetAttribute((const void*)&g8_k<0>, hipFuncAttributeMaxDynamicSharedMemorySize, 131072);
        hipFuncSetAttribute((const void*)&g8_k<5>, hipFuncAttributeMaxDynamicSharedMemorySize, 131072);
        attr_done = true;
    }

    char* p = (char*)d_ws;
    size_t off = 0;
    auto alloc = [&](size_t bytes) -> void* {
        void* q = p + off;
        off = (off + bytes + 255) & ~(size_t)255;
        return q;
    };
    float* x_f  = (float*)alloc((size_t)TT * DD * 4);     // fp32 residual stream
    bf16*  x_b  = (bf16*) alloc((size_t)TT * DD * 2);     // bf16 mirror
    bf16*  xz   = (bf16*) alloc((size_t)TT * 4096 * 2);   // in_proj out (xp|z)
    bf16*  xc   = (bf16*) alloc((size_t)TT * DDI * 2);    // conv out; later reused as y
    float* u    = (float*)alloc((size_t)TT * 16 * 4);
    bf16*  hs   = (bf16*) alloc((size_t)TT * 32 * 2);     // scan out, K-padded
    bf16*  xn   = (bf16*) alloc((size_t)TT * DD * 2);
    bf16*  h1   = (bf16*) alloc((size_t)TT * 512 * 2);
    bf16*  h2   = (bf16*) alloc((size_t)TT * 256 * 2);
    bf16*  hl   = (bf16*) alloc((size_t)TT * DD * 2);
    bf16*  inwT = (bf16*) alloc((size_t)LL * 4096 * 1024 * 2);
    bf16*  owT  = (bf16*) alloc((size_t)LL * 1024 * 2048 * 2);
    bf16*  bmT  = (bf16*) alloc((size_t)LL * 128 * 2048 * 2);
    bf16*  cmT  = (bf16*) alloc((size_t)LL * 2048 * 32 * 2);
    bf16*  a1T  = (bf16*) alloc((size_t)512 * 1024 * 2);
    bf16*  a2T  = (bf16*) alloc((size_t)256 * 512 * 2);
    bf16*  l1T  = (bf16*) alloc((size_t)1024 * 1024 * 2);
    bf16*  l2T  = (bf16*) alloc((size_t)VV * 1024 * 2);
    bf16*  y    = xc;   // xc dead once u is computed

    // ---- prep: fp32->bf16 + transpose all GEMM weights (per call) ----
    copyfeat_k<<<TT * DD / 1024, 256, 0, stream>>>(features, x_f, x_b);
    for (int l = 0; l < LL; ++l) {
        transpose_k<<<dim3(16, 64), 256, 0, stream>>>(in_proj_w + (size_t)l * 1024 * 4096,
                                                      inwT + (size_t)l * 4096 * 1024, 1024, 4096);
        transpose_k<<<dim3(32, 16), 256, 0, stream>>>(out_w + (size_t)l * 2048 * 1024,
                                                      owT + (size_t)l * 1024 * 2048, 2048, 1024);
        prep_bm_k<<<(128 * 2048) / 256, 256, 0, stream>>>(B_ssm + (size_t)l * 2048 * 16,
                                                          bmT + (size_t)l * 128 * 2048);
        prep_cm_k<<<(2048 * 32) / 256, 256, 0, stream>>>(C_ssm + (size_t)l * 16 * 2048,
                                                         cmT + (size_t)l * 2048 * 32);
    }
    transpose_k<<<dim3(16, 8), 256, 0, stream>>>(act_w1, a1T, 1024, 512);
    transpose_k<<<dim3(8, 4), 256, 0, stream>>>(act_w2, a2T, 512, 256);
    transpose_k<<<dim3(16, 16), 256, 0, stream>>>(lang_w1, l1T, 1024, 1024);
    transpose_k<<<dim3(16, 500), 256, 0, stream>>>(lang_w2, l2T, 1024, VV);

    // ---- 6 mamba blocks (R7 composition, in_proj -> g8) ----
    for (int l = 0; l < LL; ++l) {
        // xz = x @ in_w : g8, 16x16 tiles of 256^2 -> 256 blocks
        g8_k<0><<<256, 512, 131072, stream>>>(x_b, inwT + (size_t)l * 4096 * 1024,
                                              1024, 16, 4096, nullptr, xz, nullptr);
        // xc = silu(causal_dwconv(xp) + cb)
        conv_k<<<TT * DDI / 256, 256, 0, stream>>>(xz, conv_w + (size_t)l * DDI * 4,
                                                   conv_b + (size_t)l * DDI, xc);
        // u = xc @ (Bm*0.1)  (N padded to 128, store cols<16)
        gemm_k<1><<<dim3(32, 1), 256, 0, stream>>>(xc, bmT + (size_t)l * 128 * 2048,
                                                   2048, 16, u, nullptr, nullptr, nullptr, 16);
        // hs = scan(u)
        scan2_k<<<8, 256, 0, stream>>>(u, hs);
        // y = (hs @ Cm) * silu(z)
        gemm_k<2><<<dim3(32, 16), 256, 0, stream>>>(hs, cmT + (size_t)l * 2048 * 32,
                                                    32, 2048, nullptr, y, nullptr, xz + 2048, 4096);
        // x += y @ ow  (fp32 residual, refresh bf16 mirror)
        gemm_k<3><<<dim3(32, 8), 256, 0, stream>>>(y, owT + (size_t)l * 1024 * 2048,
                                                   2048, 1024, x_f, x_b, nullptr, nullptr, 0);
    }

    // ---- LN + heads ----
    ln_k<<<TT, 256, 0, stream>>>(x_f, ln_g, ln_b, xn);
    gemm_k<4><<<dim3(32, 4), 256, 0, stream>>>(xn, a1T, 1024, 512, nullptr, h1, act_b1, nullptr, 0);
    gemm_k<4><<<dim3(32, 2), 256, 0, stream>>>(h1, a2T, 512, 256, nullptr, h2, act_b2, nullptr, 0);
    act3_k<<<(TT * AA + 255) / 256, 256, 0, stream>>>(h2, act_w3, act_b3, (float*)d_out);
    gemm_k<4><<<dim3(32, 8), 256, 0, stream>>>(xn, l1T, 1024, 1024, nullptr, hl, lang_b1, nullptr, 0);
    // logits: g8 (measured ~348us), 16 x 125 tiles of 256^2 -> 2000 blocks
    g8_k<5><<<2000, 512, 131072, stream>>>(hl, l2T, 1024, 16, VV,
                                           (float*)d_out + (size_t)TT * AA, nullptr, lang_b2);
}

// Round 10
// 1646.348 us; speedup vs baseline: 1.4429x; 1.1506x over previous
//
#include <hip/hip_runtime.h>
#include <hip/hip_bf16.h>
#include <cstdint>
#include <cstddef>

// Problem dims
#define TT 4096   // B*S tokens
#define SS 2048   // S
#define DD 1024   // D
#define DDI 2048  // DI
#define LL 6
#define VV 32000
#define AA 7

typedef __hip_bfloat16 bf16;
typedef __attribute__((ext_vector_type(8))) short bf16x8;   // 8 bf16 in 4 VGPRs
typedef __attribute__((ext_vector_type(4))) float f32x4;

typedef const __attribute__((address_space(1))) void* gas_ptr;
typedef __attribute__((address_space(3))) void* las_ptr;

static __device__ __forceinline__ float b2f(bf16 h) { return __bfloat162float(h); }
static __device__ __forceinline__ bf16 f2b(float f) { return __float2bfloat16(f); }

// 64-B rows, 4x16B chunks; chunk ^= (row>>1)&3 -> verified 0 conflicts (R4/R5).
#define SWZ(off) ((off) ^ ((((off) >> 7) & 3) << 4))

// ---------------------------------------------------------------------------
// g8 (measured ~350us lang_w2; best in_proj class): 256x256 8-phase GEMM,
// BK=64, 8 waves. Two 4-slot rings of 16 KiB K-half tiles; counted vmcnt(10);
// 0 bank conflicts.  EPI: 0 = store bf16; 5 = bias + f32 store.
// ---------------------------------------------------------------------------
template<int EPI>
__global__ __launch_bounds__(512, 2)
void g8_k(const bf16* __restrict__ A, const bf16* __restrict__ Wt,
          int K, int mx, int out_ld,
          float* __restrict__ of32, bf16* __restrict__ ob16,
          const float* __restrict__ bias)
{
    extern __shared__ char lds[];   // 131072
    const int nwg = gridDim.x;
    int l = blockIdx.x;
    if ((nwg & 7) == 0) l = (l & 7) * (nwg >> 3) + (l >> 3);   // XCD-chunked
    const int row0 = (l % mx) * 256, col0 = (l / mx) * 256;

    const int tid = threadIdx.x, wid = tid >> 6, lane = tid & 63;
    const int wr = wid >> 2, wc = wid & 3;        // 2M x 4N waves
    const int l15 = lane & 15, kq = lane >> 4;

    f32x4 acc[8][4];
#pragma unroll
    for (int m = 0; m < 8; ++m)
#pragma unroll
        for (int n = 0; n < 4; ++n) acc[m][n] = f32x4{0.f, 0.f, 0.f, 0.f};

    const int sr   = tid >> 2;
    const int colE = (((tid & 3) ^ ((tid >> 3) & 3)) * 8);
    const bf16* gA = A  + (size_t)(row0 + sr) * K + colE;
    const bf16* gB = Wt + (size_t)(col0 + sr) * K + colE;
    const int dst0 = tid * 16, dst1 = 8192 + tid * 16;

    auto stageA = [&](int kh) {
        char* b = lds + (kh & 3) * 16384;
        __builtin_amdgcn_global_load_lds((gas_ptr)(gA + kh * 32),                   (las_ptr)(b + dst0), 16, 0, 0);
        __builtin_amdgcn_global_load_lds((gas_ptr)(gA + (size_t)128 * K + kh * 32), (las_ptr)(b + dst1), 16, 0, 0);
    };
    auto stageB = [&](int kh) {
        char* b = lds + 65536 + (kh & 3) * 16384;
        __builtin_amdgcn_global_load_lds((gas_ptr)(gB + kh * 32),                   (las_ptr)(b + dst0), 16, 0, 0);
        __builtin_amdgcn_global_load_lds((gas_ptr)(gB + (size_t)128 * K + kh * 32), (las_ptr)(b + dst1), 16, 0, 0);
    };

    const int NT = K >> 6, KH = K >> 5;
    stageA(0); stageB(0); stageA(1); stageB(1);
    stageA(2); stageB(2); stageA(3); stageB(3);
    int nextA = 4, nextB = 4;

    for (int t = 0; t < NT; ++t) {
        const char* As0 = lds + ((2 * t) & 3) * 16384;
        const char* As1 = lds + ((2 * t + 1) & 3) * 16384;
        const char* Bs0 = lds + 65536 + ((2 * t) & 3) * 16384;
        const char* Bs1 = lds + 65536 + ((2 * t + 1) & 3) * 16384;
        bf16x8 af[4], bfg[4];

        // q0
        if (t < NT - 3) asm volatile("s_waitcnt vmcnt(10)" ::: "memory");
        else            asm volatile("s_waitcnt vmcnt(0)" ::: "memory");
        __builtin_amdgcn_sched_barrier(0);
        __builtin_amdgcn_s_barrier();
        __builtin_amdgcn_sched_barrier(0);
#pragma unroll
        for (int fn = 0; fn < 4; ++fn)
            bfg[fn] = *(const bf16x8*)(Bs0 + SWZ((wc * 64 + fn * 16 + l15) * 64 + kq * 16));
#pragma unroll
        for (int fm = 0; fm < 4; ++fm)
            af[fm] = *(const bf16x8*)(As0 + SWZ((wr * 128 + fm * 16 + l15) * 64 + kq * 16));
        if (t > 0 && nextA < KH) { stageA(nextA); ++nextA; }
        asm volatile("s_waitcnt lgkmcnt(0)" ::: "memory");
        __builtin_amdgcn_sched_barrier(0);
        __builtin_amdgcn_s_setprio(1);
#pragma unroll
        for (int fm = 0; fm < 4; ++fm)
#pragma unroll
            for (int fn = 0; fn < 4; ++fn)
                acc[fm][fn] = __builtin_amdgcn_mfma_f32_16x16x32_bf16(af[fm], bfg[fn], acc[fm][fn], 0, 0, 0);
        __builtin_amdgcn_s_setprio(0);
        __builtin_amdgcn_sched_barrier(0);
        __builtin_amdgcn_s_barrier();
        __builtin_amdgcn_sched_barrier(0);

        // q1 (A mh1 of ks0; B reg-reused)
#pragma unroll
        for (int fm = 0; fm < 4; ++fm)
            af[fm] = *(const bf16x8*)(As0 + SWZ((wr * 128 + 64 + fm * 16 + l15) * 64 + kq * 16));
        if (nextB < KH) { stageB(nextB); ++nextB; }
        asm volatile("s_waitcnt lgkmcnt(0)" ::: "memory");
        __builtin_amdgcn_sched_barrier(0);
        __builtin_amdgcn_s_setprio(1);
#pragma unroll
        for (int fm = 0; fm < 4; ++fm)
#pragma unroll
            for (int fn = 0; fn < 4; ++fn)
                acc[4 + fm][fn] = __builtin_amdgcn_mfma_f32_16x16x32_bf16(af[fm], bfg[fn], acc[4 + fm][fn], 0, 0, 0);
        __builtin_amdgcn_s_setprio(0);
        __builtin_amdgcn_sched_barrier(0);
        __builtin_amdgcn_s_barrier();
        __builtin_amdgcn_sched_barrier(0);

        // q2
        if (t < NT - 3) asm volatile("s_waitcnt vmcnt(10)" ::: "memory");
        else            asm volatile("s_waitcnt vmcnt(0)" ::: "memory");
        __builtin_amdgcn_sched_barrier(0);
        __builtin_amdgcn_s_barrier();
        __builtin_amdgcn_sched_barrier(0);
#pragma unroll
        for (int fn = 0; fn < 4; ++fn)
            bfg[fn] = *(const bf16x8*)(Bs1 + SWZ((wc * 64 + fn * 16 + l15) * 64 + kq * 16));
#pragma unroll
        for (int fm = 0; fm < 4; ++fm)
            af[fm] = *(const bf16x8*)(As1 + SWZ((wr * 128 + fm * 16 + l15) * 64 + kq * 16));
        if (nextA < KH) { stageA(nextA); ++nextA; }
        asm volatile("s_waitcnt lgkmcnt(0)" ::: "memory");
        __builtin_amdgcn_sched_barrier(0);
        __builtin_amdgcn_s_setprio(1);
#pragma unroll
        for (int fm = 0; fm < 4; ++fm)
#pragma unroll
            for (int fn = 0; fn < 4; ++fn)
                acc[fm][fn] = __builtin_amdgcn_mfma_f32_16x16x32_bf16(af[fm], bfg[fn], acc[fm][fn], 0, 0, 0);
        __builtin_amdgcn_s_setprio(0);
        __builtin_amdgcn_sched_barrier(0);
        __builtin_amdgcn_s_barrier();
        __builtin_amdgcn_sched_barrier(0);

        // q3 (A mh1 of ks1; B reg-reused)
#pragma unroll
        for (int fm = 0; fm < 4; ++fm)
            af[fm] = *(const bf16x8*)(As1 + SWZ((wr * 128 + 64 + fm * 16 + l15) * 64 + kq * 16));
        if (nextB < KH) { stageB(nextB); ++nextB; }
        asm volatile("s_waitcnt lgkmcnt(0)" ::: "memory");
        __builtin_amdgcn_sched_barrier(0);
        __builtin_amdgcn_s_setprio(1);
#pragma unroll
        for (int fm = 0; fm < 4; ++fm)
#pragma unroll
            for (int fn = 0; fn < 4; ++fn)
                acc[4 + fm][fn] = __builtin_amdgcn_mfma_f32_16x16x32_bf16(af[fm], bfg[fn], acc[4 + fm][fn], 0, 0, 0);
        __builtin_amdgcn_s_setprio(0);
        __builtin_amdgcn_sched_barrier(0);
        __builtin_amdgcn_s_barrier();
        __builtin_amdgcn_sched_barrier(0);
    }

#pragma unroll
    for (int fm = 0; fm < 8; ++fm) {
#pragma unroll
        for (int fn = 0; fn < 4; ++fn) {
#pragma unroll
            for (int r = 0; r < 4; ++r) {
                const int row = row0 + wr * 128 + fm * 16 + kq * 4 + r;
                const int col = col0 + wc * 64 + fn * 16 + l15;
                float v = acc[fm][fn][r];
                if (EPI == 0) ob16[(size_t)row * out_ld + col] = f2b(v);
                else          of32[(size_t)row * out_ld + col] = v + bias[col];
            }
        }
    }
}

// ---------------------------------------------------------------------------
// 128x128 m97-structure GEMM (R1 baseline kernel).
// EPI: 2=mul silu(z) store bf16; 3=residual f32 in/out + bf16 out; 4=bias+relu
// ---------------------------------------------------------------------------
template<int EPI>
__global__ __launch_bounds__(256)
void gemm_k(const bf16* __restrict__ A, const bf16* __restrict__ Wt,
            int K, int out_ld,
            float* __restrict__ of32, bf16* __restrict__ ob16,
            const float* __restrict__ bias,
            const bf16* __restrict__ zp, int z_ld)
{
    __shared__ bf16x8 lsA8[128 * 4];
    __shared__ bf16x8 lsB8[128 * 4];
    bf16* lsA = (bf16*)lsA8;
    bf16* lsB = (bf16*)lsB8;

    const int tid  = threadIdx.x;
    const int w    = tid >> 6;
    const int lane = tid & 63;
    const int row0 = blockIdx.x * 128;
    const int col0 = blockIdx.y * 128;
    const int wr   = (w >> 1) * 64;
    const int wc   = (w & 1) * 64;
    const int l15  = lane & 15;
    const int kq   = lane >> 4;

    f32x4 acc[4][4];
#pragma unroll
    for (int m = 0; m < 4; ++m)
#pragma unroll
        for (int n = 0; n < 4; ++n) acc[m][n] = f32x4{0.f, 0.f, 0.f, 0.f};

    const int s0 = tid, s1 = tid + 256;
    const size_t ga0 = (size_t)(row0 + (s0 >> 2)) * K + (s0 & 3) * 8;
    const size_t ga1 = (size_t)(row0 + (s1 >> 2)) * K + (s1 & 3) * 8;
    const size_t gb0 = (size_t)(col0 + (s0 >> 2)) * K + (s0 & 3) * 8;
    const size_t gb1 = (size_t)(col0 + (s1 >> 2)) * K + (s1 & 3) * 8;
    bf16* la0 = lsA + (size_t)(w * 64) * 8;
    bf16* la1 = lsA + (size_t)(256 + w * 64) * 8;
    bf16* lb0 = lsB + (size_t)(w * 64) * 8;
    bf16* lb1 = lsB + (size_t)(256 + w * 64) * 8;

    for (int k0 = 0; k0 < K; k0 += 32) {
        __builtin_amdgcn_global_load_lds((gas_ptr)(A  + ga0 + k0), (las_ptr)la0, 16, 0, 0);
        __builtin_amdgcn_global_load_lds((gas_ptr)(A  + ga1 + k0), (las_ptr)la1, 16, 0, 0);
        __builtin_amdgcn_global_load_lds((gas_ptr)(Wt + gb0 + k0), (las_ptr)lb0, 16, 0, 0);
        __builtin_amdgcn_global_load_lds((gas_ptr)(Wt + gb1 + k0), (las_ptr)lb1, 16, 0, 0);
        __syncthreads();

        bf16x8 af[4], bfr[4];
#pragma unroll
        for (int m = 0; m < 4; ++m)
            af[m] = *(const bf16x8*)(lsA + (size_t)(wr + m * 16 + l15) * 32 + kq * 8);
#pragma unroll
        for (int n = 0; n < 4; ++n)
            bfr[n] = *(const bf16x8*)(lsB + (size_t)(wc + n * 16 + l15) * 32 + kq * 8);
#pragma unroll
        for (int m = 0; m < 4; ++m)
#pragma unroll
            for (int n = 0; n < 4; ++n)
                acc[m][n] = __builtin_amdgcn_mfma_f32_16x16x32_bf16(af[m], bfr[n], acc[m][n], 0, 0, 0);
        __syncthreads();
    }

#pragma unroll
    for (int m = 0; m < 4; ++m) {
#pragma unroll
        for (int n = 0; n < 4; ++n) {
#pragma unroll
            for (int r = 0; r < 4; ++r) {
                const int row = row0 + wr + m * 16 + kq * 4 + r;
                const int col = col0 + wc + n * 16 + l15;
                float v = acc[m][n][r];
                if (EPI == 2) {
                    float zf = b2f(zp[(size_t)row * z_ld + col]);
                    v *= zf / (1.f + expf(-zf));
                    ob16[(size_t)row * out_ld + col] = f2b(v);
                } else if (EPI == 3) {
                    float rr = of32[(size_t)row * out_ld + col] + v;
                    of32[(size_t)row * out_ld + col] = rr;
                    ob16[(size_t)row * out_ld + col] = f2b(rr);
                } else if (EPI == 4) {
                    v = fmaxf(v + bias[col], 0.f);
                    ob16[(size_t)row * out_ld + col] = f2b(v);
                }
            }
        }
    }
}

// ---------------------------------------------------------------------------
// Split-K skinny u-GEMM: up[split][T][16] = xc[T, ksplit] @ Bm[ksplit, 16]
// grid (32, 8): 128-row M-tiles x 8 K-splits of 256. Same MFMA structure as
// gemm_k, N-tile = 128 (Bm padded), only cols<16 stored. Deterministic.
// ---------------------------------------------------------------------------
__global__ __launch_bounds__(256)
void usk_k(const bf16* __restrict__ A, const bf16* __restrict__ Wt,
           float* __restrict__ up)
{
    __shared__ bf16x8 lsA8[128 * 4];
    __shared__ bf16x8 lsB8[128 * 4];
    bf16* lsA = (bf16*)lsA8;
    bf16* lsB = (bf16*)lsB8;
    const int K = 2048;

    const int tid  = threadIdx.x;
    const int w    = tid >> 6;
    const int lane = tid & 63;
    const int row0 = blockIdx.x * 128;
    const int spl  = blockIdx.y;          // 0..7
    const int kbeg = spl * 256;
    const int wr   = (w >> 1) * 64;
    const int wc   = (w & 1) * 64;
    const int l15  = lane & 15;
    const int kq   = lane >> 4;

    f32x4 acc[4][4];
#pragma unroll
    for (int m = 0; m < 4; ++m)
#pragma unroll
        for (int n = 0; n < 4; ++n) acc[m][n] = f32x4{0.f, 0.f, 0.f, 0.f};

    const int s0 = tid, s1 = tid + 256;
    const size_t ga0 = (size_t)(row0 + (s0 >> 2)) * K + (s0 & 3) * 8;
    const size_t ga1 = (size_t)(row0 + (s1 >> 2)) * K + (s1 & 3) * 8;
    const size_t gb0 = (size_t)(s0 >> 2) * K + (s0 & 3) * 8;
    const size_t gb1 = (size_t)(s1 >> 2) * K + (s1 & 3) * 8;
    bf16* la0 = lsA + (size_t)(w * 64) * 8;
    bf16* la1 = lsA + (size_t)(256 + w * 64) * 8;
    bf16* lb0 = lsB + (size_t)(w * 64) * 8;
    bf16* lb1 = lsB + (size_t)(256 + w * 64) * 8;

    for (int k0 = kbeg; k0 < kbeg + 256; k0 += 32) {
        __builtin_amdgcn_global_load_lds((gas_ptr)(A  + ga0 + k0), (las_ptr)la0, 16, 0, 0);
        __builtin_amdgcn_global_load_lds((gas_ptr)(A  + ga1 + k0), (las_ptr)la1, 16, 0, 0);
        __builtin_amdgcn_global_load_lds((gas_ptr)(Wt + gb0 + k0), (las_ptr)lb0, 16, 0, 0);
        __builtin_amdgcn_global_load_lds((gas_ptr)(Wt + gb1 + k0), (las_ptr)lb1, 16, 0, 0);
        __syncthreads();

        bf16x8 af[4], bfr[4];
#pragma unroll
        for (int m = 0; m < 4; ++m)
            af[m] = *(const bf16x8*)(lsA + (size_t)(wr + m * 16 + l15) * 32 + kq * 8);
#pragma unroll
        for (int n = 0; n < 4; ++n)
            bfr[n] = *(const bf16x8*)(lsB + (size_t)(wc + n * 16 + l15) * 32 + kq * 8);
#pragma unroll
        for (int m = 0; m < 4; ++m)
#pragma unroll
            for (int n = 0; n < 4; ++n)
                acc[m][n] = __builtin_amdgcn_mfma_f32_16x16x32_bf16(af[m], bfr[n], acc[m][n], 0, 0, 0);
        __syncthreads();
    }

    // store only cols < 16 (wc==0, n==0)
    if (wc == 0) {
#pragma unroll
        for (int m = 0; m < 4; ++m)
#pragma unroll
            for (int r = 0; r < 4; ++r) {
                const int row = row0 + wr + m * 16 + kq * 4 + r;
                up[(size_t)spl * TT * 16 + (size_t)row * 16 + l15] = acc[m][0][r];
            }
    }
}

// reduce the 8 K-split partials: u = sum_s up[s]
__global__ void ured_k(const float* __restrict__ up, float* __restrict__ u)
{
    int i = blockIdx.x * 256 + threadIdx.x;   // TT*16 = 65536
    float s = 0.f;
#pragma unroll
    for (int k = 0; k < 8; ++k) s += up[(size_t)k * TT * 16 + i];
    u[i] = s;
}

// ---------------------------------------------------------------------------
// fp32 [K,N] -> bf16 [N,K] transpose (64x64 tiles through LDS)
// ---------------------------------------------------------------------------
__global__ __launch_bounds__(256)
void transpose_k(const float* __restrict__ W, bf16* __restrict__ WT, int K, int N)
{
    __shared__ bf16 t[64][66];
    const int k0 = blockIdx.x * 64, n0 = blockIdx.y * 64;
    const int tid = threadIdx.x;
#pragma unroll
    for (int i = 0; i < 16; ++i) {
        int idx = i * 256 + tid;
        int kk = idx >> 6, nn = idx & 63;
        t[nn][kk] = f2b(W[(size_t)(k0 + kk) * N + n0 + nn]);
    }
    __syncthreads();
#pragma unroll
    for (int i = 0; i < 16; ++i) {
        int idx = i * 256 + tid;
        int nn = idx >> 6, kk = idx & 63;
        WT[(size_t)(n0 + nn) * K + k0 + kk] = t[nn][kk];
    }
}

// B_ssm [DI,16] fp32 -> bf16 [128,DI] padded, x0.1 folded in
__global__ void prep_bm_k(const float* __restrict__ Bm, bf16* __restrict__ BmT)
{
    int idx = blockIdx.x * 256 + threadIdx.x;   // 128*2048
    int n = idx >> 11, k = idx & 2047;
    float v = (n < 16) ? Bm[(size_t)k * 16 + n] * 0.1f : 0.f;
    BmT[idx] = f2b(v);
}

// C_ssm [16,DI] fp32 -> bf16 [DI,32] padded (K padded 16->32)
__global__ void prep_cm_k(const float* __restrict__ Cm, bf16* __restrict__ CmT)
{
    int idx = blockIdx.x * 256 + threadIdx.x;   // 2048*32
    int i = idx >> 5, k = idx & 31;
    float v = (k < 16) ? Cm[(size_t)k * 2048 + i] : 0.f;
    CmT[idx] = f2b(v);
}

// features -> fp32 residual copy + bf16 copy
__global__ void copyfeat_k(const float* __restrict__ f, float* __restrict__ xf,
                           bf16* __restrict__ xb)
{
    int i = (blockIdx.x * 256 + threadIdx.x) * 4;
    float4 v = *(const float4*)(f + i);
    *(float4*)(xf + i) = v;
    xb[i + 0] = f2b(v.x);
    xb[i + 1] = f2b(v.y);
    xb[i + 2] = f2b(v.z);
    xb[i + 3] = f2b(v.w);
}

// causal depthwise conv (K=4) + bias + silu; xp = first DI cols of xz[T,4096]
__global__ void conv_k(const bf16* __restrict__ xz, const float* __restrict__ cw,
                       const float* __restrict__ cb, bf16* __restrict__ xc)
{
    int idx = blockIdx.x * 256 + threadIdx.x;   // T*DI
    int t = idx >> 11, i = idx & 2047;
    int s = t & (SS - 1);
    float4 wv = *(const float4*)(cw + i * 4);
    float acc = cb[i];
    const bf16* base = xz + (size_t)t * 4096 + i;
    if (s >= 3) {
        acc = fmaf(b2f(base[-3 * 4096]), wv.x, acc);
        acc = fmaf(b2f(base[-2 * 4096]), wv.y, acc);
        acc = fmaf(b2f(base[-1 * 4096]), wv.z, acc);
    } else {
        if (s >= 2) acc = fmaf(b2f(base[-2 * 4096]), wv.y, acc);
        if (s >= 1) acc = fmaf(b2f(base[-1 * 4096]), wv.z, acc);
    }
    acc = fmaf(b2f(base[0]), wv.w, acc);
    float sig = 1.f / (1.f + expf(-acc));
    xc[idx] = f2b(acc * sig);
}

// ---------------------------------------------------------------------------
// scan h_t = 0.9 h + u_t; chunk=32 tokens, redundant 96-step warmup;
// writes hs [T,32] bf16 with cols 16..31 zeroed (K-pad for the Cm GEMM).
// ---------------------------------------------------------------------------
__global__ void scan2_k(const float* __restrict__ u, bf16* __restrict__ hs)
{
    int gid = blockIdx.x * 256 + threadIdx.x;   // 2048 total
    int n = gid & 15, c = (gid >> 4) & 63, b = gid >> 10;
    int start = c * 32;
    const float* ub = u + (size_t)b * SS * 16;
    bf16* hb = hs + (size_t)b * SS * 32;
    float h = 0.f;
    int w0 = start - 96; if (w0 < 0) w0 = 0;
    for (int t = w0; t < start; ++t) h = 0.9f * h + ub[(size_t)t * 16 + n];
    const bf16 zero = f2b(0.f);
    for (int t = start; t < start + 32; ++t) {
        h = 0.9f * h + ub[(size_t)t * 16 + n];
        hb[(size_t)t * 32 + n] = f2b(h);
        hb[(size_t)t * 32 + 16 + n] = zero;
    }
}

// LayerNorm fp32 -> bf16
__global__ __launch_bounds__(256)
void ln_k(const float* __restrict__ x, const float* __restrict__ g,
          const float* __restrict__ bb, bf16* __restrict__ xn)
{
    int t = blockIdx.x, tid = threadIdx.x;
    const float* xr = x + (size_t)t * DD;
    float4 v = *(const float4*)(xr + tid * 4);
    float s = v.x + v.y + v.z + v.w;
#pragma unroll
    for (int o = 32; o > 0; o >>= 1) s += __shfl_down(s, o, 64);
    __shared__ float r1[4], r2[4];
    if ((tid & 63) == 0) r1[tid >> 6] = s;
    __syncthreads();
    float mu = (r1[0] + r1[1] + r1[2] + r1[3]) * (1.f / DD);
    float d0 = v.x - mu, d1 = v.y - mu, d2 = v.z - mu, d3 = v.w - mu;
    float ss = d0 * d0 + d1 * d1 + d2 * d2 + d3 * d3;
#pragma unroll
    for (int o = 32; o > 0; o >>= 1) ss += __shfl_down(ss, o, 64);
    if ((tid & 63) == 0) r2[tid >> 6] = ss;
    __syncthreads();
    float var = (r2[0] + r2[1] + r2[2] + r2[3]) * (1.f / DD);
    float inv = rsqrtf(var + 1e-5f);
    int di = tid * 4;
    xn[(size_t)t * DD + di + 0] = f2b(d0 * inv * g[di + 0] + bb[di + 0]);
    xn[(size_t)t * DD + di + 1] = f2b(d1 * inv * g[di + 1] + bb[di + 1]);
    xn[(size_t)t * DD + di + 2] = f2b(d2 * inv * g[di + 2] + bb[di + 2]);
    xn[(size_t)t * DD + di + 3] = f2b(d3 * inv * g[di + 3] + bb[di + 3]);
}

// tiny head: actions = tanh(h2 @ w3 + b3)
__global__ void act3_k(const bf16* __restrict__ h2, const float* __restrict__ w3,
                       const float* __restrict__ b3, float* __restrict__ out)
{
    int idx = blockIdx.x * 256 + threadIdx.x;
    if (idx >= TT * AA) return;
    int t = idx / AA, a = idx - t * AA;
    float acc = b3[a];
    const bf16* hr = h2 + (size_t)t * 256;
    for (int k = 0; k < 256; ++k)
        acc = fmaf(b2f(hr[k]), w3[k * AA + a], acc);
    out[idx] = tanhf(acc);
}

// ---------------------------------------------------------------------------
extern "C" void kernel_launch(void* const* d_in, const int* in_sizes, int n_in,
                              void* d_out, int out_size, void* d_ws, size_t ws_size,
                              hipStream_t stream)
{
    (void)in_sizes; (void)n_in; (void)out_size; (void)ws_size;
    const float* features = (const float*)d_in[0];
    const float* in_proj_w = (const float*)d_in[1];
    const float* conv_w = (const float*)d_in[2];
    const float* conv_b = (const float*)d_in[3];
    const float* B_ssm = (const float*)d_in[4];
    const float* C_ssm = (const float*)d_in[5];
    const float* out_w = (const float*)d_in[6];
    const float* ln_g = (const float*)d_in[7];
    const float* ln_b = (const float*)d_in[8];
    const float* act_w1 = (const float*)d_in[9];
    const float* act_b1 = (const float*)d_in[10];
    const float* act_w2 = (const float*)d_in[11];
    const float* act_b2 = (const float*)d_in[12];
    const float* act_w3 = (const float*)d_in[13];
    const float* act_b3 = (const float*)d_in[14];
    const float* lang_w1 = (const float*)d_in[15];
    const float* lang_b1 = (const float*)d_in[16];
    const float* lang_w2 = (const float*)d_in[17];
    const float* lang_b2 = (const float*)d_in[18];

    static bool attr_done = false;
    if (!attr_done) {
        hipFuncSetAttribute((const void*)&g8_k<0>, hipFuncAttributeMaxDynamicSharedMemorySize, 131072);
        hipFuncSetAttribute((const void*)&g8_k<5>, hipFuncAttributeMaxDynamicSharedMemorySize, 131072);
        attr_done = true;
    }

    char* p = (char*)d_ws;
    size_t off = 0;
    auto alloc = [&](size_t bytes) -> void* {
        void* q = p + off;
        off = (off + bytes + 255) & ~(size_t)255;
        return q;
    };
    float* x_f  = (float*)alloc((size_t)TT * DD * 4);     // fp32 residual stream
    bf16*  x_b  = (bf16*) alloc((size_t)TT * DD * 2);     // bf16 mirror
    bf16*  xz   = (bf16*) alloc((size_t)TT * 4096 * 2);   // in_proj out (xp|z)
    bf16*  xc   = (bf16*) alloc((size_t)TT * DDI * 2);    // conv out; later reused as y
    float* u    = (float*)alloc((size_t)TT * 16 * 4);
    float* up   = (float*)alloc((size_t)8 * TT * 16 * 4); // split-K partials
    bf16*  hs   = (bf16*) alloc((size_t)TT * 32 * 2);     // scan out, K-padded
    bf16*  xn   = (bf16*) alloc((size_t)TT * DD * 2);
    bf16*  h1   = (bf16*) alloc((size_t)TT * 512 * 2);
    bf16*  h2   = (bf16*) alloc((size_t)TT * 256 * 2);
    bf16*  hl   = (bf16*) alloc((size_t)TT * DD * 2);
    bf16*  inwT = (bf16*) alloc((size_t)LL * 4096 * 1024 * 2);
    bf16*  owT  = (bf16*) alloc((size_t)LL * 1024 * 2048 * 2);
    bf16*  bmT  = (bf16*) alloc((size_t)LL * 128 * 2048 * 2);
    bf16*  cmT  = (bf16*) alloc((size_t)LL * 2048 * 32 * 2);
    bf16*  a1T  = (bf16*) alloc((size_t)512 * 1024 * 2);
    bf16*  a2T  = (bf16*) alloc((size_t)256 * 512 * 2);
    bf16*  l1T  = (bf16*) alloc((size_t)1024 * 1024 * 2);
    bf16*  l2T  = (bf16*) alloc((size_t)VV * 1024 * 2);
    bf16*  y    = xc;   // xc dead once u is computed

    // ---- prep: fp32->bf16 + transpose all GEMM weights (per call) ----
    copyfeat_k<<<TT * DD / 1024, 256, 0, stream>>>(features, x_f, x_b);
    for (int l = 0; l < LL; ++l) {
        transpose_k<<<dim3(16, 64), 256, 0, stream>>>(in_proj_w + (size_t)l * 1024 * 4096,
                                                      inwT + (size_t)l * 4096 * 1024, 1024, 4096);
        transpose_k<<<dim3(32, 16), 256, 0, stream>>>(out_w + (size_t)l * 2048 * 1024,
                                                      owT + (size_t)l * 1024 * 2048, 2048, 1024);
        prep_bm_k<<<(128 * 2048) / 256, 256, 0, stream>>>(B_ssm + (size_t)l * 2048 * 16,
                                                          bmT + (size_t)l * 128 * 2048);
        prep_cm_k<<<(2048 * 32) / 256, 256, 0, stream>>>(C_ssm + (size_t)l * 16 * 2048,
                                                         cmT + (size_t)l * 2048 * 32);
    }
    transpose_k<<<dim3(16, 8), 256, 0, stream>>>(act_w1, a1T, 1024, 512);
    transpose_k<<<dim3(8, 4), 256, 0, stream>>>(act_w2, a2T, 512, 256);
    transpose_k<<<dim3(16, 16), 256, 0, stream>>>(lang_w1, l1T, 1024, 1024);
    transpose_k<<<dim3(16, 500), 256, 0, stream>>>(lang_w2, l2T, 1024, VV);

    // ---- 6 mamba blocks ----
    for (int l = 0; l < LL; ++l) {
        // xz = x @ in_w : g8, 16x16 tiles of 256^2 -> 256 blocks
        g8_k<0><<<256, 512, 131072, stream>>>(x_b, inwT + (size_t)l * 4096 * 1024,
                                              1024, 16, 4096, nullptr, xz, nullptr);
        // xc = silu(causal_dwconv(xp) + cb)
        conv_k<<<TT * DDI / 256, 256, 0, stream>>>(xz, conv_w + (size_t)l * DDI * 4,
                                                   conv_b + (size_t)l * DDI, xc);
        // u = xc @ (Bm*0.1) : split-K 8x -> grid 256, then reduce
        usk_k<<<dim3(32, 8), 256, 0, stream>>>(xc, bmT + (size_t)l * 128 * 2048, up);
        ured_k<<<TT * 16 / 256, 256, 0, stream>>>(up, u);
        // hs = scan(u)
        scan2_k<<<8, 256, 0, stream>>>(u, hs);
        // y = (hs @ Cm) * silu(z)
        gemm_k<2><<<dim3(32, 16), 256, 0, stream>>>(hs, cmT + (size_t)l * 2048 * 32,
                                                    32, 2048, nullptr, y, nullptr, xz + 2048, 4096);
        // x += y @ ow  (fp32 residual, refresh bf16 mirror)
        gemm_k<3><<<dim3(32, 8), 256, 0, stream>>>(y, owT + (size_t)l * 1024 * 2048,
                                                   2048, 1024, x_f, x_b, nullptr, nullptr, 0);
    }

    // ---- LN + heads ----
    ln_k<<<TT, 256, 0, stream>>>(x_f, ln_g, ln_b, xn);
    gemm_k<4><<<dim3(32, 4), 256, 0, stream>>>(xn, a1T, 1024, 512, nullptr, h1, act_b1, nullptr, 0);
    gemm_k<4><<<dim3(32, 2), 256, 0, stream>>>(h1, a2T, 512, 256, nullptr, h2, act_b2, nullptr, 0);
    act3_k<<<(TT * AA + 255) / 256, 256, 0, stream>>>(h2, act_w3, act_b3, (float*)d_out);
    gemm_k<4><<<dim3(32, 8), 256, 0, stream>>>(xn, l1T, 1024, 1024, nullptr, hl, lang_b1, nullptr, 0);
    // logits: g8, 16 x 125 tiles of 256^2 -> 2000 blocks
    g8_k<5><<<2000, 512, 131072, stream>>>(hl, l2T, 1024, 16, VV,
                                           (float*)d_out + (size_t)TT * AA, nullptr, lang_b2);
}

// Round 11
// 1643.704 us; speedup vs baseline: 1.4452x; 1.0016x over previous
//
#include <hip/hip_runtime.h>
#include <hip/hip_bf16.h>
#include <cstdint>
#include <cstddef>

// Problem dims
#define TT 4096   // B*S tokens
#define SS 2048   // S
#define DD 1024   // D
#define DDI 2048  // DI
#define LL 6
#define VV 32000
#define AA 7

typedef __hip_bfloat16 bf16;
typedef __attribute__((ext_vector_type(8))) short bf16x8;   // 8 bf16 in 4 VGPRs
typedef __attribute__((ext_vector_type(4))) float f32x4;

typedef const __attribute__((address_space(1))) void* gas_ptr;
typedef __attribute__((address_space(3))) void* las_ptr;

static __device__ __forceinline__ float b2f(bf16 h) { return __bfloat162float(h); }
static __device__ __forceinline__ bf16 f2b(float f) { return __float2bfloat16(f); }
static __device__ __forceinline__ float bs2f(short x) {
    unsigned int u = ((unsigned int)(unsigned short)x) << 16;
    float f; __builtin_memcpy(&f, &u, 4); return f;
}

// 64-B rows, 4x16B chunks; chunk ^= (row>>1)&3 -> verified 0 conflicts (R4/R5).
#define SWZ(off) ((off) ^ ((((off) >> 7) & 3) << 4))

// ---------------------------------------------------------------------------
// g8 (measured ~350us lang_w2; in_proj ~80us): 256x256 8-phase GEMM, BK=64,
// 8 waves. Two 4-slot rings of 16 KiB K-half tiles; counted vmcnt(10).
// EPI: 0 = store bf16; 5 = bias + f32 store.
// ---------------------------------------------------------------------------
template<int EPI>
__global__ __launch_bounds__(512, 2)
void g8_k(const bf16* __restrict__ A, const bf16* __restrict__ Wt,
          int K, int mx, int out_ld,
          float* __restrict__ of32, bf16* __restrict__ ob16,
          const float* __restrict__ bias)
{
    extern __shared__ char lds[];   // 131072
    const int nwg = gridDim.x;
    int l = blockIdx.x;
    if ((nwg & 7) == 0) l = (l & 7) * (nwg >> 3) + (l >> 3);   // XCD-chunked
    const int row0 = (l % mx) * 256, col0 = (l / mx) * 256;

    const int tid = threadIdx.x, wid = tid >> 6, lane = tid & 63;
    const int wr = wid >> 2, wc = wid & 3;        // 2M x 4N waves
    const int l15 = lane & 15, kq = lane >> 4;

    f32x4 acc[8][4];
#pragma unroll
    for (int m = 0; m < 8; ++m)
#pragma unroll
        for (int n = 0; n < 4; ++n) acc[m][n] = f32x4{0.f, 0.f, 0.f, 0.f};

    const int sr   = tid >> 2;
    const int colE = (((tid & 3) ^ ((tid >> 3) & 3)) * 8);
    const bf16* gA = A  + (size_t)(row0 + sr) * K + colE;
    const bf16* gB = Wt + (size_t)(col0 + sr) * K + colE;
    const int dst0 = tid * 16, dst1 = 8192 + tid * 16;

    auto stageA = [&](int kh) {
        char* b = lds + (kh & 3) * 16384;
        __builtin_amdgcn_global_load_lds((gas_ptr)(gA + kh * 32),                   (las_ptr)(b + dst0), 16, 0, 0);
        __builtin_amdgcn_global_load_lds((gas_ptr)(gA + (size_t)128 * K + kh * 32), (las_ptr)(b + dst1), 16, 0, 0);
    };
    auto stageB = [&](int kh) {
        char* b = lds + 65536 + (kh & 3) * 16384;
        __builtin_amdgcn_global_load_lds((gas_ptr)(gB + kh * 32),                   (las_ptr)(b + dst0), 16, 0, 0);
        __builtin_amdgcn_global_load_lds((gas_ptr)(gB + (size_t)128 * K + kh * 32), (las_ptr)(b + dst1), 16, 0, 0);
    };

    const int NT = K >> 6, KH = K >> 5;
    stageA(0); stageB(0); stageA(1); stageB(1);
    stageA(2); stageB(2); stageA(3); stageB(3);
    int nextA = 4, nextB = 4;

    for (int t = 0; t < NT; ++t) {
        const char* As0 = lds + ((2 * t) & 3) * 16384;
        const char* As1 = lds + ((2 * t + 1) & 3) * 16384;
        const char* Bs0 = lds + 65536 + ((2 * t) & 3) * 16384;
        const char* Bs1 = lds + 65536 + ((2 * t + 1) & 3) * 16384;
        bf16x8 af[4], bfg[4];

        // q0
        if (t < NT - 3) asm volatile("s_waitcnt vmcnt(10)" ::: "memory");
        else            asm volatile("s_waitcnt vmcnt(0)" ::: "memory");
        __builtin_amdgcn_sched_barrier(0);
        __builtin_amdgcn_s_barrier();
        __builtin_amdgcn_sched_barrier(0);
#pragma unroll
        for (int fn = 0; fn < 4; ++fn)
            bfg[fn] = *(const bf16x8*)(Bs0 + SWZ((wc * 64 + fn * 16 + l15) * 64 + kq * 16));
#pragma unroll
        for (int fm = 0; fm < 4; ++fm)
            af[fm] = *(const bf16x8*)(As0 + SWZ((wr * 128 + fm * 16 + l15) * 64 + kq * 16));
        if (t > 0 && nextA < KH) { stageA(nextA); ++nextA; }
        asm volatile("s_waitcnt lgkmcnt(0)" ::: "memory");
        __builtin_amdgcn_sched_barrier(0);
        __builtin_amdgcn_s_setprio(1);
#pragma unroll
        for (int fm = 0; fm < 4; ++fm)
#pragma unroll
            for (int fn = 0; fn < 4; ++fn)
                acc[fm][fn] = __builtin_amdgcn_mfma_f32_16x16x32_bf16(af[fm], bfg[fn], acc[fm][fn], 0, 0, 0);
        __builtin_amdgcn_s_setprio(0);
        __builtin_amdgcn_sched_barrier(0);
        __builtin_amdgcn_s_barrier();
        __builtin_amdgcn_sched_barrier(0);

        // q1 (A mh1 of ks0; B reg-reused)
#pragma unroll
        for (int fm = 0; fm < 4; ++fm)
            af[fm] = *(const bf16x8*)(As0 + SWZ((wr * 128 + 64 + fm * 16 + l15) * 64 + kq * 16));
        if (nextB < KH) { stageB(nextB); ++nextB; }
        asm volatile("s_waitcnt lgkmcnt(0)" ::: "memory");
        __builtin_amdgcn_sched_barrier(0);
        __builtin_amdgcn_s_setprio(1);
#pragma unroll
        for (int fm = 0; fm < 4; ++fm)
#pragma unroll
            for (int fn = 0; fn < 4; ++fn)
                acc[4 + fm][fn] = __builtin_amdgcn_mfma_f32_16x16x32_bf16(af[fm], bfg[fn], acc[4 + fm][fn], 0, 0, 0);
        __builtin_amdgcn_s_setprio(0);
        __builtin_amdgcn_sched_barrier(0);
        __builtin_amdgcn_s_barrier();
        __builtin_amdgcn_sched_barrier(0);

        // q2
        if (t < NT - 3) asm volatile("s_waitcnt vmcnt(10)" ::: "memory");
        else            asm volatile("s_waitcnt vmcnt(0)" ::: "memory");
        __builtin_amdgcn_sched_barrier(0);
        __builtin_amdgcn_s_barrier();
        __builtin_amdgcn_sched_barrier(0);
#pragma unroll
        for (int fn = 0; fn < 4; ++fn)
            bfg[fn] = *(const bf16x8*)(Bs1 + SWZ((wc * 64 + fn * 16 + l15) * 64 + kq * 16));
#pragma unroll
        for (int fm = 0; fm < 4; ++fm)
            af[fm] = *(const bf16x8*)(As1 + SWZ((wr * 128 + fm * 16 + l15) * 64 + kq * 16));
        if (nextA < KH) { stageA(nextA); ++nextA; }
        asm volatile("s_waitcnt lgkmcnt(0)" ::: "memory");
        __builtin_amdgcn_sched_barrier(0);
        __builtin_amdgcn_s_setprio(1);
#pragma unroll
        for (int fm = 0; fm < 4; ++fm)
#pragma unroll
            for (int fn = 0; fn < 4; ++fn)
                acc[fm][fn] = __builtin_amdgcn_mfma_f32_16x16x32_bf16(af[fm], bfg[fn], acc[fm][fn], 0, 0, 0);
        __builtin_amdgcn_s_setprio(0);
        __builtin_amdgcn_sched_barrier(0);
        __builtin_amdgcn_s_barrier();
        __builtin_amdgcn_sched_barrier(0);

        // q3 (A mh1 of ks1; B reg-reused)
#pragma unroll
        for (int fm = 0; fm < 4; ++fm)
            af[fm] = *(const bf16x8*)(As1 + SWZ((wr * 128 + 64 + fm * 16 + l15) * 64 + kq * 16));
        if (nextB < KH) { stageB(nextB); ++nextB; }
        asm volatile("s_waitcnt lgkmcnt(0)" ::: "memory");
        __builtin_amdgcn_sched_barrier(0);
        __builtin_amdgcn_s_setprio(1);
#pragma unroll
        for (int fm = 0; fm < 4; ++fm)
#pragma unroll
            for (int fn = 0; fn < 4; ++fn)
                acc[4 + fm][fn] = __builtin_amdgcn_mfma_f32_16x16x32_bf16(af[fm], bfg[fn], acc[4 + fm][fn], 0, 0, 0);
        __builtin_amdgcn_s_setprio(0);
        __builtin_amdgcn_sched_barrier(0);
        __builtin_amdgcn_s_barrier();
        __builtin_amdgcn_sched_barrier(0);
    }

#pragma unroll
    for (int fm = 0; fm < 8; ++fm) {
#pragma unroll
        for (int fn = 0; fn < 4; ++fn) {
#pragma unroll
            for (int r = 0; r < 4; ++r) {
                const int row = row0 + wr * 128 + fm * 16 + kq * 4 + r;
                const int col = col0 + wc * 64 + fn * 16 + l15;
                float v = acc[fm][fn][r];
                if (EPI == 0) ob16[(size_t)row * out_ld + col] = f2b(v);
                else          of32[(size_t)row * out_ld + col] = v + bias[col];
            }
        }
    }
}

// ---------------------------------------------------------------------------
// g8h: 128x128 counted-vmcnt GEMM. 4 waves (2M x 2N of 64x64), 32-col phases.
// Two 5-slot rings of 8 KiB K-half tiles (A @0, B @40960) = 80 KiB -> 2/CU.
// One barrier per phase. Ledger: prologue stages kh 0..3 (16 loads); phase kh
// waits vmcnt(12) (3 newer halves in flight), stages kh+4 -> slot (kh-1)%5,
// whose readers all lgkm-waited before this phase's entry barrier.
// EPI: 3 = residual f32 in/out + bf16 out.
// ---------------------------------------------------------------------------
template<int EPI>
__global__ __launch_bounds__(256, 2)
void g8h_k(const bf16* __restrict__ A, const bf16* __restrict__ Wt,
           int K, int mx, int out_ld,
           float* __restrict__ of32, bf16* __restrict__ ob16,
           const float* __restrict__ bias)
{
    extern __shared__ char lds[];   // 81920
    const int nwg = gridDim.x;
    int l = blockIdx.x;
    if ((nwg & 7) == 0) l = (l & 7) * (nwg >> 3) + (l >> 3);   // XCD-chunked
    const int row0 = (l % mx) * 128, col0 = (l / mx) * 128;

    const int tid = threadIdx.x, wid = tid >> 6, lane = tid & 63;
    const int wr = wid >> 1, wc = wid & 1;        // 2M x 2N waves
    const int l15 = lane & 15, kq = lane >> 4;

    f32x4 acc[4][4];
#pragma unroll
    for (int m = 0; m < 4; ++m)
#pragma unroll
        for (int n = 0; n < 4; ++n) acc[m][n] = f32x4{0.f, 0.f, 0.f, 0.f};

    const int sr   = tid >> 2;                        // 0..63
    const int colE = (((tid & 3) ^ ((tid >> 3) & 3)) * 8);
    const bf16* gA = A  + (size_t)(row0 + sr) * K + colE;
    const bf16* gB = Wt + (size_t)(col0 + sr) * K + colE;
    const int dst0 = tid * 16, dst1 = 4096 + tid * 16;

    auto stage = [&](int kh) {
        char* a = lds + (kh % 5) * 8192;
        char* b = lds + 40960 + (kh % 5) * 8192;
        __builtin_amdgcn_global_load_lds((gas_ptr)(gA + kh * 32),                  (las_ptr)(a + dst0), 16, 0, 0);
        __builtin_amdgcn_global_load_lds((gas_ptr)(gA + (size_t)64 * K + kh * 32), (las_ptr)(a + dst1), 16, 0, 0);
        __builtin_amdgcn_global_load_lds((gas_ptr)(gB + kh * 32),                  (las_ptr)(b + dst0), 16, 0, 0);
        __builtin_amdgcn_global_load_lds((gas_ptr)(gB + (size_t)64 * K + kh * 32), (las_ptr)(b + dst1), 16, 0, 0);
    };

    const int KH = K >> 5;
    stage(0); stage(1); stage(2); stage(3);

    for (int kh = 0; kh < KH; ++kh) {
        const int rem = KH - 1 - kh;
        if (rem >= 3)      asm volatile("s_waitcnt vmcnt(12)" ::: "memory");
        else if (rem == 2) asm volatile("s_waitcnt vmcnt(8)" ::: "memory");
        else if (rem == 1) asm volatile("s_waitcnt vmcnt(4)" ::: "memory");
        else               asm volatile("s_waitcnt vmcnt(0)" ::: "memory");
        __builtin_amdgcn_sched_barrier(0);
        __builtin_amdgcn_s_barrier();
        __builtin_amdgcn_sched_barrier(0);

        const char* As = lds + (kh % 5) * 8192;
        const char* Bs = lds + 40960 + (kh % 5) * 8192;
        bf16x8 af[4], bfg[4];
#pragma unroll
        for (int fn = 0; fn < 4; ++fn)
            bfg[fn] = *(const bf16x8*)(Bs + SWZ((wc * 64 + fn * 16 + l15) * 64 + kq * 16));
#pragma unroll
        for (int fm = 0; fm < 4; ++fm)
            af[fm] = *(const bf16x8*)(As + SWZ((wr * 64 + fm * 16 + l15) * 64 + kq * 16));
        if (kh + 4 < KH) stage(kh + 4);
        asm volatile("s_waitcnt lgkmcnt(0)" ::: "memory");
        __builtin_amdgcn_sched_barrier(0);
        __builtin_amdgcn_s_setprio(1);
#pragma unroll
        for (int fm = 0; fm < 4; ++fm)
#pragma unroll
            for (int fn = 0; fn < 4; ++fn)
                acc[fm][fn] = __builtin_amdgcn_mfma_f32_16x16x32_bf16(af[fm], bfg[fn], acc[fm][fn], 0, 0, 0);
        __builtin_amdgcn_s_setprio(0);
        __builtin_amdgcn_sched_barrier(0);
    }

#pragma unroll
    for (int fm = 0; fm < 4; ++fm) {
#pragma unroll
        for (int fn = 0; fn < 4; ++fn) {
#pragma unroll
            for (int r = 0; r < 4; ++r) {
                const int row = row0 + wr * 64 + fm * 16 + kq * 4 + r;
                const int col = col0 + wc * 64 + fn * 16 + l15;
                float v = acc[fm][fn][r];
                if (EPI == 3) {
                    float rr = of32[(size_t)row * out_ld + col] + v;
                    of32[(size_t)row * out_ld + col] = rr;
                    ob16[(size_t)row * out_ld + col] = f2b(rr);
                } else {
                    ob16[(size_t)row * out_ld + col] = f2b(v);
                }
            }
        }
    }
}

// ---------------------------------------------------------------------------
// 128x128 m97-structure GEMM.  EPI: 4=bias+relu bf16
// ---------------------------------------------------------------------------
template<int EPI>
__global__ __launch_bounds__(256)
void gemm_k(const bf16* __restrict__ A, const bf16* __restrict__ Wt,
            int K, int out_ld,
            float* __restrict__ of32, bf16* __restrict__ ob16,
            const float* __restrict__ bias)
{
    __shared__ bf16x8 lsA8[128 * 4];
    __shared__ bf16x8 lsB8[128 * 4];
    bf16* lsA = (bf16*)lsA8;
    bf16* lsB = (bf16*)lsB8;

    const int tid  = threadIdx.x;
    const int w    = tid >> 6;
    const int lane = tid & 63;
    const int row0 = blockIdx.x * 128;
    const int col0 = blockIdx.y * 128;
    const int wr   = (w >> 1) * 64;
    const int wc   = (w & 1) * 64;
    const int l15  = lane & 15;
    const int kq   = lane >> 4;

    f32x4 acc[4][4];
#pragma unroll
    for (int m = 0; m < 4; ++m)
#pragma unroll
        for (int n = 0; n < 4; ++n) acc[m][n] = f32x4{0.f, 0.f, 0.f, 0.f};

    const int s0 = tid, s1 = tid + 256;
    const size_t ga0 = (size_t)(row0 + (s0 >> 2)) * K + (s0 & 3) * 8;
    const size_t ga1 = (size_t)(row0 + (s1 >> 2)) * K + (s1 & 3) * 8;
    const size_t gb0 = (size_t)(col0 + (s0 >> 2)) * K + (s0 & 3) * 8;
    const size_t gb1 = (size_t)(col0 + (s1 >> 2)) * K + (s1 & 3) * 8;
    bf16* la0 = lsA + (size_t)(w * 64) * 8;
    bf16* la1 = lsA + (size_t)(256 + w * 64) * 8;
    bf16* lb0 = lsB + (size_t)(w * 64) * 8;
    bf16* lb1 = lsB + (size_t)(256 + w * 64) * 8;

    for (int k0 = 0; k0 < K; k0 += 32) {
        __builtin_amdgcn_global_load_lds((gas_ptr)(A  + ga0 + k0), (las_ptr)la0, 16, 0, 0);
        __builtin_amdgcn_global_load_lds((gas_ptr)(A  + ga1 + k0), (las_ptr)la1, 16, 0, 0);
        __builtin_amdgcn_global_load_lds((gas_ptr)(Wt + gb0 + k0), (las_ptr)lb0, 16, 0, 0);
        __builtin_amdgcn_global_load_lds((gas_ptr)(Wt + gb1 + k0), (las_ptr)lb1, 16, 0, 0);
        __syncthreads();

        bf16x8 af[4], bfr[4];
#pragma unroll
        for (int m = 0; m < 4; ++m)
            af[m] = *(const bf16x8*)(lsA + (size_t)(wr + m * 16 + l15) * 32 + kq * 8);
#pragma unroll
        for (int n = 0; n < 4; ++n)
            bfr[n] = *(const bf16x8*)(lsB + (size_t)(wc + n * 16 + l15) * 32 + kq * 8);
#pragma unroll
        for (int m = 0; m < 4; ++m)
#pragma unroll
            for (int n = 0; n < 4; ++n)
                acc[m][n] = __builtin_amdgcn_mfma_f32_16x16x32_bf16(af[m], bfr[n], acc[m][n], 0, 0, 0);
        __syncthreads();
    }

#pragma unroll
    for (int m = 0; m < 4; ++m) {
#pragma unroll
        for (int n = 0; n < 4; ++n) {
#pragma unroll
            for (int r = 0; r < 4; ++r) {
                const int row = row0 + wr + m * 16 + kq * 4 + r;
                const int col = col0 + wc + n * 16 + l15;
                float v = acc[m][n][r];
                v = fmaxf(v + bias[col], 0.f);
                ob16[(size_t)row * out_ld + col] = f2b(v);
            }
        }
    }
}

// ---------------------------------------------------------------------------
// Split-K skinny u-GEMM (R10, measured good): up[s][T][16] = xc @ Bm K-split
// ---------------------------------------------------------------------------
__global__ __launch_bounds__(256)
void usk_k(const bf16* __restrict__ A, const bf16* __restrict__ Wt,
           float* __restrict__ up)
{
    __shared__ bf16x8 lsA8[128 * 4];
    __shared__ bf16x8 lsB8[128 * 4];
    bf16* lsA = (bf16*)lsA8;
    bf16* lsB = (bf16*)lsB8;
    const int K = 2048;

    const int tid  = threadIdx.x;
    const int w    = tid >> 6;
    const int lane = tid & 63;
    const int row0 = blockIdx.x * 128;
    const int spl  = blockIdx.y;          // 0..7
    const int kbeg = spl * 256;
    const int wr   = (w >> 1) * 64;
    const int wc   = (w & 1) * 64;
    const int l15  = lane & 15;
    const int kq   = lane >> 4;

    f32x4 acc[4][4];
#pragma unroll
    for (int m = 0; m < 4; ++m)
#pragma unroll
        for (int n = 0; n < 4; ++n) acc[m][n] = f32x4{0.f, 0.f, 0.f, 0.f};

    const int s0 = tid, s1 = tid + 256;
    const size_t ga0 = (size_t)(row0 + (s0 >> 2)) * K + (s0 & 3) * 8;
    const size_t ga1 = (size_t)(row0 + (s1 >> 2)) * K + (s1 & 3) * 8;
    const size_t gb0 = (size_t)(s0 >> 2) * K + (s0 & 3) * 8;
    const size_t gb1 = (size_t)(s1 >> 2) * K + (s1 & 3) * 8;
    bf16* la0 = lsA + (size_t)(w * 64) * 8;
    bf16* la1 = lsA + (size_t)(256 + w * 64) * 8;
    bf16* lb0 = lsB + (size_t)(w * 64) * 8;
    bf16* lb1 = lsB + (size_t)(256 + w * 64) * 8;

    for (int k0 = kbeg; k0 < kbeg + 256; k0 += 32) {
        __builtin_amdgcn_global_load_lds((gas_ptr)(A  + ga0 + k0), (las_ptr)la0, 16, 0, 0);
        __builtin_amdgcn_global_load_lds((gas_ptr)(A  + ga1 + k0), (las_ptr)la1, 16, 0, 0);
        __builtin_amdgcn_global_load_lds((gas_ptr)(Wt + gb0 + k0), (las_ptr)lb0, 16, 0, 0);
        __builtin_amdgcn_global_load_lds((gas_ptr)(Wt + gb1 + k0), (las_ptr)lb1, 16, 0, 0);
        __syncthreads();

        bf16x8 af[4], bfr[4];
#pragma unroll
        for (int m = 0; m < 4; ++m)
            af[m] = *(const bf16x8*)(lsA + (size_t)(wr + m * 16 + l15) * 32 + kq * 8);
#pragma unroll
        for (int n = 0; n < 4; ++n)
            bfr[n] = *(const bf16x8*)(lsB + (size_t)(wc + n * 16 + l15) * 32 + kq * 8);
#pragma unroll
        for (int m = 0; m < 4; ++m)
#pragma unroll
            for (int n = 0; n < 4; ++n)
                acc[m][n] = __builtin_amdgcn_mfma_f32_16x16x32_bf16(af[m], bfr[n], acc[m][n], 0, 0, 0);
        __syncthreads();
    }

    if (wc == 0) {
#pragma unroll
        for (int m = 0; m < 4; ++m)
#pragma unroll
            for (int r = 0; r < 4; ++r) {
                const int row = row0 + wr + m * 16 + kq * 4 + r;
                up[(size_t)spl * TT * 16 + (size_t)row * 16 + l15] = acc[m][0][r];
            }
    }
}

// reduce the 8 K-split partials: u = sum_s up[s]
__global__ void ured_k(const float* __restrict__ up, float* __restrict__ u)
{
    int i = blockIdx.x * 256 + threadIdx.x;   // TT*16 = 65536
    float s = 0.f;
#pragma unroll
    for (int k = 0; k < 8; ++k) s += up[(size_t)k * TT * 16 + i];
    u[i] = s;
}

// ---------------------------------------------------------------------------
// fp32 [K,N] -> bf16 [N,K] transpose (64x64 tiles through LDS)
// ---------------------------------------------------------------------------
__global__ __launch_bounds__(256)
void transpose_k(const float* __restrict__ W, bf16* __restrict__ WT, int K, int N)
{
    __shared__ bf16 t[64][66];
    const int k0 = blockIdx.x * 64, n0 = blockIdx.y * 64;
    const int tid = threadIdx.x;
#pragma unroll
    for (int i = 0; i < 16; ++i) {
        int idx = i * 256 + tid;
        int kk = idx >> 6, nn = idx & 63;
        t[nn][kk] = f2b(W[(size_t)(k0 + kk) * N + n0 + nn]);
    }
    __syncthreads();
#pragma unroll
    for (int i = 0; i < 16; ++i) {
        int idx = i * 256 + tid;
        int nn = idx >> 6, kk = idx & 63;
        WT[(size_t)(n0 + nn) * K + k0 + kk] = t[nn][kk];
    }
}

// B_ssm [DI,16] fp32 -> bf16 [128,DI] padded, x0.1 folded in
__global__ void prep_bm_k(const float* __restrict__ Bm, bf16* __restrict__ BmT)
{
    int idx = blockIdx.x * 256 + threadIdx.x;   // 128*2048
    int n = idx >> 11, k = idx & 2047;
    float v = (n < 16) ? Bm[(size_t)k * 16 + n] * 0.1f : 0.f;
    BmT[idx] = f2b(v);
}

// features -> fp32 residual copy + bf16 copy
__global__ void copyfeat_k(const float* __restrict__ f, float* __restrict__ xf,
                           bf16* __restrict__ xb)
{
    int i = (blockIdx.x * 256 + threadIdx.x) * 4;
    float4 v = *(const float4*)(f + i);
    *(float4*)(xf + i) = v;
    xb[i + 0] = f2b(v.x);
    xb[i + 1] = f2b(v.y);
    xb[i + 2] = f2b(v.z);
    xb[i + 3] = f2b(v.w);
}

// causal depthwise conv (K=4) + bias + silu; xp = first DI cols of xz[T,4096]
__global__ void conv_k(const bf16* __restrict__ xz, const float* __restrict__ cw,
                       const float* __restrict__ cb, bf16* __restrict__ xc)
{
    int idx = blockIdx.x * 256 + threadIdx.x;   // T*DI
    int t = idx >> 11, i = idx & 2047;
    int s = t & (SS - 1);
    float4 wv = *(const float4*)(cw + i * 4);
    float acc = cb[i];
    const bf16* base = xz + (size_t)t * 4096 + i;
    if (s >= 3) {
        acc = fmaf(b2f(base[-3 * 4096]), wv.x, acc);
        acc = fmaf(b2f(base[-2 * 4096]), wv.y, acc);
        acc = fmaf(b2f(base[-1 * 4096]), wv.z, acc);
    } else {
        if (s >= 2) acc = fmaf(b2f(base[-2 * 4096]), wv.y, acc);
        if (s >= 1) acc = fmaf(b2f(base[-1 * 4096]), wv.z, acc);
    }
    acc = fmaf(b2f(base[0]), wv.w, acc);
    float sig = 1.f / (1.f + expf(-acc));
    xc[idx] = f2b(acc * sig);
}

// ---------------------------------------------------------------------------
// scan h_t = 0.9 h + u_t; chunk=32 tokens, redundant 96-step warmup; fp32 out.
// ---------------------------------------------------------------------------
__global__ void scan2_k(const float* __restrict__ u, float* __restrict__ hs)
{
    int gid = blockIdx.x * 256 + threadIdx.x;   // 2048 total
    int n = gid & 15, c = (gid >> 4) & 63, b = gid >> 10;
    int start = c * 32;
    const float* ub = u + (size_t)b * SS * 16;
    float* hb = hs + (size_t)b * SS * 16;
    float h = 0.f;
    int w0 = start - 96; if (w0 < 0) w0 = 0;
    for (int t = w0; t < start; ++t) h = 0.9f * h + ub[(size_t)t * 16 + n];
    for (int t = start; t < start + 32; ++t) {
        h = 0.9f * h + ub[(size_t)t * 16 + n];
        hb[(size_t)t * 16 + n] = h;
    }
}

// ---------------------------------------------------------------------------
// y[t,i] = (sum_n hs[t,n] * Cm[n,i]) * silu(z[t,i])   (R6 kernel, verified)
// ---------------------------------------------------------------------------
__global__ __launch_bounds__(256)
void yk_k(const float* __restrict__ hs, const float* __restrict__ Cm,
          const bf16* __restrict__ xz, bf16* __restrict__ y)
{
    const int t = blockIdx.x, i0 = threadIdx.x * 8;
    const float* h = hs + (size_t)t * 16;
    float o[8] = {0.f, 0.f, 0.f, 0.f, 0.f, 0.f, 0.f, 0.f};
#pragma unroll
    for (int n = 0; n < 16; ++n) {
        float hn = h[n];
        const float4* c = (const float4*)(Cm + (size_t)n * DDI + i0);
        float4 c0 = c[0], c1 = c[1];
        o[0] = fmaf(hn, c0.x, o[0]); o[1] = fmaf(hn, c0.y, o[1]);
        o[2] = fmaf(hn, c0.z, o[2]); o[3] = fmaf(hn, c0.w, o[3]);
        o[4] = fmaf(hn, c1.x, o[4]); o[5] = fmaf(hn, c1.y, o[5]);
        o[6] = fmaf(hn, c1.z, o[6]); o[7] = fmaf(hn, c1.w, o[7]);
    }
    bf16x8 zv = *(const bf16x8*)(xz + (size_t)t * 4096 + 2048 + i0);
    bf16* yo = y + (size_t)t * DDI + i0;
#pragma unroll
    for (int j = 0; j < 8; ++j) {
        float zf = bs2f(zv[j]);
        yo[j] = f2b(o[j] * (zf / (1.f + expf(-zf))));
    }
}

// LayerNorm fp32 -> bf16
__global__ __launch_bounds__(256)
void ln_k(const float* __restrict__ x, const float* __restrict__ g,
          const float* __restrict__ bb, bf16* __restrict__ xn)
{
    int t = blockIdx.x, tid = threadIdx.x;
    const float* xr = x + (size_t)t * DD;
    float4 v = *(const float4*)(xr + tid * 4);
    float s = v.x + v.y + v.z + v.w;
#pragma unroll
    for (int o = 32; o > 0; o >>= 1) s += __shfl_down(s, o, 64);
    __shared__ float r1[4], r2[4];
    if ((tid & 63) == 0) r1[tid >> 6] = s;
    __syncthreads();
    float mu = (r1[0] + r1[1] + r1[2] + r1[3]) * (1.f / DD);
    float d0 = v.x - mu, d1 = v.y - mu, d2 = v.z - mu, d3 = v.w - mu;
    float ss = d0 * d0 + d1 * d1 + d2 * d2 + d3 * d3;
#pragma unroll
    for (int o = 32; o > 0; o >>= 1) ss += __shfl_down(ss, o, 64);
    if ((tid & 63) == 0) r2[tid >> 6] = ss;
    __syncthreads();
    float var = (r2[0] + r2[1] + r2[2] + r2[3]) * (1.f / DD);
    float inv = rsqrtf(var + 1e-5f);
    int di = tid * 4;
    xn[(size_t)t * DD + di + 0] = f2b(d0 * inv * g[di + 0] + bb[di + 0]);
    xn[(size_t)t * DD + di + 1] = f2b(d1 * inv * g[di + 1] + bb[di + 1]);
    xn[(size_t)t * DD + di + 2] = f2b(d2 * inv * g[di + 2] + bb[di + 2]);
    xn[(size_t)t * DD + di + 3] = f2b(d3 * inv * g[di + 3] + bb[di + 3]);
}

// tiny head: actions = tanh(h2 @ w3 + b3)
__global__ void act3_k(const bf16* __restrict__ h2, const float* __restrict__ w3,
                       const float* __restrict__ b3, float* __restrict__ out)
{
    int idx = blockIdx.x * 256 + threadIdx.x;
    if (idx >= TT * AA) return;
    int t = idx / AA, a = idx - t * AA;
    float acc = b3[a];
    const bf16* hr = h2 + (size_t)t * 256;
    for (int k = 0; k < 256; ++k)
        acc = fmaf(b2f(hr[k]), w3[k * AA + a], acc);
    out[idx] = tanhf(acc);
}

// ---------------------------------------------------------------------------
extern "C" void kernel_launch(void* const* d_in, const int* in_sizes, int n_in,
                              void* d_out, int out_size, void* d_ws, size_t ws_size,
                              hipStream_t stream)
{
    (void)in_sizes; (void)n_in; (void)out_size; (void)ws_size;
    const float* features = (const float*)d_in[0];
    const float* in_proj_w = (const float*)d_in[1];
    const float* conv_w = (const float*)d_in[2];
    const float* conv_b = (const float*)d_in[3];
    const float* B_ssm = (const float*)d_in[4];
    const float* C_ssm = (const float*)d_in[5];
    const float* out_w = (const float*)d_in[6];
    const float* ln_g = (const float*)d_in[7];
    const float* ln_b = (const float*)d_in[8];
    const float* act_w1 = (const float*)d_in[9];
    const float* act_b1 = (const float*)d_in[10];
    const float* act_w2 = (const float*)d_in[11];
    const float* act_b2 = (const float*)d_in[12];
    const float* act_w3 = (const float*)d_in[13];
    const float* act_b3 = (const float*)d_in[14];
    const float* lang_w1 = (const float*)d_in[15];
    const float* lang_b1 = (const float*)d_in[16];
    const float* lang_w2 = (const float*)d_in[17];
    const float* lang_b2 = (const float*)d_in[18];

    static bool attr_done = false;
    if (!attr_done) {
        hipFuncSetAttribute((const void*)&g8_k<0>, hipFuncAttributeMaxDynamicSharedMemorySize, 131072);
        hipFuncSetAttribute((const void*)&g8_k<5>, hipFuncAttributeMaxDynamicSharedMemorySize, 131072);
        hipFuncSetAttribute((const void*)&g8h_k<3>, hipFuncAttributeMaxDynamicSharedMemorySize, 81920);
        attr_done = true;
    }

    char* p = (char*)d_ws;
    size_t off = 0;
    auto alloc = [&](size_t bytes) -> void* {
        void* q = p + off;
        off = (off + bytes + 255) & ~(size_t)255;
        return q;
    };
    float* x_f  = (float*)alloc((size_t)TT * DD * 4);     // fp32 residual stream
    bf16*  x_b  = (bf16*) alloc((size_t)TT * DD * 2);     // bf16 mirror
    bf16*  xz   = (bf16*) alloc((size_t)TT * 4096 * 2);   // in_proj out (xp|z)
    bf16*  xc   = (bf16*) alloc((size_t)TT * DDI * 2);    // conv out; later reused as y
    float* u    = (float*)alloc((size_t)TT * 16 * 4);
    float* up   = (float*)alloc((size_t)8 * TT * 16 * 4); // split-K partials
    float* hs   = (float*)alloc((size_t)TT * 16 * 4);     // scan out fp32
    bf16*  xn   = (bf16*) alloc((size_t)TT * DD * 2);
    bf16*  h1   = (bf16*) alloc((size_t)TT * 512 * 2);
    bf16*  h2   = (bf16*) alloc((size_t)TT * 256 * 2);
    bf16*  hl   = (bf16*) alloc((size_t)TT * DD * 2);
    bf16*  inwT = (bf16*) alloc((size_t)LL * 4096 * 1024 * 2);
    bf16*  owT  = (bf16*) alloc((size_t)LL * 1024 * 2048 * 2);
    bf16*  bmT  = (bf16*) alloc((size_t)LL * 128 * 2048 * 2);
    bf16*  a1T  = (bf16*) alloc((size_t)512 * 1024 * 2);
    bf16*  a2T  = (bf16*) alloc((size_t)256 * 512 * 2);
    bf16*  l1T  = (bf16*) alloc((size_t)1024 * 1024 * 2);
    bf16*  l2T  = (bf16*) alloc((size_t)VV * 1024 * 2);
    bf16*  y    = xc;   // xc dead once u is computed

    // ---- prep: fp32->bf16 + transpose all GEMM weights (per call) ----
    copyfeat_k<<<TT * DD / 1024, 256, 0, stream>>>(features, x_f, x_b);
    for (int l = 0; l < LL; ++l) {
        transpose_k<<<dim3(16, 64), 256, 0, stream>>>(in_proj_w + (size_t)l * 1024 * 4096,
                                                      inwT + (size_t)l * 4096 * 1024, 1024, 4096);
        transpose_k<<<dim3(32, 16), 256, 0, stream>>>(out_w + (size_t)l * 2048 * 1024,
                                                      owT + (size_t)l * 1024 * 2048, 2048, 1024);
        prep_bm_k<<<(128 * 2048) / 256, 256, 0, stream>>>(B_ssm + (size_t)l * 2048 * 16,
                                                          bmT + (size_t)l * 128 * 2048);
    }
    transpose_k<<<dim3(16, 8), 256, 0, stream>>>(act_w1, a1T, 1024, 512);
    transpose_k<<<dim3(8, 4), 256, 0, stream>>>(act_w2, a2T, 512, 256);
    transpose_k<<<dim3(16, 16), 256, 0, stream>>>(lang_w1, l1T, 1024, 1024);
    transpose_k<<<dim3(16, 500), 256, 0, stream>>>(lang_w2, l2T, 1024, VV);

    // ---- 6 mamba blocks ----
    for (int l = 0; l < LL; ++l) {
        // xz = x @ in_w : g8, 16x16 tiles of 256^2 -> 256 blocks
        g8_k<0><<<256, 512, 131072, stream>>>(x_b, inwT + (size_t)l * 4096 * 1024,
                                              1024, 16, 4096, nullptr, xz, nullptr);
        // xc = silu(causal_dwconv(xp) + cb)
        conv_k<<<TT * DDI / 256, 256, 0, stream>>>(xz, conv_w + (size_t)l * DDI * 4,
                                                   conv_b + (size_t)l * DDI, xc);
        // u = xc @ (Bm*0.1) : split-K 8x -> grid 256, then reduce
        usk_k<<<dim3(32, 8), 256, 0, stream>>>(xc, bmT + (size_t)l * 128 * 2048, up);
        ured_k<<<TT * 16 / 256, 256, 0, stream>>>(up, u);
        // hs = scan(u)  (fp32)
        scan2_k<<<8, 256, 0, stream>>>(u, hs);
        // y = (hs @ Cm) * silu(z)  : fused VALU kernel (BW-bound)
        yk_k<<<TT, 256, 0, stream>>>(hs, C_ssm + (size_t)l * 16 * 2048, xz, y);
        // x += y @ ow : g8h counted-vmcnt 128^2, grid 32x8=256, 2 blocks/CU
        g8h_k<3><<<256, 256, 81920, stream>>>(y, owT + (size_t)l * 1024 * 2048,
                                              2048, 32, 1024, x_f, x_b, nullptr);
    }

    // ---- LN + heads ----
    ln_k<<<TT, 256, 0, stream>>>(x_f, ln_g, ln_b, xn);
    gemm_k<4><<<dim3(32, 4), 256, 0, stream>>>(xn, a1T, 1024, 512, nullptr, h1, act_b1);
    gemm_k<4><<<dim3(32, 2), 256, 0, stream>>>(h1, a2T, 512, 256, nullptr, h2, act_b2);
    act3_k<<<(TT * AA + 255) / 256, 256, 0, stream>>>(h2, act_w3, act_b3, (float*)d_out);
    gemm_k<4><<<dim3(32, 8), 256, 0, stream>>>(xn, l1T, 1024, 1024, nullptr, hl, lang_b1);
    // logits: g8, 16 x 125 tiles of 256^2 -> 2000 blocks
    g8_k<5><<<2000, 512, 131072, stream>>>(hl, l2T, 1024, 16, VV,
                                           (float*)d_out + (size_t)TT * AA, nullptr, lang_b2);
}

// Round 12
// 1611.953 us; speedup vs baseline: 1.4737x; 1.0197x over previous
//
#include <hip/hip_runtime.h>
#include <hip/hip_bf16.h>
#include <cstdint>
#include <cstddef>

// Problem dims
#define TT 4096   // B*S tokens
#define SS 2048   // S
#define DD 1024   // D
#define DDI 2048  // DI
#define LL 6
#define VV 32000
#define AA 7

typedef __hip_bfloat16 bf16;
typedef __attribute__((ext_vector_type(8))) short bf16x8;   // 8 bf16 in 4 VGPRs
typedef __attribute__((ext_vector_type(4))) float f32x4;

typedef const __attribute__((address_space(1))) void* gas_ptr;
typedef __attribute__((address_space(3))) void* las_ptr;

static __device__ __forceinline__ float b2f(bf16 h) { return __bfloat162float(h); }
static __device__ __forceinline__ bf16 f2b(float f) { return __float2bfloat16(f); }
static __device__ __forceinline__ float bs2f(short x) {
    unsigned int u = ((unsigned int)(unsigned short)x) << 16;
    float f; __builtin_memcpy(&f, &u, 4); return f;
}
static __device__ __forceinline__ short f2bs(float f) {
    bf16 h = f2b(f); unsigned short us; __builtin_memcpy(&us, &h, 2); return (short)us;
}

// 64-B rows, 4x16B chunks; chunk ^= (row>>1)&3 -> verified 0 conflicts (R4/R5).
#define SWZ(off) ((off) ^ ((((off) >> 7) & 3) << 4))

// ---------------------------------------------------------------------------
// g8 (measured ~350us lang_w2; in_proj ~80us): 256x256 8-phase GEMM, BK=64,
// 8 waves. Two 4-slot rings of 16 KiB K-half tiles; counted vmcnt(10).
// EPI: 0 = store bf16; 5 = bias + f32 store.
// ---------------------------------------------------------------------------
template<int EPI>
__global__ __launch_bounds__(512, 2)
void g8_k(const bf16* __restrict__ A, const bf16* __restrict__ Wt,
          int K, int mx, int out_ld,
          float* __restrict__ of32, bf16* __restrict__ ob16,
          const float* __restrict__ bias)
{
    extern __shared__ char lds[];   // 131072
    const int nwg = gridDim.x;
    int l = blockIdx.x;
    if ((nwg & 7) == 0) l = (l & 7) * (nwg >> 3) + (l >> 3);   // XCD-chunked
    const int row0 = (l % mx) * 256, col0 = (l / mx) * 256;

    const int tid = threadIdx.x, wid = tid >> 6, lane = tid & 63;
    const int wr = wid >> 2, wc = wid & 3;        // 2M x 4N waves
    const int l15 = lane & 15, kq = lane >> 4;

    f32x4 acc[8][4];
#pragma unroll
    for (int m = 0; m < 8; ++m)
#pragma unroll
        for (int n = 0; n < 4; ++n) acc[m][n] = f32x4{0.f, 0.f, 0.f, 0.f};

    const int sr   = tid >> 2;
    const int colE = (((tid & 3) ^ ((tid >> 3) & 3)) * 8);
    const bf16* gA = A  + (size_t)(row0 + sr) * K + colE;
    const bf16* gB = Wt + (size_t)(col0 + sr) * K + colE;
    const int dst0 = tid * 16, dst1 = 8192 + tid * 16;

    auto stageA = [&](int kh) {
        char* b = lds + (kh & 3) * 16384;
        __builtin_amdgcn_global_load_lds((gas_ptr)(gA + kh * 32),                   (las_ptr)(b + dst0), 16, 0, 0);
        __builtin_amdgcn_global_load_lds((gas_ptr)(gA + (size_t)128 * K + kh * 32), (las_ptr)(b + dst1), 16, 0, 0);
    };
    auto stageB = [&](int kh) {
        char* b = lds + 65536 + (kh & 3) * 16384;
        __builtin_amdgcn_global_load_lds((gas_ptr)(gB + kh * 32),                   (las_ptr)(b + dst0), 16, 0, 0);
        __builtin_amdgcn_global_load_lds((gas_ptr)(gB + (size_t)128 * K + kh * 32), (las_ptr)(b + dst1), 16, 0, 0);
    };

    const int NT = K >> 6, KH = K >> 5;
    stageA(0); stageB(0); stageA(1); stageB(1);
    stageA(2); stageB(2); stageA(3); stageB(3);
    int nextA = 4, nextB = 4;

    for (int t = 0; t < NT; ++t) {
        const char* As0 = lds + ((2 * t) & 3) * 16384;
        const char* As1 = lds + ((2 * t + 1) & 3) * 16384;
        const char* Bs0 = lds + 65536 + ((2 * t) & 3) * 16384;
        const char* Bs1 = lds + 65536 + ((2 * t + 1) & 3) * 16384;
        bf16x8 af[4], bfg[4];

        // q0
        if (t < NT - 3) asm volatile("s_waitcnt vmcnt(10)" ::: "memory");
        else            asm volatile("s_waitcnt vmcnt(0)" ::: "memory");
        __builtin_amdgcn_sched_barrier(0);
        __builtin_amdgcn_s_barrier();
        __builtin_amdgcn_sched_barrier(0);
#pragma unroll
        for (int fn = 0; fn < 4; ++fn)
            bfg[fn] = *(const bf16x8*)(Bs0 + SWZ((wc * 64 + fn * 16 + l15) * 64 + kq * 16));
#pragma unroll
        for (int fm = 0; fm < 4; ++fm)
            af[fm] = *(const bf16x8*)(As0 + SWZ((wr * 128 + fm * 16 + l15) * 64 + kq * 16));
        if (t > 0 && nextA < KH) { stageA(nextA); ++nextA; }
        asm volatile("s_waitcnt lgkmcnt(0)" ::: "memory");
        __builtin_amdgcn_sched_barrier(0);
        __builtin_amdgcn_s_setprio(1);
#pragma unroll
        for (int fm = 0; fm < 4; ++fm)
#pragma unroll
            for (int fn = 0; fn < 4; ++fn)
                acc[fm][fn] = __builtin_amdgcn_mfma_f32_16x16x32_bf16(af[fm], bfg[fn], acc[fm][fn], 0, 0, 0);
        __builtin_amdgcn_s_setprio(0);
        __builtin_amdgcn_sched_barrier(0);
        __builtin_amdgcn_s_barrier();
        __builtin_amdgcn_sched_barrier(0);

        // q1 (A mh1 of ks0; B reg-reused)
#pragma unroll
        for (int fm = 0; fm < 4; ++fm)
            af[fm] = *(const bf16x8*)(As0 + SWZ((wr * 128 + 64 + fm * 16 + l15) * 64 + kq * 16));
        if (nextB < KH) { stageB(nextB); ++nextB; }
        asm volatile("s_waitcnt lgkmcnt(0)" ::: "memory");
        __builtin_amdgcn_sched_barrier(0);
        __builtin_amdgcn_s_setprio(1);
#pragma unroll
        for (int fm = 0; fm < 4; ++fm)
#pragma unroll
            for (int fn = 0; fn < 4; ++fn)
                acc[4 + fm][fn] = __builtin_amdgcn_mfma_f32_16x16x32_bf16(af[fm], bfg[fn], acc[4 + fm][fn], 0, 0, 0);
        __builtin_amdgcn_s_setprio(0);
        __builtin_amdgcn_sched_barrier(0);
        __builtin_amdgcn_s_barrier();
        __builtin_amdgcn_sched_barrier(0);

        // q2
        if (t < NT - 3) asm volatile("s_waitcnt vmcnt(10)" ::: "memory");
        else            asm volatile("s_waitcnt vmcnt(0)" ::: "memory");
        __builtin_amdgcn_sched_barrier(0);
        __builtin_amdgcn_s_barrier();
        __builtin_amdgcn_sched_barrier(0);
#pragma unroll
        for (int fn = 0; fn < 4; ++fn)
            bfg[fn] = *(const bf16x8*)(Bs1 + SWZ((wc * 64 + fn * 16 + l15) * 64 + kq * 16));
#pragma unroll
        for (int fm = 0; fm < 4; ++fm)
            af[fm] = *(const bf16x8*)(As1 + SWZ((wr * 128 + fm * 16 + l15) * 64 + kq * 16));
        if (nextA < KH) { stageA(nextA); ++nextA; }
        asm volatile("s_waitcnt lgkmcnt(0)" ::: "memory");
        __builtin_amdgcn_sched_barrier(0);
        __builtin_amdgcn_s_setprio(1);
#pragma unroll
        for (int fm = 0; fm < 4; ++fm)
#pragma unroll
            for (int fn = 0; fn < 4; ++fn)
                acc[fm][fn] = __builtin_amdgcn_mfma_f32_16x16x32_bf16(af[fm], bfg[fn], acc[fm][fn], 0, 0, 0);
        __builtin_amdgcn_s_setprio(0);
        __builtin_amdgcn_sched_barrier(0);
        __builtin_amdgcn_s_barrier();
        __builtin_amdgcn_sched_barrier(0);

        // q3 (A mh1 of ks1; B reg-reused)
#pragma unroll
        for (int fm = 0; fm < 4; ++fm)
            af[fm] = *(const bf16x8*)(As1 + SWZ((wr * 128 + 64 + fm * 16 + l15) * 64 + kq * 16));
        if (nextB < KH) { stageB(nextB); ++nextB; }
        asm volatile("s_waitcnt lgkmcnt(0)" ::: "memory");
        __builtin_amdgcn_sched_barrier(0);
        __builtin_amdgcn_s_setprio(1);
#pragma unroll
        for (int fm = 0; fm < 4; ++fm)
#pragma unroll
            for (int fn = 0; fn < 4; ++fn)
                acc[4 + fm][fn] = __builtin_amdgcn_mfma_f32_16x16x32_bf16(af[fm], bfg[fn], acc[4 + fm][fn], 0, 0, 0);
        __builtin_amdgcn_s_setprio(0);
        __builtin_amdgcn_sched_barrier(0);
        __builtin_amdgcn_s_barrier();
        __builtin_amdgcn_sched_barrier(0);
    }

#pragma unroll
    for (int fm = 0; fm < 8; ++fm) {
#pragma unroll
        for (int fn = 0; fn < 4; ++fn) {
#pragma unroll
            for (int r = 0; r < 4; ++r) {
                const int row = row0 + wr * 128 + fm * 16 + kq * 4 + r;
                const int col = col0 + wc * 64 + fn * 16 + l15;
                float v = acc[fm][fn][r];
                if (EPI == 0) ob16[(size_t)row * out_ld + col] = f2b(v);
                else          of32[(size_t)row * out_ld + col] = v + bias[col];
            }
        }
    }
}

// ---------------------------------------------------------------------------
// g8h: 128x128 counted-vmcnt GEMM (R11, ow).  EPI: 3 = residual f32 + bf16.
// ---------------------------------------------------------------------------
template<int EPI>
__global__ __launch_bounds__(256, 2)
void g8h_k(const bf16* __restrict__ A, const bf16* __restrict__ Wt,
           int K, int mx, int out_ld,
           float* __restrict__ of32, bf16* __restrict__ ob16,
           const float* __restrict__ bias)
{
    extern __shared__ char lds[];   // 81920
    const int nwg = gridDim.x;
    int l = blockIdx.x;
    if ((nwg & 7) == 0) l = (l & 7) * (nwg >> 3) + (l >> 3);   // XCD-chunked
    const int row0 = (l % mx) * 128, col0 = (l / mx) * 128;

    const int tid = threadIdx.x, wid = tid >> 6, lane = tid & 63;
    const int wr = wid >> 1, wc = wid & 1;        // 2M x 2N waves
    const int l15 = lane & 15, kq = lane >> 4;

    f32x4 acc[4][4];
#pragma unroll
    for (int m = 0; m < 4; ++m)
#pragma unroll
        for (int n = 0; n < 4; ++n) acc[m][n] = f32x4{0.f, 0.f, 0.f, 0.f};

    const int sr   = tid >> 2;                        // 0..63
    const int colE = (((tid & 3) ^ ((tid >> 3) & 3)) * 8);
    const bf16* gA = A  + (size_t)(row0 + sr) * K + colE;
    const bf16* gB = Wt + (size_t)(col0 + sr) * K + colE;
    const int dst0 = tid * 16, dst1 = 4096 + tid * 16;

    auto stage = [&](int kh) {
        char* a = lds + (kh % 5) * 8192;
        char* b = lds + 40960 + (kh % 5) * 8192;
        __builtin_amdgcn_global_load_lds((gas_ptr)(gA + kh * 32),                  (las_ptr)(a + dst0), 16, 0, 0);
        __builtin_amdgcn_global_load_lds((gas_ptr)(gA + (size_t)64 * K + kh * 32), (las_ptr)(a + dst1), 16, 0, 0);
        __builtin_amdgcn_global_load_lds((gas_ptr)(gB + kh * 32),                  (las_ptr)(b + dst0), 16, 0, 0);
        __builtin_amdgcn_global_load_lds((gas_ptr)(gB + (size_t)64 * K + kh * 32), (las_ptr)(b + dst1), 16, 0, 0);
    };

    const int KH = K >> 5;
    stage(0); stage(1); stage(2); stage(3);

    for (int kh = 0; kh < KH; ++kh) {
        const int rem = KH - 1 - kh;
        if (rem >= 3)      asm volatile("s_waitcnt vmcnt(12)" ::: "memory");
        else if (rem == 2) asm volatile("s_waitcnt vmcnt(8)" ::: "memory");
        else if (rem == 1) asm volatile("s_waitcnt vmcnt(4)" ::: "memory");
        else               asm volatile("s_waitcnt vmcnt(0)" ::: "memory");
        __builtin_amdgcn_sched_barrier(0);
        __builtin_amdgcn_s_barrier();
        __builtin_amdgcn_sched_barrier(0);

        const char* As = lds + (kh % 5) * 8192;
        const char* Bs = lds + 40960 + (kh % 5) * 8192;
        bf16x8 af[4], bfg[4];
#pragma unroll
        for (int fn = 0; fn < 4; ++fn)
            bfg[fn] = *(const bf16x8*)(Bs + SWZ((wc * 64 + fn * 16 + l15) * 64 + kq * 16));
#pragma unroll
        for (int fm = 0; fm < 4; ++fm)
            af[fm] = *(const bf16x8*)(As + SWZ((wr * 64 + fm * 16 + l15) * 64 + kq * 16));
        if (kh + 4 < KH) stage(kh + 4);
        asm volatile("s_waitcnt lgkmcnt(0)" ::: "memory");
        __builtin_amdgcn_sched_barrier(0);
        __builtin_amdgcn_s_setprio(1);
#pragma unroll
        for (int fm = 0; fm < 4; ++fm)
#pragma unroll
            for (int fn = 0; fn < 4; ++fn)
                acc[fm][fn] = __builtin_amdgcn_mfma_f32_16x16x32_bf16(af[fm], bfg[fn], acc[fm][fn], 0, 0, 0);
        __builtin_amdgcn_s_setprio(0);
        __builtin_amdgcn_sched_barrier(0);
    }

#pragma unroll
    for (int fm = 0; fm < 4; ++fm) {
#pragma unroll
        for (int fn = 0; fn < 4; ++fn) {
#pragma unroll
            for (int r = 0; r < 4; ++r) {
                const int row = row0 + wr * 64 + fm * 16 + kq * 4 + r;
                const int col = col0 + wc * 64 + fn * 16 + l15;
                float v = acc[fm][fn][r];
                if (EPI == 3) {
                    float rr = of32[(size_t)row * out_ld + col] + v;
                    of32[(size_t)row * out_ld + col] = rr;
                    ob16[(size_t)row * out_ld + col] = f2b(rr);
                } else {
                    ob16[(size_t)row * out_ld + col] = f2b(v);
                }
            }
        }
    }
}

// ---------------------------------------------------------------------------
// 128x128 m97-structure GEMM.  EPI: 4=bias+relu bf16
// ---------------------------------------------------------------------------
template<int EPI>
__global__ __launch_bounds__(256)
void gemm_k(const bf16* __restrict__ A, const bf16* __restrict__ Wt,
            int K, int out_ld,
            float* __restrict__ of32, bf16* __restrict__ ob16,
            const float* __restrict__ bias)
{
    __shared__ bf16x8 lsA8[128 * 4];
    __shared__ bf16x8 lsB8[128 * 4];
    bf16* lsA = (bf16*)lsA8;
    bf16* lsB = (bf16*)lsB8;

    const int tid  = threadIdx.x;
    const int w    = tid >> 6;
    const int lane = tid & 63;
    const int row0 = blockIdx.x * 128;
    const int col0 = blockIdx.y * 128;
    const int wr   = (w >> 1) * 64;
    const int wc   = (w & 1) * 64;
    const int l15  = lane & 15;
    const int kq   = lane >> 4;

    f32x4 acc[4][4];
#pragma unroll
    for (int m = 0; m < 4; ++m)
#pragma unroll
        for (int n = 0; n < 4; ++n) acc[m][n] = f32x4{0.f, 0.f, 0.f, 0.f};

    const int s0 = tid, s1 = tid + 256;
    const size_t ga0 = (size_t)(row0 + (s0 >> 2)) * K + (s0 & 3) * 8;
    const size_t ga1 = (size_t)(row0 + (s1 >> 2)) * K + (s1 & 3) * 8;
    const size_t gb0 = (size_t)(col0 + (s0 >> 2)) * K + (s0 & 3) * 8;
    const size_t gb1 = (size_t)(col0 + (s1 >> 2)) * K + (s1 & 3) * 8;
    bf16* la0 = lsA + (size_t)(w * 64) * 8;
    bf16* la1 = lsA + (size_t)(256 + w * 64) * 8;
    bf16* lb0 = lsB + (size_t)(w * 64) * 8;
    bf16* lb1 = lsB + (size_t)(256 + w * 64) * 8;

    for (int k0 = 0; k0 < K; k0 += 32) {
        __builtin_amdgcn_global_load_lds((gas_ptr)(A  + ga0 + k0), (las_ptr)la0, 16, 0, 0);
        __builtin_amdgcn_global_load_lds((gas_ptr)(A  + ga1 + k0), (las_ptr)la1, 16, 0, 0);
        __builtin_amdgcn_global_load_lds((gas_ptr)(Wt + gb0 + k0), (las_ptr)lb0, 16, 0, 0);
        __builtin_amdgcn_global_load_lds((gas_ptr)(Wt + gb1 + k0), (las_ptr)lb1, 16, 0, 0);
        __syncthreads();

        bf16x8 af[4], bfr[4];
#pragma unroll
        for (int m = 0; m < 4; ++m)
            af[m] = *(const bf16x8*)(lsA + (size_t)(wr + m * 16 + l15) * 32 + kq * 8);
#pragma unroll
        for (int n = 0; n < 4; ++n)
            bfr[n] = *(const bf16x8*)(lsB + (size_t)(wc + n * 16 + l15) * 32 + kq * 8);
#pragma unroll
        for (int m = 0; m < 4; ++m)
#pragma unroll
            for (int n = 0; n < 4; ++n)
                acc[m][n] = __builtin_amdgcn_mfma_f32_16x16x32_bf16(af[m], bfr[n], acc[m][n], 0, 0, 0);
        __syncthreads();
    }

#pragma unroll
    for (int m = 0; m < 4; ++m) {
#pragma unroll
        for (int n = 0; n < 4; ++n) {
#pragma unroll
            for (int r = 0; r < 4; ++r) {
                const int row = row0 + wr + m * 16 + kq * 4 + r;
                const int col = col0 + wc + n * 16 + l15;
                float v = acc[m][n][r];
                v = fmaxf(v + bias[col], 0.f);
                ob16[(size_t)row * out_ld + col] = f2b(v);
            }
        }
    }
}

// ---------------------------------------------------------------------------
// Fused conv + split-K skinny u-GEMM (R12):
// A-tile = silu(dwconv(xz_xp)+cb) computed in-register and ds_written to the
// SAME linear LDS layout usk_k used (tid*16B) -> read side unchanged.
// B staged via global_load_lds from bmT (padded, x0.1 folded).
// up[spl][T][16] partials; grid (32, 8). Bit-identical numerics to
// conv_k + usk_k (fp32 conv -> bf16 round -> MFMA).
// ---------------------------------------------------------------------------
__global__ __launch_bounds__(256)
void cusk_k(const bf16* __restrict__ xz, const float* __restrict__ cw,
            const float* __restrict__ cb, const bf16* __restrict__ Wt,
            float* __restrict__ up)
{
    __shared__ bf16x8 lsA8[128 * 4];
    __shared__ bf16x8 lsB8[128 * 4];
    bf16* lsA = (bf16*)lsA8;
    bf16* lsB = (bf16*)lsB8;
    const int K = 2048;

    const int tid  = threadIdx.x;
    const int w    = tid >> 6;
    const int lane = tid & 63;
    const int row0 = blockIdx.x * 128;
    const int spl  = blockIdx.y;          // 0..7
    const int kbeg = spl * 256;
    const int wr   = (w >> 1) * 64;
    const int wc   = (w & 1) * 64;
    const int l15  = lane & 15;
    const int kq   = lane >> 4;

    f32x4 acc[4][4];
#pragma unroll
    for (int m = 0; m < 4; ++m)
#pragma unroll
        for (int n = 0; n < 4; ++n) acc[m][n] = f32x4{0.f, 0.f, 0.f, 0.f};

    // A staging coords: thread covers rows r0g (slot tid) and r1g (slot tid+256),
    // cols i0..i0+7 of xc, where xc = silu(conv(xz[:, :2048])).
    const int trow = tid >> 2, tch = tid & 3;
    const int r0g = row0 + trow, r1g = r0g + 64;
    const int sq0 = r0g & (SS - 1), sq1 = r1g & (SS - 1);

    // B staging (unchanged from usk_k)
    const int s0 = tid, s1 = tid + 256;
    const size_t gb0 = (size_t)(s0 >> 2) * K + (s0 & 3) * 8;
    const size_t gb1 = (size_t)(s1 >> 2) * K + (s1 & 3) * 8;
    bf16* lb0 = lsB + (size_t)(w * 64) * 8;
    bf16* lb1 = lsB + (size_t)(256 + w * 64) * 8;

    for (int k0 = kbeg; k0 < kbeg + 256; k0 += 32) {
        const int i0 = k0 + tch * 8;       // channel base (< 2048)

        // B: async stage
        __builtin_amdgcn_global_load_lds((gas_ptr)(Wt + gb0 + k0), (las_ptr)lb0, 16, 0, 0);
        __builtin_amdgcn_global_load_lds((gas_ptr)(Wt + gb1 + k0), (las_ptr)lb1, 16, 0, 0);

        // A: in-register conv for rows r0g, r1g, channels i0..i0+7
        bf16x8 vA0, vA1;
        {
            const bf16* b0 = xz + (size_t)r0g * 4096 + i0;
            bf16x8 x0 = *(const bf16x8*)b0;
            bf16x8 x1 = {}, x2 = {}, x3 = {};
            if (sq0 >= 1) x1 = *(const bf16x8*)(b0 - 4096);
            if (sq0 >= 2) x2 = *(const bf16x8*)(b0 - 2 * 4096);
            if (sq0 >= 3) x3 = *(const bf16x8*)(b0 - 3 * 4096);
#pragma unroll
            for (int c = 0; c < 8; ++c) {
                float4 wv4 = ((const float4*)cw)[i0 + c];
                float a = cb[i0 + c];
                a = fmaf(bs2f(x3[c]), wv4.x, a);
                a = fmaf(bs2f(x2[c]), wv4.y, a);
                a = fmaf(bs2f(x1[c]), wv4.z, a);
                a = fmaf(bs2f(x0[c]), wv4.w, a);
                float sig = 1.f / (1.f + expf(-a));
                vA0[c] = f2bs(a * sig);
            }
        }
        {
            const bf16* b0 = xz + (size_t)r1g * 4096 + i0;
            bf16x8 x0 = *(const bf16x8*)b0;
            bf16x8 x1 = {}, x2 = {}, x3 = {};
            if (sq1 >= 1) x1 = *(const bf16x8*)(b0 - 4096);
            if (sq1 >= 2) x2 = *(const bf16x8*)(b0 - 2 * 4096);
            if (sq1 >= 3) x3 = *(const bf16x8*)(b0 - 3 * 4096);
#pragma unroll
            for (int c = 0; c < 8; ++c) {
                float4 wv4 = ((const float4*)cw)[i0 + c];
                float a = cb[i0 + c];
                a = fmaf(bs2f(x3[c]), wv4.x, a);
                a = fmaf(bs2f(x2[c]), wv4.y, a);
                a = fmaf(bs2f(x1[c]), wv4.z, a);
                a = fmaf(bs2f(x0[c]), wv4.w, a);
                float sig = 1.f / (1.f + expf(-a));
                vA1[c] = f2bs(a * sig);
            }
        }
        // A: ds_write to the same linear slots global_load_lds used before
        lsA8[tid] = vA0;
        lsA8[tid + 256] = vA1;
        __syncthreads();

        bf16x8 af[4], bfr[4];
#pragma unroll
        for (int m = 0; m < 4; ++m)
            af[m] = *(const bf16x8*)(lsA + (size_t)(wr + m * 16 + l15) * 32 + kq * 8);
#pragma unroll
        for (int n = 0; n < 4; ++n)
            bfr[n] = *(const bf16x8*)(lsB + (size_t)(wc + n * 16 + l15) * 32 + kq * 8);
#pragma unroll
        for (int m = 0; m < 4; ++m)
#pragma unroll
            for (int n = 0; n < 4; ++n)
                acc[m][n] = __builtin_amdgcn_mfma_f32_16x16x32_bf16(af[m], bfr[n], acc[m][n], 0, 0, 0);
        __syncthreads();
    }

    if (wc == 0) {
#pragma unroll
        for (int m = 0; m < 4; ++m)
#pragma unroll
            for (int r = 0; r < 4; ++r) {
                const int row = row0 + wr + m * 16 + kq * 4 + r;
                up[(size_t)spl * TT * 16 + (size_t)row * 16 + l15] = acc[m][0][r];
            }
    }
}

// reduce the 8 K-split partials: u = sum_s up[s]
__global__ void ured_k(const float* __restrict__ up, float* __restrict__ u)
{
    int i = blockIdx.x * 256 + threadIdx.x;   // TT*16 = 65536
    float s = 0.f;
#pragma unroll
    for (int k = 0; k < 8; ++k) s += up[(size_t)k * TT * 16 + i];
    u[i] = s;
}

// ---------------------------------------------------------------------------
// fp32 [K,N] -> bf16 [N,K] transpose (64x64 tiles through LDS)
// ---------------------------------------------------------------------------
__global__ __launch_bounds__(256)
void transpose_k(const float* __restrict__ W, bf16* __restrict__ WT, int K, int N)
{
    __shared__ bf16 t[64][66];
    const int k0 = blockIdx.x * 64, n0 = blockIdx.y * 64;
    const int tid = threadIdx.x;
#pragma unroll
    for (int i = 0; i < 16; ++i) {
        int idx = i * 256 + tid;
        int kk = idx >> 6, nn = idx & 63;
        t[nn][kk] = f2b(W[(size_t)(k0 + kk) * N + n0 + nn]);
    }
    __syncthreads();
#pragma unroll
    for (int i = 0; i < 16; ++i) {
        int idx = i * 256 + tid;
        int nn = idx >> 6, kk = idx & 63;
        WT[(size_t)(n0 + nn) * K + k0 + kk] = t[nn][kk];
    }
}

// B_ssm [DI,16] fp32 -> bf16 [128,DI] padded, x0.1 folded in
__global__ void prep_bm_k(const float* __restrict__ Bm, bf16* __restrict__ BmT)
{
    int idx = blockIdx.x * 256 + threadIdx.x;   // 128*2048
    int n = idx >> 11, k = idx & 2047;
    float v = (n < 16) ? Bm[(size_t)k * 16 + n] * 0.1f : 0.f;
    BmT[idx] = f2b(v);
}

// features -> fp32 residual copy + bf16 copy
__global__ void copyfeat_k(const float* __restrict__ f, float* __restrict__ xf,
                           bf16* __restrict__ xb)
{
    int i = (blockIdx.x * 256 + threadIdx.x) * 4;
    float4 v = *(const float4*)(f + i);
    *(float4*)(xf + i) = v;
    xb[i + 0] = f2b(v.x);
    xb[i + 1] = f2b(v.y);
    xb[i + 2] = f2b(v.z);
    xb[i + 3] = f2b(v.w);
}

// ---------------------------------------------------------------------------
// scan h_t = 0.9 h + u_t; chunk=32 tokens, redundant 96-step warmup; fp32 out.
// ---------------------------------------------------------------------------
__global__ void scan2_k(const float* __restrict__ u, float* __restrict__ hs)
{
    int gid = blockIdx.x * 256 + threadIdx.x;   // 2048 total
    int n = gid & 15, c = (gid >> 4) & 63, b = gid >> 10;
    int start = c * 32;
    const float* ub = u + (size_t)b * SS * 16;
    float* hb = hs + (size_t)b * SS * 16;
    float h = 0.f;
    int w0 = start - 96; if (w0 < 0) w0 = 0;
    for (int t = w0; t < start; ++t) h = 0.9f * h + ub[(size_t)t * 16 + n];
    for (int t = start; t < start + 32; ++t) {
        h = 0.9f * h + ub[(size_t)t * 16 + n];
        hb[(size_t)t * 16 + n] = h;
    }
}

// ---------------------------------------------------------------------------
// y[t,i] = (sum_n hs[t,n] * Cm[n,i]) * silu(z[t,i])
// ---------------------------------------------------------------------------
__global__ __launch_bounds__(256)
void yk_k(const float* __restrict__ hs, const float* __restrict__ Cm,
          const bf16* __restrict__ xz, bf16* __restrict__ y)
{
    const int t = blockIdx.x, i0 = threadIdx.x * 8;
    const float* h = hs + (size_t)t * 16;
    float o[8] = {0.f, 0.f, 0.f, 0.f, 0.f, 0.f, 0.f, 0.f};
#pragma unroll
    for (int n = 0; n < 16; ++n) {
        float hn = h[n];
        const float4* c = (const float4*)(Cm + (size_t)n * DDI + i0);
        float4 c0 = c[0], c1 = c[1];
        o[0] = fmaf(hn, c0.x, o[0]); o[1] = fmaf(hn, c0.y, o[1]);
        o[2] = fmaf(hn, c0.z, o[2]); o[3] = fmaf(hn, c0.w, o[3]);
        o[4] = fmaf(hn, c1.x, o[4]); o[5] = fmaf(hn, c1.y, o[5]);
        o[6] = fmaf(hn, c1.z, o[6]); o[7] = fmaf(hn, c1.w, o[7]);
    }
    bf16x8 zv = *(const bf16x8*)(xz + (size_t)t * 4096 + 2048 + i0);
    bf16* yo = y + (size_t)t * DDI + i0;
#pragma unroll
    for (int j = 0; j < 8; ++j) {
        float zf = bs2f(zv[j]);
        yo[j] = f2b(o[j] * (zf / (1.f + expf(-zf))));
    }
}

// LayerNorm fp32 -> bf16
__global__ __launch_bounds__(256)
void ln_k(const float* __restrict__ x, const float* __restrict__ g,
          const float* __restrict__ bb, bf16* __restrict__ xn)
{
    int t = blockIdx.x, tid = threadIdx.x;
    const float* xr = x + (size_t)t * DD;
    float4 v = *(const float4*)(xr + tid * 4);
    float s = v.x + v.y + v.z + v.w;
#pragma unroll
    for (int o = 32; o > 0; o >>= 1) s += __shfl_down(s, o, 64);
    __shared__ float r1[4], r2[4];
    if ((tid & 63) == 0) r1[tid >> 6] = s;
    __syncthreads();
    float mu = (r1[0] + r1[1] + r1[2] + r1[3]) * (1.f / DD);
    float d0 = v.x - mu, d1 = v.y - mu, d2 = v.z - mu, d3 = v.w - mu;
    float ss = d0 * d0 + d1 * d1 + d2 * d2 + d3 * d3;
#pragma unroll
    for (int o = 32; o > 0; o >>= 1) ss += __shfl_down(ss, o, 64);
    if ((tid & 63) == 0) r2[tid >> 6] = ss;
    __syncthreads();
    float var = (r2[0] + r2[1] + r2[2] + r2[3]) * (1.f / DD);
    float inv = rsqrtf(var + 1e-5f);
    int di = tid * 4;
    xn[(size_t)t * DD + di + 0] = f2b(d0 * inv * g[di + 0] + bb[di + 0]);
    xn[(size_t)t * DD + di + 1] = f2b(d1 * inv * g[di + 1] + bb[di + 1]);
    xn[(size_t)t * DD + di + 2] = f2b(d2 * inv * g[di + 2] + bb[di + 2]);
    xn[(size_t)t * DD + di + 3] = f2b(d3 * inv * g[di + 3] + bb[di + 3]);
}

// tiny head: actions = tanh(h2 @ w3 + b3)
__global__ void act3_k(const bf16* __restrict__ h2, const float* __restrict__ w3,
                       const float* __restrict__ b3, float* __restrict__ out)
{
    int idx = blockIdx.x * 256 + threadIdx.x;
    if (idx >= TT * AA) return;
    int t = idx / AA, a = idx - t * AA;
    float acc = b3[a];
    const bf16* hr = h2 + (size_t)t * 256;
    for (int k = 0; k < 256; ++k)
        acc = fmaf(b2f(hr[k]), w3[k * AA + a], acc);
    out[idx] = tanhf(acc);
}

// ---------------------------------------------------------------------------
extern "C" void kernel_launch(void* const* d_in, const int* in_sizes, int n_in,
                              void* d_out, int out_size, void* d_ws, size_t ws_size,
                              hipStream_t stream)
{
    (void)in_sizes; (void)n_in; (void)out_size; (void)ws_size;
    const float* features = (const float*)d_in[0];
    const float* in_proj_w = (const float*)d_in[1];
    const float* conv_w = (const float*)d_in[2];
    const float* conv_b = (const float*)d_in[3];
    const float* B_ssm = (const float*)d_in[4];
    const float* C_ssm = (const float*)d_in[5];
    const float* out_w = (const float*)d_in[6];
    const float* ln_g = (const float*)d_in[7];
    const float* ln_b = (const float*)d_in[8];
    const float* act_w1 = (const float*)d_in[9];
    const float* act_b1 = (const float*)d_in[10];
    const float* act_w2 = (const float*)d_in[11];
    const float* act_b2 = (const float*)d_in[12];
    const float* act_w3 = (const float*)d_in[13];
    const float* act_b3 = (const float*)d_in[14];
    const float* lang_w1 = (const float*)d_in[15];
    const float* lang_b1 = (const float*)d_in[16];
    const float* lang_w2 = (const float*)d_in[17];
    const float* lang_b2 = (const float*)d_in[18];

    static bool attr_done = false;
    if (!attr_done) {
        hipFuncSetAttribute((const void*)&g8_k<0>, hipFuncAttributeMaxDynamicSharedMemorySize, 131072);
        hipFuncSetAttribute((const void*)&g8_k<5>, hipFuncAttributeMaxDynamicSharedMemorySize, 131072);
        hipFuncSetAttribute((const void*)&g8h_k<3>, hipFuncAttributeMaxDynamicSharedMemorySize, 81920);
        attr_done = true;
    }

    char* p = (char*)d_ws;
    size_t off = 0;
    auto alloc = [&](size_t bytes) -> void* {
        void* q = p + off;
        off = (off + bytes + 255) & ~(size_t)255;
        return q;
    };
    float* x_f  = (float*)alloc((size_t)TT * DD * 4);     // fp32 residual stream
    bf16*  x_b  = (bf16*) alloc((size_t)TT * DD * 2);     // bf16 mirror
    bf16*  xz   = (bf16*) alloc((size_t)TT * 4096 * 2);   // in_proj out (xp|z)
    bf16*  y    = (bf16*) alloc((size_t)TT * DDI * 2);    // gated SSM out
    float* u    = (float*)alloc((size_t)TT * 16 * 4);
    float* up   = (float*)alloc((size_t)8 * TT * 16 * 4); // split-K partials
    float* hs   = (float*)alloc((size_t)TT * 16 * 4);     // scan out fp32
    bf16*  xn   = (bf16*) alloc((size_t)TT * DD * 2);
    bf16*  h1   = (bf16*) alloc((size_t)TT * 512 * 2);
    bf16*  h2   = (bf16*) alloc((size_t)TT * 256 * 2);
    bf16*  hl   = (bf16*) alloc((size_t)TT * DD * 2);
    bf16*  inwT = (bf16*) alloc((size_t)LL * 4096 * 1024 * 2);
    bf16*  owT  = (bf16*) alloc((size_t)LL * 1024 * 2048 * 2);
    bf16*  bmT  = (bf16*) alloc((size_t)LL * 128 * 2048 * 2);
    bf16*  a1T  = (bf16*) alloc((size_t)512 * 1024 * 2);
    bf16*  a2T  = (bf16*) alloc((size_t)256 * 512 * 2);
    bf16*  l1T  = (bf16*) alloc((size_t)1024 * 1024 * 2);
    bf16*  l2T  = (bf16*) alloc((size_t)VV * 1024 * 2);

    // ---- prep: fp32->bf16 + transpose all GEMM weights (per call) ----
    copyfeat_k<<<TT * DD / 1024, 256, 0, stream>>>(features, x_f, x_b);
    for (int l = 0; l < LL; ++l) {
        transpose_k<<<dim3(16, 64), 256, 0, stream>>>(in_proj_w + (size_t)l * 1024 * 4096,
                                                      inwT + (size_t)l * 4096 * 1024, 1024, 4096);
        transpose_k<<<dim3(32, 16), 256, 0, stream>>>(out_w + (size_t)l * 2048 * 1024,
                                                      owT + (size_t)l * 1024 * 2048, 2048, 1024);
        prep_bm_k<<<(128 * 2048) / 256, 256, 0, stream>>>(B_ssm + (size_t)l * 2048 * 16,
                                                          bmT + (size_t)l * 128 * 2048);
    }
    transpose_k<<<dim3(16, 8), 256, 0, stream>>>(act_w1, a1T, 1024, 512);
    transpose_k<<<dim3(8, 4), 256, 0, stream>>>(act_w2, a2T, 512, 256);
    transpose_k<<<dim3(16, 16), 256, 0, stream>>>(lang_w1, l1T, 1024, 1024);
    transpose_k<<<dim3(16, 500), 256, 0, stream>>>(lang_w2, l2T, 1024, VV);

    // ---- 6 mamba blocks ----
    for (int l = 0; l < LL; ++l) {
        // xz = x @ in_w : g8, 16x16 tiles of 256^2 -> 256 blocks
        g8_k<0><<<256, 512, 131072, stream>>>(x_b, inwT + (size_t)l * 4096 * 1024,
                                              1024, 16, 4096, nullptr, xz, nullptr);
        // u = 0.1 * silu(conv(xp)+cb) @ Bm : fused conv + split-K GEMM
        cusk_k<<<dim3(32, 8), 256, 0, stream>>>(xz, conv_w + (size_t)l * DDI * 4,
                                                conv_b + (size_t)l * DDI,
                                                bmT + (size_t)l * 128 * 2048, up);
        ured_k<<<TT * 16 / 256, 256, 0, stream>>>(up, u);
        // hs = scan(u)  (fp32)
        scan2_k<<<8, 256, 0, stream>>>(u, hs);
        // y = (hs @ Cm) * silu(z)  : fused VALU kernel (BW-bound)
        yk_k<<<TT, 256, 0, stream>>>(hs, C_ssm + (size_t)l * 16 * 2048, xz, y);
        // x += y @ ow : g8h counted-vmcnt 128^2, grid 32x8=256, 2 blocks/CU
        g8h_k<3><<<256, 256, 81920, stream>>>(y, owT + (size_t)l * 1024 * 2048,
                                              2048, 32, 1024, x_f, x_b, nullptr);
    }

    // ---- LN + heads ----
    ln_k<<<TT, 256, 0, stream>>>(x_f, ln_g, ln_b, xn);
    gemm_k<4><<<dim3(32, 4), 256, 0, stream>>>(xn, a1T, 1024, 512, nullptr, h1, act_b1);
    gemm_k<4><<<dim3(32, 2), 256, 0, stream>>>(h1, a2T, 512, 256, nullptr, h2, act_b2);
    act3_k<<<(TT * AA + 255) / 256, 256, 0, stream>>>(h2, act_w3, act_b3, (float*)d_out);
    gemm_k<4><<<dim3(32, 8), 256, 0, stream>>>(xn, l1T, 1024, 1024, nullptr, hl, lang_b1);
    // logits: g8, 16 x 125 tiles of 256^2 -> 2000 blocks
    g8_k<5><<<2000, 512, 131072, stream>>>(hl, l2T, 1024, 16, VV,
                                           (float*)d_out + (size_t)TT * AA, nullptr, lang_b2);
}

// Round 13
// 1596.096 us; speedup vs baseline: 1.4883x; 1.0099x over previous
//
#include <hip/hip_runtime.h>
#include <hip/hip_bf16.h>
#include <cstdint>
#include <cstddef>

// Problem dims
#define TT 4096   // B*S tokens
#define SS 2048   // S
#define DD 1024   // D
#define DDI 2048  // DI
#define LL 6
#define VV 32000
#define AA 7

typedef __hip_bfloat16 bf16;
typedef __attribute__((ext_vector_type(8))) short bf16x8;   // 8 bf16 in 4 VGPRs
typedef __attribute__((ext_vector_type(4))) short bf16x4;   // 4 bf16 in 2 VGPRs
typedef __attribute__((ext_vector_type(4))) float f32x4;

typedef const __attribute__((address_space(1))) void* gas_ptr;
typedef __attribute__((address_space(3))) void* las_ptr;

static __device__ __forceinline__ float b2f(bf16 h) { return __bfloat162float(h); }
static __device__ __forceinline__ bf16 f2b(float f) { return __float2bfloat16(f); }
static __device__ __forceinline__ float bs2f(short x) {
    unsigned int u = ((unsigned int)(unsigned short)x) << 16;
    float f; __builtin_memcpy(&f, &u, 4); return f;
}
static __device__ __forceinline__ short f2bs(float f) {
    bf16 h = f2b(f); unsigned short us; __builtin_memcpy(&us, &h, 2); return (short)us;
}

// 64-B rows, 4x16B chunks; chunk ^= (row>>1)&3 -> verified 0 conflicts (R4/R5).
#define SWZ(off) ((off) ^ ((((off) >> 7) & 3) << 4))

// ---------------------------------------------------------------------------
// g8: 256x256 8-phase GEMM, BK=64, 8 waves; two 4-slot rings; vmcnt(10).
// R13: epilogue transposes each wave's 128x64 acc through a private 16 KiB
// LDS scratch and stores full-line segments (256 B f32 / 128 B bf16) to kill
// write RFO (FETCH excess ~= WRITE/2 observed through R12).
// EPI: 0 = store bf16; 5 = bias + f32 store.
// ---------------------------------------------------------------------------
template<int EPI>
__global__ __launch_bounds__(512, 2)
void g8_k(const bf16* __restrict__ A, const bf16* __restrict__ Wt,
          int K, int mx, int out_ld,
          float* __restrict__ of32, bf16* __restrict__ ob16,
          const float* __restrict__ bias)
{
    extern __shared__ char lds[];   // 131072
    const int nwg = gridDim.x;
    int l = blockIdx.x;
    if ((nwg & 7) == 0) l = (l & 7) * (nwg >> 3) + (l >> 3);   // XCD-chunked
    const int row0 = (l % mx) * 256, col0 = (l / mx) * 256;

    const int tid = threadIdx.x, wid = tid >> 6, lane = tid & 63;
    const int wr = wid >> 2, wc = wid & 3;        // 2M x 4N waves
    const int l15 = lane & 15, kq = lane >> 4;

    f32x4 acc[8][4];
#pragma unroll
    for (int m = 0; m < 8; ++m)
#pragma unroll
        for (int n = 0; n < 4; ++n) acc[m][n] = f32x4{0.f, 0.f, 0.f, 0.f};

    const int sr   = tid >> 2;
    const int colE = (((tid & 3) ^ ((tid >> 3) & 3)) * 8);
    const bf16* gA = A  + (size_t)(row0 + sr) * K + colE;
    const bf16* gB = Wt + (size_t)(col0 + sr) * K + colE;
    const int dst0 = tid * 16, dst1 = 8192 + tid * 16;

    auto stageA = [&](int kh) {
        char* b = lds + (kh & 3) * 16384;
        __builtin_amdgcn_global_load_lds((gas_ptr)(gA + kh * 32),                   (las_ptr)(b + dst0), 16, 0, 0);
        __builtin_amdgcn_global_load_lds((gas_ptr)(gA + (size_t)128 * K + kh * 32), (las_ptr)(b + dst1), 16, 0, 0);
    };
    auto stageB = [&](int kh) {
        char* b = lds + 65536 + (kh & 3) * 16384;
        __builtin_amdgcn_global_load_lds((gas_ptr)(gB + kh * 32),                   (las_ptr)(b + dst0), 16, 0, 0);
        __builtin_amdgcn_global_load_lds((gas_ptr)(gB + (size_t)128 * K + kh * 32), (las_ptr)(b + dst1), 16, 0, 0);
    };

    const int NT = K >> 6, KH = K >> 5;
    stageA(0); stageB(0); stageA(1); stageB(1);
    stageA(2); stageB(2); stageA(3); stageB(3);
    int nextA = 4, nextB = 4;

    for (int t = 0; t < NT; ++t) {
        const char* As0 = lds + ((2 * t) & 3) * 16384;
        const char* As1 = lds + ((2 * t + 1) & 3) * 16384;
        const char* Bs0 = lds + 65536 + ((2 * t) & 3) * 16384;
        const char* Bs1 = lds + 65536 + ((2 * t + 1) & 3) * 16384;
        bf16x8 af[4], bfg[4];

        // q0
        if (t < NT - 3) asm volatile("s_waitcnt vmcnt(10)" ::: "memory");
        else            asm volatile("s_waitcnt vmcnt(0)" ::: "memory");
        __builtin_amdgcn_sched_barrier(0);
        __builtin_amdgcn_s_barrier();
        __builtin_amdgcn_sched_barrier(0);
#pragma unroll
        for (int fn = 0; fn < 4; ++fn)
            bfg[fn] = *(const bf16x8*)(Bs0 + SWZ((wc * 64 + fn * 16 + l15) * 64 + kq * 16));
#pragma unroll
        for (int fm = 0; fm < 4; ++fm)
            af[fm] = *(const bf16x8*)(As0 + SWZ((wr * 128 + fm * 16 + l15) * 64 + kq * 16));
        if (t > 0 && nextA < KH) { stageA(nextA); ++nextA; }
        asm volatile("s_waitcnt lgkmcnt(0)" ::: "memory");
        __builtin_amdgcn_sched_barrier(0);
        __builtin_amdgcn_s_setprio(1);
#pragma unroll
        for (int fm = 0; fm < 4; ++fm)
#pragma unroll
            for (int fn = 0; fn < 4; ++fn)
                acc[fm][fn] = __builtin_amdgcn_mfma_f32_16x16x32_bf16(af[fm], bfg[fn], acc[fm][fn], 0, 0, 0);
        __builtin_amdgcn_s_setprio(0);
        __builtin_amdgcn_sched_barrier(0);
        __builtin_amdgcn_s_barrier();
        __builtin_amdgcn_sched_barrier(0);

        // q1 (A mh1 of ks0; B reg-reused)
#pragma unroll
        for (int fm = 0; fm < 4; ++fm)
            af[fm] = *(const bf16x8*)(As0 + SWZ((wr * 128 + 64 + fm * 16 + l15) * 64 + kq * 16));
        if (nextB < KH) { stageB(nextB); ++nextB; }
        asm volatile("s_waitcnt lgkmcnt(0)" ::: "memory");
        __builtin_amdgcn_sched_barrier(0);
        __builtin_amdgcn_s_setprio(1);
#pragma unroll
        for (int fm = 0; fm < 4; ++fm)
#pragma unroll
            for (int fn = 0; fn < 4; ++fn)
                acc[4 + fm][fn] = __builtin_amdgcn_mfma_f32_16x16x32_bf16(af[fm], bfg[fn], acc[4 + fm][fn], 0, 0, 0);
        __builtin_amdgcn_s_setprio(0);
        __builtin_amdgcn_sched_barrier(0);
        __builtin_amdgcn_s_barrier();
        __builtin_amdgcn_sched_barrier(0);

        // q2
        if (t < NT - 3) asm volatile("s_waitcnt vmcnt(10)" ::: "memory");
        else            asm volatile("s_waitcnt vmcnt(0)" ::: "memory");
        __builtin_amdgcn_sched_barrier(0);
        __builtin_amdgcn_s_barrier();
        __builtin_amdgcn_sched_barrier(0);
#pragma unroll
        for (int fn = 0; fn < 4; ++fn)
            bfg[fn] = *(const bf16x8*)(Bs1 + SWZ((wc * 64 + fn * 16 + l15) * 64 + kq * 16));
#pragma unroll
        for (int fm = 0; fm < 4; ++fm)
            af[fm] = *(const bf16x8*)(As1 + SWZ((wr * 128 + fm * 16 + l15) * 64 + kq * 16));
        if (nextA < KH) { stageA(nextA); ++nextA; }
        asm volatile("s_waitcnt lgkmcnt(0)" ::: "memory");
        __builtin_amdgcn_sched_barrier(0);
        __builtin_amdgcn_s_setprio(1);
#pragma unroll
        for (int fm = 0; fm < 4; ++fm)
#pragma unroll
            for (int fn = 0; fn < 4; ++fn)
                acc[fm][fn] = __builtin_amdgcn_mfma_f32_16x16x32_bf16(af[fm], bfg[fn], acc[fm][fn], 0, 0, 0);
        __builtin_amdgcn_s_setprio(0);
        __builtin_amdgcn_sched_barrier(0);
        __builtin_amdgcn_s_barrier();
        __builtin_amdgcn_sched_barrier(0);

        // q3 (A mh1 of ks1; B reg-reused)
#pragma unroll
        for (int fm = 0; fm < 4; ++fm)
            af[fm] = *(const bf16x8*)(As1 + SWZ((wr * 128 + 64 + fm * 16 + l15) * 64 + kq * 16));
        if (nextB < KH) { stageB(nextB); ++nextB; }
        asm volatile("s_waitcnt lgkmcnt(0)" ::: "memory");
        __builtin_amdgcn_sched_barrier(0);
        __builtin_amdgcn_s_setprio(1);
#pragma unroll
        for (int fm = 0; fm < 4; ++fm)
#pragma unroll
            for (int fn = 0; fn < 4; ++fn)
                acc[4 + fm][fn] = __builtin_amdgcn_mfma_f32_16x16x32_bf16(af[fm], bfg[fn], acc[4 + fm][fn], 0, 0, 0);
        __builtin_amdgcn_s_setprio(0);
        __builtin_amdgcn_sched_barrier(0);
        __builtin_amdgcn_s_barrier();
        __builtin_amdgcn_sched_barrier(0);
    }

    // ---- epilogue: per-wave LDS transpose -> full-line coalesced stores ----
    // All waves are past the final q3 barrier, so the staging LDS is dead.
    float* sc = (float*)(lds + wid * 16384);   // 64x64 f32, wave-private
#pragma unroll
    for (int h = 0; h < 2; ++h) {
        asm volatile("s_waitcnt lgkmcnt(0)" ::: "memory");   // prior reads done before overwrite
        __builtin_amdgcn_sched_barrier(0);
#pragma unroll
        for (int fm = 0; fm < 4; ++fm)
#pragma unroll
            for (int fn = 0; fn < 4; ++fn)
#pragma unroll
                for (int r = 0; r < 4; ++r)
                    sc[(fm * 16 + kq * 4 + r) * 64 + fn * 16 + l15] = acc[h * 4 + fm][fn][r];
        asm volatile("s_waitcnt lgkmcnt(0)" ::: "memory");
        __builtin_amdgcn_sched_barrier(0);
#pragma unroll
        for (int j = 0; j < 16; ++j) {
            const int rl = j * 4 + kq;
            f32x4 v4 = *(const f32x4*)&sc[rl * 64 + l15 * 4];
            const int row = row0 + wr * 128 + h * 64 + rl;
            const int col = col0 + wc * 64 + l15 * 4;
            if (EPI == 0) {
                bf16x4 ov = { f2bs(v4[0]), f2bs(v4[1]), f2bs(v4[2]), f2bs(v4[3]) };
                *(bf16x4*)(ob16 + (size_t)row * out_ld + col) = ov;
            } else {
                float4 bv = *(const float4*)(bias + col);
                f32x4 ov = { v4[0] + bv.x, v4[1] + bv.y, v4[2] + bv.z, v4[3] + bv.w };
                *(f32x4*)(of32 + (size_t)row * out_ld + col) = ov;
            }
        }
    }
}

// ---------------------------------------------------------------------------
// g8h: 128x128 counted-vmcnt GEMM (ow).  EPI: 3 = residual f32 + bf16.
// ---------------------------------------------------------------------------
template<int EPI>
__global__ __launch_bounds__(256, 2)
void g8h_k(const bf16* __restrict__ A, const bf16* __restrict__ Wt,
           int K, int mx, int out_ld,
           float* __restrict__ of32, bf16* __restrict__ ob16,
           const float* __restrict__ bias)
{
    extern __shared__ char lds[];   // 81920
    const int nwg = gridDim.x;
    int l = blockIdx.x;
    if ((nwg & 7) == 0) l = (l & 7) * (nwg >> 3) + (l >> 3);   // XCD-chunked
    const int row0 = (l % mx) * 128, col0 = (l / mx) * 128;

    const int tid = threadIdx.x, wid = tid >> 6, lane = tid & 63;
    const int wr = wid >> 1, wc = wid & 1;        // 2M x 2N waves
    const int l15 = lane & 15, kq = lane >> 4;

    f32x4 acc[4][4];
#pragma unroll
    for (int m = 0; m < 4; ++m)
#pragma unroll
        for (int n = 0; n < 4; ++n) acc[m][n] = f32x4{0.f, 0.f, 0.f, 0.f};

    const int sr   = tid >> 2;                        // 0..63
    const int colE = (((tid & 3) ^ ((tid >> 3) & 3)) * 8);
    const bf16* gA = A  + (size_t)(row0 + sr) * K + colE;
    const bf16* gB = Wt + (size_t)(col0 + sr) * K + colE;
    const int dst0 = tid * 16, dst1 = 4096 + tid * 16;

    auto stage = [&](int kh) {
        char* a = lds + (kh % 5) * 8192;
        char* b = lds + 40960 + (kh % 5) * 8192;
        __builtin_amdgcn_global_load_lds((gas_ptr)(gA + kh * 32),                  (las_ptr)(a + dst0), 16, 0, 0);
        __builtin_amdgcn_global_load_lds((gas_ptr)(gA + (size_t)64 * K + kh * 32), (las_ptr)(a + dst1), 16, 0, 0);
        __builtin_amdgcn_global_load_lds((gas_ptr)(gB + kh * 32),                  (las_ptr)(b + dst0), 16, 0, 0);
        __builtin_amdgcn_global_load_lds((gas_ptr)(gB + (size_t)64 * K + kh * 32), (las_ptr)(b + dst1), 16, 0, 0);
    };

    const int KH = K >> 5;
    stage(0); stage(1); stage(2); stage(3);

    for (int kh = 0; kh < KH; ++kh) {
        const int rem = KH - 1 - kh;
        if (rem >= 3)      asm volatile("s_waitcnt vmcnt(12)" ::: "memory");
        else if (rem == 2) asm volatile("s_waitcnt vmcnt(8)" ::: "memory");
        else if (rem == 1) asm volatile("s_waitcnt vmcnt(4)" ::: "memory");
        else               asm volatile("s_waitcnt vmcnt(0)" ::: "memory");
        __builtin_amdgcn_sched_barrier(0);
        __builtin_amdgcn_s_barrier();
        __builtin_amdgcn_sched_barrier(0);

        const char* As = lds + (kh % 5) * 8192;
        const char* Bs = lds + 40960 + (kh % 5) * 8192;
        bf16x8 af[4], bfg[4];
#pragma unroll
        for (int fn = 0; fn < 4; ++fn)
            bfg[fn] = *(const bf16x8*)(Bs + SWZ((wc * 64 + fn * 16 + l15) * 64 + kq * 16));
#pragma unroll
        for (int fm = 0; fm < 4; ++fm)
            af[fm] = *(const bf16x8*)(As + SWZ((wr * 64 + fm * 16 + l15) * 64 + kq * 16));
        if (kh + 4 < KH) stage(kh + 4);
        asm volatile("s_waitcnt lgkmcnt(0)" ::: "memory");
        __builtin_amdgcn_sched_barrier(0);
        __builtin_amdgcn_s_setprio(1);
#pragma unroll
        for (int fm = 0; fm < 4; ++fm)
#pragma unroll
            for (int fn = 0; fn < 4; ++fn)
                acc[fm][fn] = __builtin_amdgcn_mfma_f32_16x16x32_bf16(af[fm], bfg[fn], acc[fm][fn], 0, 0, 0);
        __builtin_amdgcn_s_setprio(0);
        __builtin_amdgcn_sched_barrier(0);
    }

#pragma unroll
    for (int fm = 0; fm < 4; ++fm) {
#pragma unroll
        for (int fn = 0; fn < 4; ++fn) {
#pragma unroll
            for (int r = 0; r < 4; ++r) {
                const int row = row0 + wr * 64 + fm * 16 + kq * 4 + r;
                const int col = col0 + wc * 64 + fn * 16 + l15;
                float v = acc[fm][fn][r];
                if (EPI == 3) {
                    float rr = of32[(size_t)row * out_ld + col] + v;
                    of32[(size_t)row * out_ld + col] = rr;
                    ob16[(size_t)row * out_ld + col] = f2b(rr);
                } else {
                    ob16[(size_t)row * out_ld + col] = f2b(v);
                }
            }
        }
    }
}

// ---------------------------------------------------------------------------
// 128x128 m97-structure GEMM.  EPI: 4=bias+relu bf16
// ---------------------------------------------------------------------------
template<int EPI>
__global__ __launch_bounds__(256)
void gemm_k(const bf16* __restrict__ A, const bf16* __restrict__ Wt,
            int K, int out_ld,
            float* __restrict__ of32, bf16* __restrict__ ob16,
            const float* __restrict__ bias)
{
    __shared__ bf16x8 lsA8[128 * 4];
    __shared__ bf16x8 lsB8[128 * 4];
    bf16* lsA = (bf16*)lsA8;
    bf16* lsB = (bf16*)lsB8;

    const int tid  = threadIdx.x;
    const int w    = tid >> 6;
    const int lane = tid & 63;
    const int row0 = blockIdx.x * 128;
    const int col0 = blockIdx.y * 128;
    const int wr   = (w >> 1) * 64;
    const int wc   = (w & 1) * 64;
    const int l15  = lane & 15;
    const int kq   = lane >> 4;

    f32x4 acc[4][4];
#pragma unroll
    for (int m = 0; m < 4; ++m)
#pragma unroll
        for (int n = 0; n < 4; ++n) acc[m][n] = f32x4{0.f, 0.f, 0.f, 0.f};

    const int s0 = tid, s1 = tid + 256;
    const size_t ga0 = (size_t)(row0 + (s0 >> 2)) * K + (s0 & 3) * 8;
    const size_t ga1 = (size_t)(row0 + (s1 >> 2)) * K + (s1 & 3) * 8;
    const size_t gb0 = (size_t)(col0 + (s0 >> 2)) * K + (s0 & 3) * 8;
    const size_t gb1 = (size_t)(col0 + (s1 >> 2)) * K + (s1 & 3) * 8;
    bf16* la0 = lsA + (size_t)(w * 64) * 8;
    bf16* la1 = lsA + (size_t)(256 + w * 64) * 8;
    bf16* lb0 = lsB + (size_t)(w * 64) * 8;
    bf16* lb1 = lsB + (size_t)(256 + w * 64) * 8;

    for (int k0 = 0; k0 < K; k0 += 32) {
        __builtin_amdgcn_global_load_lds((gas_ptr)(A  + ga0 + k0), (las_ptr)la0, 16, 0, 0);
        __builtin_amdgcn_global_load_lds((gas_ptr)(A  + ga1 + k0), (las_ptr)la1, 16, 0, 0);
        __builtin_amdgcn_global_load_lds((gas_ptr)(Wt + gb0 + k0), (las_ptr)lb0, 16, 0, 0);
        __builtin_amdgcn_global_load_lds((gas_ptr)(Wt + gb1 + k0), (las_ptr)lb1, 16, 0, 0);
        __syncthreads();

        bf16x8 af[4], bfr[4];
#pragma unroll
        for (int m = 0; m < 4; ++m)
            af[m] = *(const bf16x8*)(lsA + (size_t)(wr + m * 16 + l15) * 32 + kq * 8);
#pragma unroll
        for (int n = 0; n < 4; ++n)
            bfr[n] = *(const bf16x8*)(lsB + (size_t)(wc + n * 16 + l15) * 32 + kq * 8);
#pragma unroll
        for (int m = 0; m < 4; ++m)
#pragma unroll
            for (int n = 0; n < 4; ++n)
                acc[m][n] = __builtin_amdgcn_mfma_f32_16x16x32_bf16(af[m], bfr[n], acc[m][n], 0, 0, 0);
        __syncthreads();
    }

#pragma unroll
    for (int m = 0; m < 4; ++m) {
#pragma unroll
        for (int n = 0; n < 4; ++n) {
#pragma unroll
            for (int r = 0; r < 4; ++r) {
                const int row = row0 + wr + m * 16 + kq * 4 + r;
                const int col = col0 + wc + n * 16 + l15;
                float v = acc[m][n][r];
                v = fmaxf(v + bias[col], 0.f);
                ob16[(size_t)row * out_ld + col] = f2b(v);
            }
        }
    }
}

// ---------------------------------------------------------------------------
// Fused conv + split-K skinny u-GEMM (R12, measured good).
// ---------------------------------------------------------------------------
__global__ __launch_bounds__(256)
void cusk_k(const bf16* __restrict__ xz, const float* __restrict__ cw,
            const float* __restrict__ cb, const bf16* __restrict__ Wt,
            float* __restrict__ up)
{
    __shared__ bf16x8 lsA8[128 * 4];
    __shared__ bf16x8 lsB8[128 * 4];
    bf16* lsA = (bf16*)lsA8;
    bf16* lsB = (bf16*)lsB8;
    const int K = 2048;

    const int tid  = threadIdx.x;
    const int w    = tid >> 6;
    const int lane = tid & 63;
    const int row0 = blockIdx.x * 128;
    const int spl  = blockIdx.y;          // 0..7
    const int kbeg = spl * 256;
    const int wr   = (w >> 1) * 64;
    const int wc   = (w & 1) * 64;
    const int l15  = lane & 15;
    const int kq   = lane >> 4;

    f32x4 acc[4][4];
#pragma unroll
    for (int m = 0; m < 4; ++m)
#pragma unroll
        for (int n = 0; n < 4; ++n) acc[m][n] = f32x4{0.f, 0.f, 0.f, 0.f};

    const int trow = tid >> 2, tch = tid & 3;
    const int r0g = row0 + trow, r1g = r0g + 64;
    const int sq0 = r0g & (SS - 1), sq1 = r1g & (SS - 1);

    const int s0 = tid, s1 = tid + 256;
    const size_t gb0 = (size_t)(s0 >> 2) * K + (s0 & 3) * 8;
    const size_t gb1 = (size_t)(s1 >> 2) * K + (s1 & 3) * 8;
    bf16* lb0 = lsB + (size_t)(w * 64) * 8;
    bf16* lb1 = lsB + (size_t)(256 + w * 64) * 8;

    for (int k0 = kbeg; k0 < kbeg + 256; k0 += 32) {
        const int i0 = k0 + tch * 8;       // channel base (< 2048)

        __builtin_amdgcn_global_load_lds((gas_ptr)(Wt + gb0 + k0), (las_ptr)lb0, 16, 0, 0);
        __builtin_amdgcn_global_load_lds((gas_ptr)(Wt + gb1 + k0), (las_ptr)lb1, 16, 0, 0);

        bf16x8 vA0, vA1;
        {
            const bf16* b0 = xz + (size_t)r0g * 4096 + i0;
            bf16x8 x0 = *(const bf16x8*)b0;
            bf16x8 x1 = {}, x2 = {}, x3 = {};
            if (sq0 >= 1) x1 = *(const bf16x8*)(b0 - 4096);
            if (sq0 >= 2) x2 = *(const bf16x8*)(b0 - 2 * 4096);
            if (sq0 >= 3) x3 = *(const bf16x8*)(b0 - 3 * 4096);
#pragma unroll
            for (int c = 0; c < 8; ++c) {
                float4 wv4 = ((const float4*)cw)[i0 + c];
                float a = cb[i0 + c];
                a = fmaf(bs2f(x3[c]), wv4.x, a);
                a = fmaf(bs2f(x2[c]), wv4.y, a);
                a = fmaf(bs2f(x1[c]), wv4.z, a);
                a = fmaf(bs2f(x0[c]), wv4.w, a);
                float sig = 1.f / (1.f + expf(-a));
                vA0[c] = f2bs(a * sig);
            }
        }
        {
            const bf16* b0 = xz + (size_t)r1g * 4096 + i0;
            bf16x8 x0 = *(const bf16x8*)b0;
            bf16x8 x1 = {}, x2 = {}, x3 = {};
            if (sq1 >= 1) x1 = *(const bf16x8*)(b0 - 4096);
            if (sq1 >= 2) x2 = *(const bf16x8*)(b0 - 2 * 4096);
            if (sq1 >= 3) x3 = *(const bf16x8*)(b0 - 3 * 4096);
#pragma unroll
            for (int c = 0; c < 8; ++c) {
                float4 wv4 = ((const float4*)cw)[i0 + c];
                float a = cb[i0 + c];
                a = fmaf(bs2f(x3[c]), wv4.x, a);
                a = fmaf(bs2f(x2[c]), wv4.y, a);
                a = fmaf(bs2f(x1[c]), wv4.z, a);
                a = fmaf(bs2f(x0[c]), wv4.w, a);
                float sig = 1.f / (1.f + expf(-a));
                vA1[c] = f2bs(a * sig);
            }
        }
        lsA8[tid] = vA0;
        lsA8[tid + 256] = vA1;
        __syncthreads();

        bf16x8 af[4], bfr[4];
#pragma unroll
        for (int m = 0; m < 4; ++m)
            af[m] = *(const bf16x8*)(lsA + (size_t)(wr + m * 16 + l15) * 32 + kq * 8);
#pragma unroll
        for (int n = 0; n < 4; ++n)
            bfr[n] = *(const bf16x8*)(lsB + (size_t)(wc + n * 16 + l15) * 32 + kq * 8);
#pragma unroll
        for (int m = 0; m < 4; ++m)
#pragma unroll
            for (int n = 0; n < 4; ++n)
                acc[m][n] = __builtin_amdgcn_mfma_f32_16x16x32_bf16(af[m], bfr[n], acc[m][n], 0, 0, 0);
        __syncthreads();
    }

    if (wc == 0) {
#pragma unroll
        for (int m = 0; m < 4; ++m)
#pragma unroll
            for (int r = 0; r < 4; ++r) {
                const int row = row0 + wr + m * 16 + kq * 4 + r;
                up[(size_t)spl * TT * 16 + (size_t)row * 16 + l15] = acc[m][0][r];
            }
    }
}

// reduce the 8 K-split partials: u = sum_s up[s]
__global__ void ured_k(const float* __restrict__ up, float* __restrict__ u)
{
    int i = blockIdx.x * 256 + threadIdx.x;   // TT*16 = 65536
    float s = 0.f;
#pragma unroll
    for (int k = 0; k < 8; ++k) s += up[(size_t)k * TT * 16 + i];
    u[i] = s;
}

// ---------------------------------------------------------------------------
// fp32 [K,N] -> bf16 [N,K] transpose (64x64 tiles through LDS)
// ---------------------------------------------------------------------------
__global__ __launch_bounds__(256)
void transpose_k(const float* __restrict__ W, bf16* __restrict__ WT, int K, int N)
{
    __shared__ bf16 t[64][66];
    const int k0 = blockIdx.x * 64, n0 = blockIdx.y * 64;
    const int tid = threadIdx.x;
#pragma unroll
    for (int i = 0; i < 16; ++i) {
        int idx = i * 256 + tid;
        int kk = idx >> 6, nn = idx & 63;
        t[nn][kk] = f2b(W[(size_t)(k0 + kk) * N + n0 + nn]);
    }
    __syncthreads();
#pragma unroll
    for (int i = 0; i < 16; ++i) {
        int idx = i * 256 + tid;
        int nn = idx >> 6, kk = idx & 63;
        WT[(size_t)(n0 + nn) * K + k0 + kk] = t[nn][kk];
    }
}

// B_ssm [DI,16] fp32 -> bf16 [128,DI] padded, x0.1 folded in
__global__ void prep_bm_k(const float* __restrict__ Bm, bf16* __restrict__ BmT)
{
    int idx = blockIdx.x * 256 + threadIdx.x;   // 128*2048
    int n = idx >> 11, k = idx & 2047;
    float v = (n < 16) ? Bm[(size_t)k * 16 + n] * 0.1f : 0.f;
    BmT[idx] = f2b(v);
}

// features -> fp32 residual copy + bf16 copy
__global__ void copyfeat_k(const float* __restrict__ f, float* __restrict__ xf,
                           bf16* __restrict__ xb)
{
    int i = (blockIdx.x * 256 + threadIdx.x) * 4;
    float4 v = *(const float4*)(f + i);
    *(float4*)(xf + i) = v;
    xb[i + 0] = f2b(v.x);
    xb[i + 1] = f2b(v.y);
    xb[i + 2] = f2b(v.z);
    xb[i + 3] = f2b(v.w);
}

// ---------------------------------------------------------------------------
// scan h_t = 0.9 h + u_t; chunk=32 tokens, redundant 96-step warmup; fp32 out.
// ---------------------------------------------------------------------------
__global__ void scan2_k(const float* __restrict__ u, float* __restrict__ hs)
{
    int gid = blockIdx.x * 256 + threadIdx.x;   // 2048 total
    int n = gid & 15, c = (gid >> 4) & 63, b = gid >> 10;
    int start = c * 32;
    const float* ub = u + (size_t)b * SS * 16;
    float* hb = hs + (size_t)b * SS * 16;
    float h = 0.f;
    int w0 = start - 96; if (w0 < 0) w0 = 0;
    for (int t = w0; t < start; ++t) h = 0.9f * h + ub[(size_t)t * 16 + n];
    for (int t = start; t < start + 32; ++t) {
        h = 0.9f * h + ub[(size_t)t * 16 + n];
        hb[(size_t)t * 16 + n] = h;
    }
}

// ---------------------------------------------------------------------------
// y[t,i] = (sum_n hs[t,n] * Cm[n,i]) * silu(z[t,i])
// ---------------------------------------------------------------------------
__global__ __launch_bounds__(256)
void yk_k(const float* __restrict__ hs, const float* __restrict__ Cm,
          const bf16* __restrict__ xz, bf16* __restrict__ y)
{
    const int t = blockIdx.x, i0 = threadIdx.x * 8;
    const float* h = hs + (size_t)t * 16;
    float o[8] = {0.f, 0.f, 0.f, 0.f, 0.f, 0.f, 0.f, 0.f};
#pragma unroll
    for (int n = 0; n < 16; ++n) {
        float hn = h[n];
        const float4* c = (const float4*)(Cm + (size_t)n * DDI + i0);
        float4 c0 = c[0], c1 = c[1];
        o[0] = fmaf(hn, c0.x, o[0]); o[1] = fmaf(hn, c0.y, o[1]);
        o[2] = fmaf(hn, c0.z, o[2]); o[3] = fmaf(hn, c0.w, o[3]);
        o[4] = fmaf(hn, c1.x, o[4]); o[5] = fmaf(hn, c1.y, o[5]);
        o[6] = fmaf(hn, c1.z, o[6]); o[7] = fmaf(hn, c1.w, o[7]);
    }
    bf16x8 zv = *(const bf16x8*)(xz + (size_t)t * 4096 + 2048 + i0);
    bf16* yo = y + (size_t)t * DDI + i0;
#pragma unroll
    for (int j = 0; j < 8; ++j) {
        float zf = bs2f(zv[j]);
        yo[j] = f2b(o[j] * (zf / (1.f + expf(-zf))));
    }
}

// LayerNorm fp32 -> bf16
__global__ __launch_bounds__(256)
void ln_k(const float* __restrict__ x, const float* __restrict__ g,
          const float* __restrict__ bb, bf16* __restrict__ xn)
{
    int t = blockIdx.x, tid = threadIdx.x;
    const float* xr = x + (size_t)t * DD;
    float4 v = *(const float4*)(xr + tid * 4);
    float s = v.x + v.y + v.z + v.w;
#pragma unroll
    for (int o = 32; o > 0; o >>= 1) s += __shfl_down(s, o, 64);
    __shared__ float r1[4], r2[4];
    if ((tid & 63) == 0) r1[tid >> 6] = s;
    __syncthreads();
    float mu = (r1[0] + r1[1] + r1[2] + r1[3]) * (1.f / DD);
    float d0 = v.x - mu, d1 = v.y - mu, d2 = v.z - mu, d3 = v.w - mu;
    float ss = d0 * d0 + d1 * d1 + d2 * d2 + d3 * d3;
#pragma unroll
    for (int o = 32; o > 0; o >>= 1) ss += __shfl_down(ss, o, 64);
    if ((tid & 63) == 0) r2[tid >> 6] = ss;
    __syncthreads();
    float var = (r2[0] + r2[1] + r2[2] + r2[3]) * (1.f / DD);
    float inv = rsqrtf(var + 1e-5f);
    int di = tid * 4;
    xn[(size_t)t * DD + di + 0] = f2b(d0 * inv * g[di + 0] + bb[di + 0]);
    xn[(size_t)t * DD + di + 1] = f2b(d1 * inv * g[di + 1] + bb[di + 1]);
    xn[(size_t)t * DD + di + 2] = f2b(d2 * inv * g[di + 2] + bb[di + 2]);
    xn[(size_t)t * DD + di + 3] = f2b(d3 * inv * g[di + 3] + bb[di + 3]);
}

// tiny head: actions = tanh(h2 @ w3 + b3)
__global__ void act3_k(const bf16* __restrict__ h2, const float* __restrict__ w3,
                       const float* __restrict__ b3, float* __restrict__ out)
{
    int idx = blockIdx.x * 256 + threadIdx.x;
    if (idx >= TT * AA) return;
    int t = idx / AA, a = idx - t * AA;
    float acc = b3[a];
    const bf16* hr = h2 + (size_t)t * 256;
    for (int k = 0; k < 256; ++k)
        acc = fmaf(b2f(hr[k]), w3[k * AA + a], acc);
    out[idx] = tanhf(acc);
}

// ---------------------------------------------------------------------------
extern "C" void kernel_launch(void* const* d_in, const int* in_sizes, int n_in,
                              void* d_out, int out_size, void* d_ws, size_t ws_size,
                              hipStream_t stream)
{
    (void)in_sizes; (void)n_in; (void)out_size; (void)ws_size;
    const float* features = (const float*)d_in[0];
    const float* in_proj_w = (const float*)d_in[1];
    const float* conv_w = (const float*)d_in[2];
    const float* conv_b = (const float*)d_in[3];
    const float* B_ssm = (const float*)d_in[4];
    const float* C_ssm = (const float*)d_in[5];
    const float* out_w = (const float*)d_in[6];
    const float* ln_g = (const float*)d_in[7];
    const float* ln_b = (const float*)d_in[8];
    const float* act_w1 = (const float*)d_in[9];
    const float* act_b1 = (const float*)d_in[10];
    const float* act_w2 = (const float*)d_in[11];
    const float* act_b2 = (const float*)d_in[12];
    const float* act_w3 = (const float*)d_in[13];
    const float* act_b3 = (const float*)d_in[14];
    const float* lang_w1 = (const float*)d_in[15];
    const float* lang_b1 = (const float*)d_in[16];
    const float* lang_w2 = (const float*)d_in[17];
    const float* lang_b2 = (const float*)d_in[18];

    static bool attr_done = false;
    if (!attr_done) {
        hipFuncSetAttribute((const void*)&g8_k<0>, hipFuncAttributeMaxDynamicSharedMemorySize, 131072);
        hipFuncSetAttribute((const void*)&g8_k<5>, hipFuncAttributeMaxDynamicSharedMemorySize, 131072);
        hipFuncSetAttribute((const void*)&g8h_k<3>, hipFuncAttributeMaxDynamicSharedMemorySize, 81920);
        attr_done = true;
    }

    char* p = (char*)d_ws;
    size_t off = 0;
    auto alloc = [&](size_t bytes) -> void* {
        void* q = p + off;
        off = (off + bytes + 255) & ~(size_t)255;
        return q;
    };
    float* x_f  = (float*)alloc((size_t)TT * DD * 4);     // fp32 residual stream
    bf16*  x_b  = (bf16*) alloc((size_t)TT * DD * 2);     // bf16 mirror
    bf16*  xz   = (bf16*) alloc((size_t)TT * 4096 * 2);   // in_proj out (xp|z)
    bf16*  y    = (bf16*) alloc((size_t)TT * DDI * 2);    // gated SSM out
    float* u    = (float*)alloc((size_t)TT * 16 * 4);
    float* up   = (float*)alloc((size_t)8 * TT * 16 * 4); // split-K partials
    float* hs   = (float*)alloc((size_t)TT * 16 * 4);     // scan out fp32
    bf16*  xn   = (bf16*) alloc((size_t)TT * DD * 2);
    bf16*  h1   = (bf16*) alloc((size_t)TT * 512 * 2);
    bf16*  h2   = (bf16*) alloc((size_t)TT * 256 * 2);
    bf16*  hl   = (bf16*) alloc((size_t)TT * DD * 2);
    bf16*  inwT = (bf16*) alloc((size_t)LL * 4096 * 1024 * 2);
    bf16*  owT  = (bf16*) alloc((size_t)LL * 1024 * 2048 * 2);
    bf16*  bmT  = (bf16*) alloc((size_t)LL * 128 * 2048 * 2);
    bf16*  a1T  = (bf16*) alloc((size_t)512 * 1024 * 2);
    bf16*  a2T  = (bf16*) alloc((size_t)256 * 512 * 2);
    bf16*  l1T  = (bf16*) alloc((size_t)1024 * 1024 * 2);
    bf16*  l2T  = (bf16*) alloc((size_t)VV * 1024 * 2);

    // ---- prep: fp32->bf16 + transpose all GEMM weights (per call) ----
    copyfeat_k<<<TT * DD / 1024, 256, 0, stream>>>(features, x_f, x_b);
    for (int l = 0; l < LL; ++l) {
        transpose_k<<<dim3(16, 64), 256, 0, stream>>>(in_proj_w + (size_t)l * 1024 * 4096,
                                                      inwT + (size_t)l * 4096 * 1024, 1024, 4096);
        transpose_k<<<dim3(32, 16), 256, 0, stream>>>(out_w + (size_t)l * 2048 * 1024,
                                                      owT + (size_t)l * 1024 * 2048, 2048, 1024);
        prep_bm_k<<<(128 * 2048) / 256, 256, 0, stream>>>(B_ssm + (size_t)l * 2048 * 16,
                                                          bmT + (size_t)l * 128 * 2048);
    }
    transpose_k<<<dim3(16, 8), 256, 0, stream>>>(act_w1, a1T, 1024, 512);
    transpose_k<<<dim3(8, 4), 256, 0, stream>>>(act_w2, a2T, 512, 256);
    transpose_k<<<dim3(16, 16), 256, 0, stream>>>(lang_w1, l1T, 1024, 1024);
    transpose_k<<<dim3(16, 500), 256, 0, stream>>>(lang_w2, l2T, 1024, VV);

    // ---- 6 mamba blocks ----
    for (int l = 0; l < LL; ++l) {
        // xz = x @ in_w : g8, 16x16 tiles of 256^2 -> 256 blocks
        g8_k<0><<<256, 512, 131072, stream>>>(x_b, inwT + (size_t)l * 4096 * 1024,
                                              1024, 16, 4096, nullptr, xz, nullptr);
        // u = 0.1 * silu(conv(xp)+cb) @ Bm : fused conv + split-K GEMM
        cusk_k<<<dim3(32, 8), 256, 0, stream>>>(xz, conv_w + (size_t)l * DDI * 4,
                                                conv_b + (size_t)l * DDI,
                                                bmT + (size_t)l * 128 * 2048, up);
        ured_k<<<TT * 16 / 256, 256, 0, stream>>>(up, u);
        // hs = scan(u)  (fp32)
        scan2_k<<<8, 256, 0, stream>>>(u, hs);
        // y = (hs @ Cm) * silu(z)  : fused VALU kernel (BW-bound)
        yk_k<<<TT, 256, 0, stream>>>(hs, C_ssm + (size_t)l * 16 * 2048, xz, y);
        // x += y @ ow : g8h counted-vmcnt 128^2, grid 32x8=256, 2 blocks/CU
        g8h_k<3><<<256, 256, 81920, stream>>>(y, owT + (size_t)l * 1024 * 2048,
                                              2048, 32, 1024, x_f, x_b, nullptr);
    }

    // ---- LN + heads ----
    ln_k<<<TT, 256, 0, stream>>>(x_f, ln_g, ln_b, xn);
    gemm_k<4><<<dim3(32, 4), 256, 0, stream>>>(xn, a1T, 1024, 512, nullptr, h1, act_b1);
    gemm_k<4><<<dim3(32, 2), 256, 0, stream>>>(h1, a2T, 512, 256, nullptr, h2, act_b2);
    act3_k<<<(TT * AA + 255) / 256, 256, 0, stream>>>(h2, act_w3, act_b3, (float*)d_out);
    gemm_k<4><<<dim3(32, 8), 256, 0, stream>>>(xn, l1T, 1024, 1024, nullptr, hl, lang_b1);
    // logits: g8, 16 x 125 tiles of 256^2 -> 2000 blocks
    g8_k<5><<<2000, 512, 131072, stream>>>(hl, l2T, 1024, 16, VV,
                                           (float*)d_out + (size_t)TT * AA, nullptr, lang_b2);
}